// Round 1
// baseline (457.170 us; speedup 1.0000x reference)
//
#include <hip/hip_runtime.h>
#include <math.h>

#define NSAMP 32768
#define NFFT2 65536
#define NFRM 128
#define NROWS 128
#define PSTRIDE 320

typedef float2 cplx;

__device__ __forceinline__ cplx cmul_(cplx a, cplx b){ return make_float2(a.x*b.x - a.y*b.y, a.x*b.y + a.y*b.x); }
__device__ __forceinline__ cplx cadd_(cplx a, cplx b){ return make_float2(a.x+b.x, a.y+b.y); }
__device__ __forceinline__ cplx csub_(cplx a, cplx b){ return make_float2(a.x-b.x, a.y-b.y); }

template<bool INV>
__device__ __forceinline__ void dft4_(cplx x0,cplx x1,cplx x2,cplx x3, cplx&y0,cplx&y1,cplx&y2,cplx&y3){
  cplx t0=cadd_(x0,x2), t1=csub_(x0,x2), t2=cadd_(x1,x3), t3=csub_(x1,x3);
  y0=cadd_(t0,t2); y2=csub_(t0,t2);
  cplx it3 = make_float2(-t3.y, t3.x);
  if (INV){ y1=cadd_(t1,it3); y3=csub_(t1,it3); }
  else    { y1=csub_(t1,it3); y3=cadd_(t1,it3); }
}

template<bool INV>
__device__ __forceinline__ void dft8_(const cplx* a, cplx* b){
  cplx e0,e1,e2,e3,o0,o1,o2,o3;
  dft4_<INV>(a[0],a[2],a[4],a[6], e0,e1,e2,e3);
  dft4_<INV>(a[1],a[3],a[5],a[7], o0,o1,o2,o3);
  const float r = 0.70710678118654752440f;
  cplx w1 = INV ? make_float2(r, r)    : make_float2(r,-r);
  cplx w2 = INV ? make_float2(0.f,1.f) : make_float2(0.f,-1.f);
  cplx w3 = INV ? make_float2(-r,r)    : make_float2(-r,-r);
  cplx t1 = cmul_(o1,w1), t2 = cmul_(o2,w2), t3 = cmul_(o3,w3);
  b[0]=cadd_(e0,o0); b[4]=csub_(e0,o0);
  b[1]=cadd_(e1,t1); b[5]=csub_(e1,t1);
  b[2]=cadd_(e2,t2); b[6]=csub_(e2,t2);
  b[3]=cadd_(e3,t3); b[7]=csub_(e3,t3);
}

// ---------------- Stockham mixed-radix pass ----------------
// pass: n = N/s current sub-length, m = n/R.  tau = p*s+q in [0, N/R).
// load  src[sig*N + tau + r*(N/R)]
// store dst[sig*N + q + s*(R*p+u)] * W_n^{p*u}   (thetaBase = sgn*2*pi*s/N)
template<int R, bool INV>
__global__ __launch_bounds__(256) void k_fft_pass(const cplx* __restrict__ src, cplx* __restrict__ dst,
    int logPerSig, int logS, int N, float thetaBase, int total){
  int idx = blockIdx.x*blockDim.x + threadIdx.x;
  if (idx >= total) return;
  int perSig = 1<<logPerSig;
  int sig = idx >> logPerSig;
  int tau = idx & (perSig-1);
  int p = tau >> logS;
  int q = tau & ((1<<logS)-1);
  size_t base = (size_t)sig * (size_t)N;
  const cplx* sb = src + base;
  cplx* db = dst + base;
  cplx a[R], b[R];
  #pragma unroll
  for (int r=0;r<R;r++) a[r] = sb[tau + r*perSig];
  if constexpr (R==8) dft8_<INV>(a,b);
  else { b[0]=cadd_(a[0],a[1]); b[1]=csub_(a[0],a[1]); }
  float theta = thetaBase*(float)p;
  float sn, cs; sincosf(theta, &sn, &cs);
  cplx w = make_float2(cs, sn), wu = w;
  int ob = q + ((p<<logS)*R);
  db[ob] = b[0];
  #pragma unroll
  for (int u=1;u<R;u++){ db[ob + (u<<logS)] = cmul_(b[u], wu); wu = cmul_(wu, w); }
}

// ---------------- parameter extraction ----------------
__global__ void k_params(const float* __restrict__ x, float* __restrict__ P){
  int row = blockIdx.x; int tid = threadIdx.x;
  const float* xr = x + row*428;
  float* Pr = P + row*PSTRIDE;
  __shared__ float sx[428];
  for (int i = tid; i < 428; i += 64) sx[i] = 1.0f/(1.0f+expf(-xr[i]));
  __syncthreads();
  if (tid == 0){
    float mean = sx[0]; float stds = sx[1]*0.1f; float amp = sx[2]*sx[2];
    float f0 = sx[3]*sx[3];
    float mu = fminf(fmaxf(mean*32768.0f, -16384.0f), 49152.0f);
    float sigma = fminf(fmaxf((1e-8f + stds)*32768.0f, 0.0f), 32767.0f);
    float c = 1.0f/(sigma*2.5066282746310002f);
    float tt0 = fminf(fmaxf(floorf(mu), 0.0f), 32767.0f);
    float tt1 = fminf(fmaxf(ceilf(mu), 0.0f), 32767.0f);
    float z0 = (tt0-mu)/sigma, z1=(tt1-mu)/sigma;
    float gmax = fmaxf(expf(-0.5f*z0*z0), expf(-0.5f*z1*z1));
    float pscale = c / (c*gmax + 1e-12f);
    Pr[0]=mu; Pr[1]=sigma; Pr[2]=amp; Pr[3]=pscale;
    Pr[4] = 1.0f;
    for (int h=1;h<8;h++) Pr[4+h] = 1.0f + sx[4+h]*7.0f;
    for (int h=0;h<8;h++){ float m = sx[12+h]*0.9999f; Pr[12+h] = m*m; }
    for (int h=0;h<8;h++) Pr[20+h] = sx[164+h]*sx[164+h];
    for (int i=0;i<16;i++) Pr[28+i] = sx[20+i];
    float acc = 0.0f;
    for (int f=0; f<NFRM; f++){ acc += sx[36+f]*2.0f - 1.0f; Pr[64+f] = fminf(fmaxf(acc,0.0f),1.0f); }
    for (int f=0; f<NFRM; f++){ float var = sx[172+f]*(f0*0.01f); Pr[192+f] = f0 + var; }
  }
}

// ---------------- pack noise pairs ----------------
__global__ void k_pack_noise(const float* __restrict__ noise, cplx* __restrict__ A){
  int i = blockIdx.x*blockDim.x + threadIdx.x;
  if (i >= 64*NSAMP) return;
  int j = i >> 15; int t = i & (NSAMP-1);
  float re = noise[(size_t)(2*j)*NSAMP + t]*2.0f - 1.0f;
  float im = noise[(size_t)(2*j+1)*NSAMP + t]*2.0f - 1.0f;
  A[i] = make_float2(re, im);
}

// ---------------- spectral filter + repack for inverse, x(1/N) ----------------
__global__ void k_filter(const cplx* __restrict__ Zb, cplx* __restrict__ Ab, const float* __restrict__ P){
  int i = blockIdx.x*blockDim.x + threadIdx.x;
  if (i >= 64*NSAMP) return;
  int j = i >> 15; int k = i & (NSAMP-1);
  cplx Z = Zb[i];
  cplx Zc = Zb[(j<<15) + ((NSAMP - k) & (NSAMP-1))];
  cplx U1 = make_float2(0.5f*(Z.x + Zc.x), 0.5f*(Z.y - Zc.y));
  cplx U2 = make_float2(0.5f*(Z.y + Zc.y), -0.5f*(Z.x - Zc.x));
  int kb = (k <= NSAMP/2) ? k : (NSAMP - k);
  float coords = (kb + 0.5f)*(16.0f/16385.0f) - 0.5f;
  coords = fminf(fmaxf(coords, 0.0f), 15.0f);
  int lo = (int)coords; float w = coords - lo; int hi = min(lo+1, 15);
  const float* c1 = P + (size_t)(2*j)*PSTRIDE + 28;
  const float* c2 = c1 + PSTRIDE;
  float s1 = c1[lo]*(1.0f-w) + c1[hi]*w;
  float s2 = c2[lo]*(1.0f-w) + c2[hi]*w;
  const float scale = 1.0f/32768.0f;
  float S1x = U1.x*s1*scale, S1y = U1.y*s1*scale;
  float S2x = U2.x*s2*scale, S2y = U2.y*s2*scale;
  Ab[i] = make_float2(S1x - S2y, S1y + S2x);
}

// ---------------- build atoms (re) + res (im), zero-pad upper half ----------------
__global__ __launch_bounds__(256) void k_build(const float* __restrict__ P,
    const cplx* __restrict__ NZ, cplx* __restrict__ C, int rowBase){
  int row = rowBase + blockIdx.x;
  int tid = threadIdx.x;
  const float* Pr = P + (size_t)row*PSTRIDE;
  __shared__ float fe[NFRM], f0a[NFRM];
  __shared__ float pw[8][NFRM];
  __shared__ double lsum[256];
  __shared__ float fac_s[8], mags_s[8], ampf_s[8];
  if (tid < NFRM){ fe[tid]=Pr[64+tid]; f0a[tid]=Pr[192+tid]; }
  if (tid < 8){ fac_s[tid]=Pr[4+tid]; mags_s[tid]=Pr[12+tid]; ampf_s[tid]=Pr[20+tid]; }
  __syncthreads();
  if (tid < 8){
    float m = mags_s[tid], acc = m;
    pw[tid][0]=acc;
    for (int f=1; f<NFRM; f++){ acc*=m; pw[tid][f]=acc; }
  }
  const float MINF  = 20.0f/11025.0f;
  const float FSPAN = (3000.0f-20.0f)/11025.0f;
  int t0 = tid*128;
  double local = 0.0;
  for (int i=0;i<128;i++){
    int t = t0+i;
    float cc = fminf(fmaxf((t+0.5f)*(1.0f/256.0f)-0.5f,0.0f),127.0f);
    int lo=(int)cc; float w=cc-lo; int hi=min(lo+1,NFRM-1);
    float f0t = MINF + (f0a[lo]*(1.0f-w)+f0a[hi]*w)*FSPAN;
    local += (double)f0t;
  }
  lsum[tid]=local;
  __syncthreads();
  if (tid==0){
    double acc=0.0;
    for (int j=0;j<256;j++){ double v=lsum[j]; lsum[j]=acc; acc+=v; }
  }
  __syncthreads();
  double phi = lsum[tid];
  float mu=Pr[0], sigma=Pr[1], amp=Pr[2], pscale=Pr[3];
  const cplx* nzrow = NZ + (size_t)(row>>1)*NSAMP;
  int compIm = row & 1;
  cplx* Crow = C + (size_t)blockIdx.x*NFFT2;
  for (int i=0;i<128;i++){
    int t = t0+i;
    float cc = fminf(fmaxf((t+0.5f)*(1.0f/256.0f)-0.5f,0.0f),127.0f);
    int lo=(int)cc; float w=cc-lo; int hi=min(lo+1,NFRM-1);
    float f0t = MINF + (f0a[lo]*(1.0f-w)+f0a[hi]*w)*FSPAN;
    phi += (double)f0t;
    float resv = 0.0f;
    #pragma unroll
    for (int h=0; h<8; h++){
      double ph = phi*(double)fac_s[h];
      ph -= floor(ph*0.5)*2.0;           // phase mod 2 (units of pi)
      float mg = pw[h][lo]*(1.0f-w)+pw[h][hi]*w;
      resv += sinf((float)ph * 3.14159265358979f) * ampf_s[h] * mg;
    }
    float z = ((float)t - mu)/sigma;
    float prb = pscale*expf(-0.5f*z*z);
    cplx nzv = nzrow[t];
    float nzval = compIm ? nzv.y : nzv.x;
    float fev = fe[lo]*(1.0f-w)+fe[hi]*w;
    Crow[t] = make_float2(prb*nzval*amp*fev, resv);
    Crow[t+NSAMP] = make_float2(0.f,0.f);
  }
}

// ---------------- spectral product, sum events, pack batch pairs, x(1/M) ----------------
__global__ void k_combine(const cplx* __restrict__ C, cplx* __restrict__ D, int bpc, int paired, int total){
  int i = blockIdx.x*blockDim.x + threadIdx.x;
  if (i >= total) return;
  int j = i >> 16; int k = i & (NFFT2-1);
  int km = (NFFT2 - k) & (NFFT2-1);
  const float scale = 1.0f/65536.0f;
  float Wx = 0.f, Wy = 0.f;
  int nb = paired ? 2 : 1;
  for (int bb=0; bb<nb; bb++){
    int bLocal = paired ? (2*j+bb) : j;
    float Px = 0.f, Py = 0.f;
    const cplx* Cb = C + (size_t)bLocal*8*NFFT2;
    for (int e=0;e<8;e++){
      cplx Z  = Cb[(size_t)e*NFFT2 + k];
      cplx Zc = Cb[(size_t)e*NFFT2 + km];
      cplx Z2  = cmul_(Z,Z);
      cplx Zc2 = cmul_(Zc,Zc);
      float dx = Z2.x - Zc2.x;          // Z^2 - conj(Zc^2)
      float dy = Z2.y + Zc2.y;
      Px += 0.25f*dy;  Py += -0.25f*dx; // * (-i/4)
    }
    if (bb==0){ Wx += Px*scale; Wy += Py*scale; }
    else      { Wx += -Py*scale; Wy += Px*scale; } // + i*P
  }
  D[i] = make_float2(Wx, Wy);
}

// ---------------- unpack + write output ----------------
__global__ void k_output(const cplx* __restrict__ F, float* __restrict__ out, int bBase, int paired, int total){
  int i = blockIdx.x*blockDim.x + threadIdx.x;
  if (i >= total) return;
  int bl = i >> 15; int t = i & (NSAMP-1);
  float v;
  if (paired){
    int j = bl >> 1; int comp = bl & 1;
    cplx z = F[(size_t)j*NFFT2 + t];
    v = comp ? z.y : z.x;
  } else {
    v = F[(size_t)bl*NFFT2 + t].x;
  }
  out[(size_t)(bBase+bl)*NSAMP + t] = v;
}

// ---------------- host ----------------
template<int R, bool INV>
static void launchPass(const cplx* src, cplx* dst, int N, int s, int nsig, hipStream_t stream){
  int perSig = N/R;
  int logPerSig = __builtin_ctz(perSig);
  int logS = __builtin_ctz(s);
  int total = nsig*perSig;
  float tb = (INV?2.0f:-2.0f)*3.14159265358979323846f*(float)s/(float)N;
  k_fft_pass<R,INV><<<(total+255)/256, 256, 0, stream>>>(src, dst, logPerSig, logS, N, tb, total);
}

extern "C" void kernel_launch(void* const* d_in, const int* in_sizes, int n_in,
                              void* d_out, int out_size, void* d_ws, size_t ws_size,
                              hipStream_t stream){
  const float* x = (const float*)d_in[0];
  const float* noise = (const float*)d_in[1];
  float* out = (float*)d_out;
  char* ws = (char*)d_ws;

  const size_t oA = (size_t)1<<20;                       // params below 1 MiB
  const size_t szN = (size_t)64*NSAMP*sizeof(cplx);      // 16 MiB
  const size_t oB = oA + szN;
  const size_t oC = oB + szN;

  // choose number of batch chunks so 2 conv buffers fit
  const int cand[5] = {1,2,4,8,16};
  int nchunk = -1;
  for (int ci=0; ci<5; ci++){
    size_t csz = ((size_t)(128/cand[ci]))*NFFT2*sizeof(cplx);
    if (oC + 2*csz <= ws_size){ nchunk = cand[ci]; break; }
  }
  if (nchunk < 0) return; // workspace too small; leave output (graceful fail)

  int sigPerChunk = 128/nchunk;
  size_t csz = (size_t)sigPerChunk*NFFT2*sizeof(cplx);
  size_t oD = oC + csz;

  float* P = (float*)(ws);
  cplx* A = (cplx*)(ws + oA);
  cplx* B = (cplx*)(ws + oB);
  cplx* C = (cplx*)(ws + oC);
  cplx* D = (cplx*)(ws + oD);

  k_params<<<128, 64, 0, stream>>>(x, P);
  {
    int total = 64*NSAMP;
    k_pack_noise<<<(total+255)/256, 256, 0, stream>>>(noise, A);
  }
  // noise forward: 32768 = 8^5
  {
    cplx *src=A, *dst=B; int s=1;
    for (int pass=0; pass<5; pass++){
      launchPass<8,false>(src, dst, NSAMP, s, 64, stream);
      cplx* t=src; src=dst; dst=t; s*=8;
    }
    // result in B
  }
  {
    int total = 64*NSAMP;
    k_filter<<<(total+255)/256, 256, 0, stream>>>(B, A, P);
  }
  // noise inverse
  {
    cplx *src=A, *dst=B; int s=1;
    for (int pass=0; pass<5; pass++){
      launchPass<8,true>(src, dst, NSAMP, s, 64, stream);
      cplx* t=src; src=dst; dst=t; s*=8;
    }
    // result (nz pairs) in B
  }
  int bpc = sigPerChunk/8;
  int paired = (bpc >= 2) ? 1 : 0;
  int npair = paired ? bpc/2 : bpc;
  for (int c=0; c<nchunk; c++){
    int rowBase = c*sigPerChunk;
    k_build<<<sigPerChunk, 256, 0, stream>>>(P, B, C, rowBase);
    // conv forward: 65536 = 8^5 * 2
    {
      cplx *src=C, *dst=D; int s=1;
      for (int pass=0; pass<5; pass++){
        launchPass<8,false>(src, dst, NFFT2, s, sigPerChunk, stream);
        cplx* t=src; src=dst; dst=t; s*=8;
      }
      launchPass<2,false>(src, dst, NFFT2, s, sigPerChunk, stream);
      // after 6 passes result back in C
    }
    {
      int total = npair*NFFT2;
      k_combine<<<(total+255)/256, 256, 0, stream>>>(C, D, bpc, paired, total);
    }
    // conv inverse on npair signals: D <-> C, result ends in D
    {
      cplx *src=D, *dst=C; int s=1;
      for (int pass=0; pass<5; pass++){
        launchPass<8,true>(src, dst, NFFT2, s, npair, stream);
        cplx* t=src; src=dst; dst=t; s*=8;
      }
      launchPass<2,true>(src, dst, NFFT2, s, npair, stream);
      // result in D
    }
    {
      int total = bpc*NSAMP;
      k_output<<<(total+255)/256, 256, 0, stream>>>(D, out, c*bpc, paired, total);
    }
  }
}

// Round 2
// 364.389 us; speedup vs baseline: 1.2546x; 1.2546x over previous
//
#include <hip/hip_runtime.h>
#include <math.h>

#define NSAMP 32768
#define NFFT2 65536
#define NFRM 128
#define PSTRIDE 320
#define SPLITS 16

typedef float2 cplx;

__device__ __forceinline__ cplx cmul_(cplx a, cplx b){ return make_float2(a.x*b.x - a.y*b.y, a.x*b.y + a.y*b.x); }
__device__ __forceinline__ cplx cadd_(cplx a, cplx b){ return make_float2(a.x+b.x, a.y+b.y); }
__device__ __forceinline__ cplx csub_(cplx a, cplx b){ return make_float2(a.x-b.x, a.y-b.y); }

template<bool INV>
__device__ __forceinline__ void dft4_(cplx x0,cplx x1,cplx x2,cplx x3, cplx&y0,cplx&y1,cplx&y2,cplx&y3){
  cplx t0=cadd_(x0,x2), t1=csub_(x0,x2), t2=cadd_(x1,x3), t3=csub_(x1,x3);
  y0=cadd_(t0,t2); y2=csub_(t0,t2);
  cplx it3 = make_float2(-t3.y, t3.x);
  if (INV){ y1=cadd_(t1,it3); y3=csub_(t1,it3); }
  else    { y1=csub_(t1,it3); y3=cadd_(t1,it3); }
}

template<bool INV>
__device__ __forceinline__ void dft8_(const cplx* a, cplx* b){
  cplx e0,e1,e2,e3,o0,o1,o2,o3;
  dft4_<INV>(a[0],a[2],a[4],a[6], e0,e1,e2,e3);
  dft4_<INV>(a[1],a[3],a[5],a[7], o0,o1,o2,o3);
  const float r = 0.70710678118654752440f;
  cplx w1 = INV ? make_float2(r, r)    : make_float2(r,-r);
  cplx w2 = INV ? make_float2(0.f,1.f) : make_float2(0.f,-1.f);
  cplx w3 = INV ? make_float2(-r,r)    : make_float2(-r,-r);
  cplx t1 = cmul_(o1,w1), t2 = cmul_(o2,w2), t3 = cmul_(o3,w3);
  b[0]=cadd_(e0,o0); b[4]=csub_(e0,o0);
  b[1]=cadd_(e1,t1); b[5]=csub_(e1,t1);
  b[2]=cadd_(e2,t2); b[6]=csub_(e2,t2);
  b[3]=cadd_(e3,t3); b[7]=csub_(e3,t3);
}

// ---------------- Stockham mixed-radix pass ----------------
template<int R, bool INV>
__global__ __launch_bounds__(256) void k_fft_pass(const cplx* __restrict__ src, cplx* __restrict__ dst,
    int logPerSig, int logS, int N, float thetaBase, int total){
  int idx = blockIdx.x*blockDim.x + threadIdx.x;
  if (idx >= total) return;
  int perSig = 1<<logPerSig;
  int sig = idx >> logPerSig;
  int tau = idx & (perSig-1);
  int p = tau >> logS;
  int q = tau & ((1<<logS)-1);
  size_t base = (size_t)sig * (size_t)N;
  const cplx* sb = src + base;
  cplx* db = dst + base;
  cplx a[R], b[R];
  #pragma unroll
  for (int r=0;r<R;r++) a[r] = sb[tau + r*perSig];
  if constexpr (R==8) dft8_<INV>(a,b);
  else { b[0]=cadd_(a[0],a[1]); b[1]=csub_(a[0],a[1]); }
  float theta = thetaBase*(float)p;
  float sn, cs; sincosf(theta, &sn, &cs);
  cplx w = make_float2(cs, sn), wu = w;
  int ob = q + ((p<<logS)*R);
  db[ob] = b[0];
  #pragma unroll
  for (int u=1;u<R;u++){ db[ob + (u<<logS)] = cmul_(b[u], wu); wu = cmul_(wu, w); }
}

// ---------------- parameter extraction ----------------
__global__ void k_params(const float* __restrict__ x, float* __restrict__ P){
  int row = blockIdx.x; int tid = threadIdx.x;
  const float* xr = x + row*428;
  float* Pr = P + row*PSTRIDE;
  __shared__ float sx[428];
  for (int i = tid; i < 428; i += 64) sx[i] = 1.0f/(1.0f+expf(-xr[i]));
  __syncthreads();
  if (tid == 0){
    float mean = sx[0]; float stds = sx[1]*0.1f; float amp = sx[2]*sx[2];
    float f0 = sx[3]*sx[3];
    float mu = fminf(fmaxf(mean*32768.0f, -16384.0f), 49152.0f);
    float sigma = fminf(fmaxf((1e-8f + stds)*32768.0f, 0.0f), 32767.0f);
    float c = 1.0f/(sigma*2.5066282746310002f);
    float tt0 = fminf(fmaxf(floorf(mu), 0.0f), 32767.0f);
    float tt1 = fminf(fmaxf(ceilf(mu), 0.0f), 32767.0f);
    float z0 = (tt0-mu)/sigma, z1=(tt1-mu)/sigma;
    float gmax = fmaxf(expf(-0.5f*z0*z0), expf(-0.5f*z1*z1));
    float pscale = c / (c*gmax + 1e-12f);
    Pr[0]=mu; Pr[1]=sigma; Pr[2]=amp; Pr[3]=pscale;
    Pr[4] = 1.0f;
    for (int h=1;h<8;h++) Pr[4+h] = 1.0f + sx[4+h]*7.0f;
    for (int h=0;h<8;h++){ float m = sx[12+h]*0.9999f; Pr[12+h] = m*m; }
    for (int h=0;h<8;h++) Pr[20+h] = sx[164+h]*sx[164+h];
    for (int i=0;i<16;i++) Pr[28+i] = sx[20+i];
    float acc = 0.0f;
    for (int f=0; f<NFRM; f++){ acc += sx[36+f]*2.0f - 1.0f; Pr[64+f] = fminf(fmaxf(acc,0.0f),1.0f); }
    for (int f=0; f<NFRM; f++){ float var = sx[172+f]*(f0*0.01f); Pr[192+f] = f0 + var; }
  }
}

// ---------------- pack noise pairs ----------------
__global__ void k_pack_noise(const float* __restrict__ noise, cplx* __restrict__ A){
  int i = blockIdx.x*blockDim.x + threadIdx.x;
  if (i >= 64*NSAMP) return;
  int j = i >> 15; int t = i & (NSAMP-1);
  float re = noise[(size_t)(2*j)*NSAMP + t]*2.0f - 1.0f;
  float im = noise[(size_t)(2*j+1)*NSAMP + t]*2.0f - 1.0f;
  A[i] = make_float2(re, im);
}

// ---------------- spectral filter + repack for inverse, x(1/N) ----------------
__global__ void k_filter(const cplx* __restrict__ Zb, cplx* __restrict__ Ab, const float* __restrict__ P){
  int i = blockIdx.x*blockDim.x + threadIdx.x;
  if (i >= 64*NSAMP) return;
  int j = i >> 15; int k = i & (NSAMP-1);
  cplx Z = Zb[i];
  cplx Zc = Zb[(j<<15) + ((NSAMP - k) & (NSAMP-1))];
  cplx U1 = make_float2(0.5f*(Z.x + Zc.x), 0.5f*(Z.y - Zc.y));
  cplx U2 = make_float2(0.5f*(Z.y + Zc.y), -0.5f*(Z.x - Zc.x));
  int kb = (k <= NSAMP/2) ? k : (NSAMP - k);
  float coords = (kb + 0.5f)*(16.0f/16385.0f) - 0.5f;
  coords = fminf(fmaxf(coords, 0.0f), 15.0f);
  int lo = (int)coords; float w = coords - lo; int hi = min(lo+1, 15);
  const float* c1 = P + (size_t)(2*j)*PSTRIDE + 28;
  const float* c2 = c1 + PSTRIDE;
  float s1 = c1[lo]*(1.0f-w) + c1[hi]*w;
  float s2 = c2[lo]*(1.0f-w) + c2[hi]*w;
  const float scale = 1.0f/32768.0f;
  float S1x = U1.x*s1*scale, S1y = U1.y*s1*scale;
  float S2x = U2.x*s2*scale, S2y = U2.y*s2*scale;
  Ab[i] = make_float2(S1x - S2y, S1y + S2x);
}

// ---------------- build atoms (re) + res (im), coalesced, closed-form phase ----------------
// grid: (SPLITS, sigPerChunk); block handles NSAMP/SPLITS = 2048 samples of one row.
__global__ __launch_bounds__(256) void k_build(const float* __restrict__ P,
    const cplx* __restrict__ NZ, cplx* __restrict__ Cbuf, int rowBase){
  int row = rowBase + blockIdx.y;
  int split = blockIdx.x;
  int tid = threadIdx.x;
  const float* Pr = P + (size_t)row*PSTRIDE;
  __shared__ float fe[NFRM], f0a[NFRM];
  __shared__ float pw[8][NFRM];
  __shared__ double Cc[NFRM];
  __shared__ float fac_s[8], ampf_s[8], sc[4];
  if (tid < NFRM){ fe[tid]=Pr[64+tid]; f0a[tid]=Pr[192+tid]; }
  if (tid < 8){ fac_s[tid]=Pr[4+tid]; ampf_s[tid]=Pr[20+tid]; }
  if (tid >= 16 && tid < 20) sc[tid-16] = Pr[tid-16];
  __syncthreads();
  if (tid < 8){
    float m = Pr[12+tid], acc = m;
    pw[tid][0]=acc;
    for (int f=1; f<NFRM; f++){ acc*=m; pw[tid][f]=acc; }
  }
  if (tid == 255){
    // inclusive raw-f0 cumsum at segment starts:
    // Cc[k] = sum of raw f0t over [0, 128+256k)
    double acc = 128.0*(double)f0a[0];
    Cc[0] = acc;
    for (int k=0;k<127;k++){ acc += 128.0*((double)f0a[k]+(double)f0a[k+1]); Cc[k+1]=acc; }
  }
  __syncthreads();
  const double MINF_D  = 20.0/11025.0;
  const double FSPAN_D = 2980.0/11025.0;
  float mu=sc[0], sigma=sc[1], amp=sc[2], pscale=sc[3];
  const cplx* nzrow = NZ + (size_t)(row>>1)*NSAMP;
  int compIm = row & 1;
  cplx* Crow = Cbuf + (size_t)blockIdx.y*NFFT2;
  int base = split*(NSAMP/SPLITS);
  for (int m=0;m<(NSAMP/SPLITS)/256;m++){
    int t = base + m*256 + tid;
    float cc = fminf(fmaxf((t+0.5f)*(1.0f/256.0f)-0.5f,0.0f),127.0f);
    int lo=(int)cc; float w=cc-lo; int hi=min(lo+1,NFRM-1);
    // closed-form inclusive cumsum of raw f0t (piecewise-linear arithmetic series)
    double rawcum;
    if (t < 128){
      rawcum = (double)(t+1)*(double)f0a[0];
    } else {
      int k = (t-128)>>8; int n = (t-128-(k<<8)) + 1;
      if (k < 127){
        double d = (double)f0a[k+1]-(double)f0a[k];
        rawcum = Cc[k] + (double)n*(double)f0a[k] + d*((double)n*(double)n)*(1.0/512.0);
      } else {
        rawcum = Cc[127] + (double)n*(double)f0a[127];
      }
    }
    double phi = (double)(t+1)*MINF_D + FSPAN_D*rawcum;  // units of pi
    float resv = 0.0f;
    #pragma unroll
    for (int h=0; h<8; h++){
      double ph = phi*(double)fac_s[h];
      ph -= floor(ph*0.5)*2.0;           // phase mod 2 (units of pi)
      float mg = pw[h][lo]*(1.0f-w)+pw[h][hi]*w;
      resv += sinf((float)ph * 3.14159265358979f) * ampf_s[h] * mg;
    }
    float z = ((float)t - mu)/sigma;
    float prb = pscale*expf(-0.5f*z*z);
    cplx nzv = nzrow[t];
    float nzval = compIm ? nzv.y : nzv.x;
    float fev = fe[lo]*(1.0f-w)+fe[hi]*w;
    Crow[t] = make_float2(prb*nzval*amp*fev, resv);
    Crow[t+NSAMP] = make_float2(0.f,0.f);
  }
}

// ---------------- spectral product, sum events, pack batch pairs, x(1/M) ----------------
__global__ void k_combine(const cplx* __restrict__ C, cplx* __restrict__ D, int bpc, int paired, int total){
  int i = blockIdx.x*blockDim.x + threadIdx.x;
  if (i >= total) return;
  int j = i >> 16; int k = i & (NFFT2-1);
  int km = (NFFT2 - k) & (NFFT2-1);
  const float scale = 1.0f/65536.0f;
  float Wx = 0.f, Wy = 0.f;
  int nb = paired ? 2 : 1;
  for (int bb=0; bb<nb; bb++){
    int bLocal = paired ? (2*j+bb) : j;
    float Px = 0.f, Py = 0.f;
    const cplx* Cb = C + (size_t)bLocal*8*NFFT2;
    for (int e=0;e<8;e++){
      cplx Z  = Cb[(size_t)e*NFFT2 + k];
      cplx Zc = Cb[(size_t)e*NFFT2 + km];
      cplx Z2  = cmul_(Z,Z);
      cplx Zc2 = cmul_(Zc,Zc);
      float dx = Z2.x - Zc2.x;
      float dy = Z2.y + Zc2.y;
      Px += 0.25f*dy;  Py += -0.25f*dx;
    }
    if (bb==0){ Wx += Px*scale; Wy += Py*scale; }
    else      { Wx += -Py*scale; Wy += Px*scale; }
  }
  D[i] = make_float2(Wx, Wy);
}

// ---------------- unpack + write output ----------------
__global__ void k_output(const cplx* __restrict__ F, float* __restrict__ out, int bBase, int paired, int total){
  int i = blockIdx.x*blockDim.x + threadIdx.x;
  if (i >= total) return;
  int bl = i >> 15; int t = i & (NSAMP-1);
  float v;
  if (paired){
    int j = bl >> 1; int comp = bl & 1;
    cplx z = F[(size_t)j*NFFT2 + t];
    v = comp ? z.y : z.x;
  } else {
    v = F[(size_t)bl*NFFT2 + t].x;
  }
  out[(size_t)(bBase+bl)*NSAMP + t] = v;
}

// ---------------- host ----------------
template<int R, bool INV>
static void launchPass(const cplx* src, cplx* dst, int N, int s, int nsig, hipStream_t stream){
  int perSig = N/R;
  int logPerSig = __builtin_ctz(perSig);
  int logS = __builtin_ctz(s);
  int total = nsig*perSig;
  float tb = (INV?2.0f:-2.0f)*3.14159265358979323846f*(float)s/(float)N;
  k_fft_pass<R,INV><<<(total+255)/256, 256, 0, stream>>>(src, dst, logPerSig, logS, N, tb, total);
}

extern "C" void kernel_launch(void* const* d_in, const int* in_sizes, int n_in,
                              void* d_out, int out_size, void* d_ws, size_t ws_size,
                              hipStream_t stream){
  const float* x = (const float*)d_in[0];
  const float* noise = (const float*)d_in[1];
  float* out = (float*)d_out;
  char* ws = (char*)d_ws;

  const size_t oA = (size_t)1<<20;
  const size_t szN = (size_t)64*NSAMP*sizeof(cplx);
  const size_t oB = oA + szN;
  const size_t oC = oB + szN;

  const int cand[5] = {1,2,4,8,16};
  int nchunk = -1;
  for (int ci=0; ci<5; ci++){
    size_t csz = ((size_t)(128/cand[ci]))*NFFT2*sizeof(cplx);
    if (oC + 2*csz <= ws_size){ nchunk = cand[ci]; break; }
  }
  if (nchunk < 0) return;

  int sigPerChunk = 128/nchunk;
  size_t csz = (size_t)sigPerChunk*NFFT2*sizeof(cplx);
  size_t oD = oC + csz;

  float* P = (float*)(ws);
  cplx* A = (cplx*)(ws + oA);
  cplx* B = (cplx*)(ws + oB);
  cplx* C = (cplx*)(ws + oC);
  cplx* D = (cplx*)(ws + oD);

  k_params<<<128, 64, 0, stream>>>(x, P);
  {
    int total = 64*NSAMP;
    k_pack_noise<<<(total+255)/256, 256, 0, stream>>>(noise, A);
  }
  {
    cplx *src=A, *dst=B; int s=1;
    for (int pass=0; pass<5; pass++){
      launchPass<8,false>(src, dst, NSAMP, s, 64, stream);
      cplx* t=src; src=dst; dst=t; s*=8;
    }
  }
  {
    int total = 64*NSAMP;
    k_filter<<<(total+255)/256, 256, 0, stream>>>(B, A, P);
  }
  {
    cplx *src=A, *dst=B; int s=1;
    for (int pass=0; pass<5; pass++){
      launchPass<8,true>(src, dst, NSAMP, s, 64, stream);
      cplx* t=src; src=dst; dst=t; s*=8;
    }
  }
  int bpc = sigPerChunk/8;
  int paired = (bpc >= 2) ? 1 : 0;
  int npair = paired ? bpc/2 : bpc;
  for (int c=0; c<nchunk; c++){
    int rowBase = c*sigPerChunk;
    k_build<<<dim3(SPLITS, sigPerChunk), 256, 0, stream>>>(P, B, C, rowBase);
    {
      cplx *src=C, *dst=D; int s=1;
      for (int pass=0; pass<5; pass++){
        launchPass<8,false>(src, dst, NFFT2, s, sigPerChunk, stream);
        cplx* t=src; src=dst; dst=t; s*=8;
      }
      launchPass<2,false>(src, dst, NFFT2, s, sigPerChunk, stream);
    }
    {
      int total = npair*NFFT2;
      k_combine<<<(total+255)/256, 256, 0, stream>>>(C, D, bpc, paired, total);
    }
    {
      cplx *src=D, *dst=C; int s=1;
      for (int pass=0; pass<5; pass++){
        launchPass<8,true>(src, dst, NFFT2, s, npair, stream);
        cplx* t=src; src=dst; dst=t; s*=8;
      }
      launchPass<2,true>(src, dst, NFFT2, s, npair, stream);
    }
    {
      int total = bpc*NSAMP;
      k_output<<<(total+255)/256, 256, 0, stream>>>(D, out, c*bpc, paired, total);
    }
  }
}

// Round 3
// 168.071 us; speedup vs baseline: 2.7201x; 2.1681x over previous
//
#include <hip/hip_runtime.h>
#include <math.h>

#define NSAMP 32768
#define NFFT2 65536
#define NFRM 128
#define PSTRIDE 576
#define TWO_PI_F 6.28318530717958647692f

typedef float2 cplx;

__device__ __forceinline__ cplx cmul_(cplx a, cplx b){ return make_float2(a.x*b.x - a.y*b.y, a.x*b.y + a.y*b.x); }
__device__ __forceinline__ cplx cadd_(cplx a, cplx b){ return make_float2(a.x+b.x, a.y+b.y); }
__device__ __forceinline__ cplx csub_(cplx a, cplx b){ return make_float2(a.x-b.x, a.y-b.y); }

template<bool INV>
__device__ __forceinline__ void dft4_(cplx x0,cplx x1,cplx x2,cplx x3, cplx&y0,cplx&y1,cplx&y2,cplx&y3){
  cplx t0=cadd_(x0,x2), t1=csub_(x0,x2), t2=cadd_(x1,x3), t3=csub_(x1,x3);
  y0=cadd_(t0,t2); y2=csub_(t0,t2);
  cplx it3 = make_float2(-t3.y, t3.x);
  if (INV){ y1=cadd_(t1,it3); y3=csub_(t1,it3); }
  else    { y1=csub_(t1,it3); y3=cadd_(t1,it3); }
}

template<bool INV>
__device__ __forceinline__ void dft8_(const cplx* a, cplx* b){
  cplx e0,e1,e2,e3,o0,o1,o2,o3;
  dft4_<INV>(a[0],a[2],a[4],a[6], e0,e1,e2,e3);
  dft4_<INV>(a[1],a[3],a[5],a[7], o0,o1,o2,o3);
  const float r = 0.70710678118654752440f;
  cplx w1 = INV ? make_float2(r, r)    : make_float2(r,-r);
  cplx w2 = INV ? make_float2(0.f,1.f) : make_float2(0.f,-1.f);
  cplx w3 = INV ? make_float2(-r,r)    : make_float2(-r,-r);
  cplx t1 = cmul_(o1,w1), t2 = cmul_(o2,w2), t3 = cmul_(o3,w3);
  b[0]=cadd_(e0,o0); b[4]=csub_(e0,o0);
  b[1]=cadd_(e1,t1); b[5]=csub_(e1,t1);
  b[2]=cadd_(e2,t2); b[6]=csub_(e2,t2);
  b[3]=cadd_(e3,t3); b[7]=csub_(e3,t3);
}

template<bool INV>
__device__ __forceinline__ void dft8ip_(cplx* v){
  cplx b[8];
  dft8_<INV>(v, b);
  #pragma unroll
  for (int i=0;i<8;i++) v[i] = b[i];
}

// 16-point DFT in place: v[k] = sum_n W16^{+/- nk} v[n]
template<bool INV>
__device__ __forceinline__ void dft16ip_(cplx* v){
  cplx t0[4], t1[4], t2[4], t3[4];
  dft4_<INV>(v[0], v[4], v[8],  v[12], t0[0],t0[1],t0[2],t0[3]);
  dft4_<INV>(v[1], v[5], v[9],  v[13], t1[0],t1[1],t1[2],t1[3]);
  dft4_<INV>(v[2], v[6], v[10], v[14], t2[0],t2[1],t2[2],t2[3]);
  dft4_<INV>(v[3], v[7], v[11], v[15], t3[0],t3[1],t3[2],t3[3]);
  const float C1=0.92387953251128675613f, S1=0.38268343236508977172f, R2=0.70710678118654752440f;
  #define TWD_(x, cc, ss) (INV ? cmul_((x), make_float2((cc), (ss))) : cmul_((x), make_float2((cc), -(ss))))
  t1[1] = TWD_(t1[1], C1, S1);    // W^1
  t1[2] = TWD_(t1[2], R2, R2);    // W^2
  t1[3] = TWD_(t1[3], S1, C1);    // W^3
  t2[1] = TWD_(t2[1], R2, R2);    // W^2
  t2[2] = TWD_(t2[2], 0.f, 1.f);  // W^4
  t2[3] = TWD_(t2[3], -R2, R2);   // W^6
  t3[1] = TWD_(t3[1], S1, C1);    // W^3
  t3[2] = TWD_(t3[2], -R2, R2);   // W^6
  t3[3] = TWD_(t3[3], -C1, -S1);  // W^9
  #undef TWD_
  dft4_<INV>(t0[0], t1[0], t2[0], t3[0], v[0], v[4], v[8],  v[12]);
  dft4_<INV>(t0[1], t1[1], t2[1], t3[1], v[1], v[5], v[9],  v[13]);
  dft4_<INV>(t0[2], t1[2], t2[2], t3[2], v[2], v[6], v[10], v[14]);
  dft4_<INV>(t0[3], t1[3], t2[3], t3[3], v[3], v[7], v[11], v[15]);
}

// ---------------- LDS-fused radix-R0 Stockham pass ----------------
// pass1 (!FINALPASS, s=1): loads src[tau + r*perSig], R0-pt DFT, *W_N^{tau*u}, stores dst[R0*tau + u]
// final  (FINALPASS, s=perSig): loads same, R0-pt DFT, stores dst[tau + perSig*u]
// 16 groups (tau = tBase..tBase+15) per block, 256 threads.
template<int R0, bool INV, bool LOADHALF, bool FINALPASS>
__global__ __launch_bounds__(256) void k_fft_block(const cplx* __restrict__ src, cplx* __restrict__ dst,
    int perSig, int blocksPerSig, float interBase){
  constexpr int Q = R0/16;
  constexpr int S1 = R0 + 8;
  constexpr int LSZ = (R0*17 > 16*S1) ? R0*17 : 16*S1;
  __shared__ float lre[LSZ], lim[LSZ];
  int t = threadIdx.x;
  int bx = blockIdx.x;
  int sig = bx / blocksPerSig;
  int tBase = (bx - sig*blocksPerSig) * 16;
  const size_t N = (size_t)R0 * (size_t)perSig;
  const cplx* sb = src + (size_t)sig * N;
  cplx* db = dst + (size_t)sig * N;
  // coalesced load -> LDS [g][r]
  #pragma unroll
  for (int i=0;i<R0/16;i++){
    int e = t + 256*i;
    int g = e & 15, r = e >> 4;
    float xre = 0.f, xim = 0.f;
    if (!LOADHALF || r < R0/2){
      cplx vv = sb[tBase + g + (size_t)r*perSig];
      xre = vv.x; xim = vv.y;
    }
    lre[g*S1 + r] = xre; lim[g*S1 + r] = xim;
  }
  __syncthreads();
  // stage 1: Q-pt DFT over bb (r = a + 16*bb), thread (g,a)
  int g = t >> 4, a = t & 15;
  cplx v[Q];
  #pragma unroll
  for (int bb=0;bb<Q;bb++){
    int idx = g*S1 + a + 16*bb;
    v[bb] = make_float2(lre[idx], lim[idx]);
  }
  if constexpr (Q==16) dft16ip_<INV>(v); else dft8ip_<INV>(v);
  {
    // intra twiddle W_R0^{a*c}
    float th = (INV ? TWO_PI_F : -TWO_PI_F) * (float)a / (float)R0;
    float sn, cs; __sincosf(th, &sn, &cs);
    cplx w1 = make_float2(cs, sn), wu = w1;
    #pragma unroll
    for (int c=1;c<Q;c++){ v[c] = cmul_(v[c], wu); wu = cmul_(wu, w1); }
  }
  __syncthreads();
  // transposed store with rotation swizzle
  #pragma unroll
  for (int c=0;c<Q;c++){
    int m = a*Q + ((c + a) & (Q-1));
    lre[g*S1 + m] = v[c].x; lim[g*S1 + m] = v[c].y;
  }
  __syncthreads();
  // stage 2: 16-pt DFT over a, thread (g2,c2)
  bool active = (R0 == 256) || (t < 128);
  int g2 = (R0==256) ? (t>>4) : (t>>3);
  int c2 = (R0==256) ? (t&15) : (t&7);
  cplx z[16];
  if (active){
    #pragma unroll
    for (int a2=0;a2<16;a2++){
      int m = a2*Q + ((c2 + a2) & (Q-1));
      z[a2] = make_float2(lre[g2*S1 + m], lim[g2*S1 + m]);
    }
    dft16ip_<INV>(z);
  }
  if constexpr (!FINALPASS){
    if (active){
      int p = tBase + g2;
      float thp = interBase * (float)p;
      float snc, csc; __sincosf(thp * (float)c2, &snc, &csc);
      float sns, css; __sincosf(thp * (float)Q,  &sns, &css);
      cplx wu = make_float2(csc, snc), ws = make_float2(css, sns);
      size_t ob = (size_t)R0 * (size_t)p + (size_t)c2;
      #pragma unroll
      for (int d=0; d<16; d++){
        db[ob + (size_t)(d*Q)] = cmul_(z[d], wu);
        wu = cmul_(wu, ws);
      }
    }
  } else {
    __syncthreads();
    if (active){
      #pragma unroll
      for (int d=0;d<16;d++){
        int u = c2 + Q*d;
        lre[u*17 + g2] = z[d].x; lim[u*17 + g2] = z[d].y;
      }
    }
    __syncthreads();
    #pragma unroll
    for (int i=0;i<R0/16;i++){
      int e = t + 256*i;
      int g3 = e & 15, u = e >> 4;
      db[tBase + g3 + (size_t)u*perSig] = make_float2(lre[u*17+g3], lim[u*17+g3]);
    }
  }
}

// ---------------- parameter extraction (+ per-row double cumsum) ----------------
__global__ void k_params(const float* __restrict__ x, float* __restrict__ P){
  int row = blockIdx.x; int tid = threadIdx.x;
  const float* xr = x + row*428;
  float* Pr = P + (size_t)row*PSTRIDE;
  __shared__ float sx[428];
  for (int i = tid; i < 428; i += 64) sx[i] = 1.0f/(1.0f+expf(-xr[i]));
  __syncthreads();
  if (tid == 0){
    float mean = sx[0]; float stds = sx[1]*0.1f; float amp = sx[2]*sx[2];
    float f0 = sx[3]*sx[3];
    float mu = fminf(fmaxf(mean*32768.0f, -16384.0f), 49152.0f);
    float sigma = fminf(fmaxf((1e-8f + stds)*32768.0f, 0.0f), 32767.0f);
    float c = 1.0f/(sigma*2.5066282746310002f);
    float tt0 = fminf(fmaxf(floorf(mu), 0.0f), 32767.0f);
    float tt1 = fminf(fmaxf(ceilf(mu), 0.0f), 32767.0f);
    float z0 = (tt0-mu)/sigma, z1=(tt1-mu)/sigma;
    float gmax = fmaxf(expf(-0.5f*z0*z0), expf(-0.5f*z1*z1));
    float pscale = c / (c*gmax + 1e-12f);
    Pr[0]=mu; Pr[1]=sigma; Pr[2]=amp; Pr[3]=pscale;
    Pr[4] = 1.0f;
    for (int h=1;h<8;h++) Pr[4+h] = 1.0f + sx[4+h]*7.0f;
    for (int h=0;h<8;h++){ float m = sx[12+h]*0.9999f; Pr[12+h] = m*m; }
    for (int h=0;h<8;h++) Pr[20+h] = sx[164+h]*sx[164+h];
    for (int i=0;i<16;i++) Pr[28+i] = sx[20+i];
    float acc = 0.0f;
    for (int f=0; f<NFRM; f++){ acc += sx[36+f]*2.0f - 1.0f; Pr[64+f] = fminf(fmaxf(acc,0.0f),1.0f); }
    for (int f=0; f<NFRM; f++){ float var = sx[172+f]*(f0*0.01f); Pr[192+f] = f0 + var; }
    // Cc[k] = raw-f0 cumsum over first 128+256k samples (double)
    double* Cd = (double*)(Pr + 320);
    double accd = 128.0*(double)Pr[192];
    Cd[0] = accd;
    for (int k=0;k<127;k++){ accd += 128.0*((double)Pr[192+k] + (double)Pr[192+k+1]); Cd[k+1] = accd; }
  }
}

// ---------------- pack noise pairs ----------------
__global__ void k_pack_noise(const float* __restrict__ noise, cplx* __restrict__ A){
  int i = blockIdx.x*blockDim.x + threadIdx.x;
  if (i >= 64*NSAMP) return;
  int j = i >> 15; int t = i & (NSAMP-1);
  float re = noise[(size_t)(2*j)*NSAMP + t]*2.0f - 1.0f;
  float im = noise[(size_t)(2*j+1)*NSAMP + t]*2.0f - 1.0f;
  A[i] = make_float2(re, im);
}

// ---------------- spectral filter + repack for inverse, x(1/N) ----------------
__global__ void k_filter(const cplx* __restrict__ Zb, cplx* __restrict__ Ab, const float* __restrict__ P){
  int i = blockIdx.x*blockDim.x + threadIdx.x;
  if (i >= 64*NSAMP) return;
  int j = i >> 15; int k = i & (NSAMP-1);
  cplx Z = Zb[i];
  cplx Zc = Zb[(j<<15) + ((NSAMP - k) & (NSAMP-1))];
  cplx U1 = make_float2(0.5f*(Z.x + Zc.x), 0.5f*(Z.y - Zc.y));
  cplx U2 = make_float2(0.5f*(Z.y + Zc.y), -0.5f*(Z.x - Zc.x));
  int kb = (k <= NSAMP/2) ? k : (NSAMP - k);
  float coords = (kb + 0.5f)*(16.0f/16385.0f) - 0.5f;
  coords = fminf(fmaxf(coords, 0.0f), 15.0f);
  int lo = (int)coords; float w = coords - lo; int hi = min(lo+1, 15);
  const float* c1 = P + (size_t)(2*j)*PSTRIDE + 28;
  const float* c2 = c1 + PSTRIDE;
  float s1 = c1[lo]*(1.0f-w) + c1[hi]*w;
  float s2 = c2[lo]*(1.0f-w) + c2[hi]*w;
  const float scale = 1.0f/32768.0f;
  float S1x = U1.x*s1*scale, S1y = U1.y*s1*scale;
  float S2x = U2.x*s2*scale, S2y = U2.y*s2*scale;
  Ab[i] = make_float2(S1x - S2y, S1y + S2x);
}

// ---------------- build atoms (re) + res (im); fp32 phase via per-segment anchors ----------------
__global__ __launch_bounds__(256) void k_build(const float* __restrict__ P,
    const cplx* __restrict__ NZ, cplx* __restrict__ Cbuf, int rowBase){
  int row = rowBase + blockIdx.y;
  int split = blockIdx.x;
  int tid = threadIdx.x;
  const float* Pr = P + (size_t)row*PSTRIDE;
  const double* Cd = (const double*)(Pr + 320);
  __shared__ float fe[NFRM], f0a[NFRM];
  __shared__ float pw2[8][NFRM];
  __shared__ float A2[9][8], L2[9][8], Q2[9][8];
  __shared__ float fac_s[8], sc[4];
  if (tid < NFRM){ fe[tid] = Pr[64+tid]; f0a[tid] = Pr[192+tid]; }
  if (tid < 8) fac_s[tid] = Pr[4+tid];
  if (tid >= 8 && tid < 12) sc[tid-8] = Pr[tid-8];
  __syncthreads();
  if (tid < 8){
    float m = Pr[12+tid], af = Pr[20+tid];
    float acc = m*af;
    pw2[tid][0] = acc;
    for (int f=1; f<NFRM; f++){ acc *= m; pw2[tid][f] = acc; }
  }
  int kbase = (split==0) ? -1 : (8*split - 1);
  if (tid < 72){
    int j = tid >> 3, h = tid & 7;
    const double MINF_D = 20.0/11025.0, FSPAN_D = 2980.0/11025.0;
    double fac = (double)fac_s[h];
    int k = kbase + j;
    double A, Lv, Qv;
    if (k < 0){
      A = 0.0;
      Lv = fac*(MINF_D + FSPAN_D*(double)f0a[0]);
      Qv = 0.0;
    } else if (k > 127){
      A = 0.0; Lv = 0.0; Qv = 0.0;
    } else {
      double phi0 = (double)(128 + 256*k)*MINF_D + FSPAN_D*Cd[k];
      A = fmod(fac*phi0, 2.0);
      double f0k = (double)f0a[k];
      double d = (k < 127) ? ((double)f0a[k+1] - f0k) : 0.0;
      Lv = fac*(MINF_D + FSPAN_D*f0k);
      Qv = fac*FSPAN_D*d*(1.0/512.0);
    }
    A2[j][h] = (float)(0.5*A);
    L2[j][h] = (float)(0.5*Lv);
    Q2[j][h] = (float)(0.5*Qv);
  }
  __syncthreads();
  float mu=sc[0], sigma=sc[1], amp=sc[2], pscale=sc[3];
  const cplx* nzrow = NZ + (size_t)(row>>1)*NSAMP;
  int compIm = row & 1;
  cplx* Crow = Cbuf + (size_t)blockIdx.y*NFFT2;
  int base = split*2048;
  #pragma unroll
  for (int m=0;m<8;m++){
    int t = base + m*256 + tid;
    float cc = fminf(fmaxf((t+0.5f)*(1.0f/256.0f)-0.5f,0.0f),127.0f);
    int lo=(int)cc; float w=cc-lo; int hi=min(lo+1,NFRM-1);
    int slot, n0;
    if (t < 128){ slot = 0; n0 = t + 1; }
    else { int km = (t-128)>>8; slot = km - kbase; n0 = t - (127 + 256*km); }
    float nf = (float)n0, nf2 = nf*nf;
    float resv = 0.0f;
    #pragma unroll
    for (int h=0; h<8; h++){
      float r = A2[slot][h] + nf*L2[slot][h] + nf2*Q2[slot][h]; // phase/2 in revolutions
      float fr = r - floorf(r);
      float s = __builtin_amdgcn_sinf(fr);   // sin(2*pi*fr) == sin(pi*phase)
      float mg = pw2[h][lo] + w*(pw2[h][hi]-pw2[h][lo]);
      resv += s*mg;
    }
    float z = ((float)t - mu)/sigma;
    float prb = pscale*__expf(-0.5f*z*z);
    cplx nzv = nzrow[t];
    float nzval = compIm ? nzv.y : nzv.x;
    float fev = fe[lo] + w*(fe[hi]-fe[lo]);
    Crow[t] = make_float2(prb*nzval*amp*fev, resv);
    // upper (zero) half intentionally not written; conv pass1 uses LOADHALF
  }
}

// ---------------- spectral product, sum events, pack batch pairs, x(1/M) ----------------
__global__ void k_combine(const cplx* __restrict__ C, cplx* __restrict__ D, int bpc, int paired, int total){
  int i = blockIdx.x*blockDim.x + threadIdx.x;
  if (i >= total) return;
  int j = i >> 16; int k = i & (NFFT2-1);
  int km = (NFFT2 - k) & (NFFT2-1);
  const float scale = 1.0f/65536.0f;
  float Wx = 0.f, Wy = 0.f;
  int nb = paired ? 2 : 1;
  for (int bb=0; bb<nb; bb++){
    int bLocal = paired ? (2*j+bb) : j;
    float Px = 0.f, Py = 0.f;
    const cplx* Cb = C + (size_t)bLocal*8*NFFT2;
    for (int e=0;e<8;e++){
      cplx Z  = Cb[(size_t)e*NFFT2 + k];
      cplx Zc = Cb[(size_t)e*NFFT2 + km];
      cplx Z2  = cmul_(Z,Z);
      cplx Zc2 = cmul_(Zc,Zc);
      float dx = Z2.x - Zc2.x;
      float dy = Z2.y + Zc2.y;
      Px += 0.25f*dy;  Py += -0.25f*dx;
    }
    if (bb==0){ Wx += Px*scale; Wy += Py*scale; }
    else      { Wx += -Py*scale; Wy += Px*scale; }
  }
  D[i] = make_float2(Wx, Wy);
}

// ---------------- unpack + write output ----------------
__global__ void k_output(const cplx* __restrict__ F, float* __restrict__ out, int bBase, int paired, int total){
  int i = blockIdx.x*blockDim.x + threadIdx.x;
  if (i >= total) return;
  int bl = i >> 15; int t = i & (NSAMP-1);
  float v;
  if (paired){
    int j = bl >> 1; int comp = bl & 1;
    cplx z = F[(size_t)j*NFFT2 + t];
    v = comp ? z.y : z.x;
  } else {
    v = F[(size_t)bl*NFFT2 + t].x;
  }
  out[(size_t)(bBase+bl)*NSAMP + t] = v;
}

// ---------------- host ----------------
extern "C" void kernel_launch(void* const* d_in, const int* in_sizes, int n_in,
                              void* d_out, int out_size, void* d_ws, size_t ws_size,
                              hipStream_t stream){
  const float* x = (const float*)d_in[0];
  const float* noise = (const float*)d_in[1];
  float* out = (float*)d_out;
  char* ws = (char*)d_ws;

  const size_t oA = (size_t)1<<20;
  const size_t szN = (size_t)64*NSAMP*sizeof(cplx);
  const size_t oB = oA + szN;
  const size_t oC = oB + szN;

  const int cand[5] = {1,2,4,8,16};
  int nchunk = -1;
  for (int ci=0; ci<5; ci++){
    size_t csz = ((size_t)(128/cand[ci]))*NFFT2*sizeof(cplx);
    if (oC + 2*csz <= ws_size){ nchunk = cand[ci]; break; }
  }
  if (nchunk < 0) return;

  int sigPerChunk = 128/nchunk;
  size_t csz = (size_t)sigPerChunk*NFFT2*sizeof(cplx);
  size_t oD = oC + csz;

  float* P = (float*)(ws);
  cplx* A = (cplx*)(ws + oA);
  cplx* B = (cplx*)(ws + oB);
  cplx* C = (cplx*)(ws + oC);
  cplx* D = (cplx*)(ws + oD);

  k_params<<<128, 64, 0, stream>>>(x, P);
  {
    int total = 64*NSAMP;
    k_pack_noise<<<(total+255)/256, 256, 0, stream>>>(noise, A);
  }
  // noise forward FFT (32768 = 256*128): A -> B -> A  (spectrum in A)
  k_fft_block<256,false,false,false><<<64*8,  256, 0, stream>>>(A, B, 128, 8,  -TWO_PI_F/32768.0f);
  k_fft_block<128,false,false,true ><<<64*16, 256, 0, stream>>>(B, A, 256, 16, 0.0f);
  {
    int total = 64*NSAMP;
    k_filter<<<(total+255)/256, 256, 0, stream>>>(A, B, P);
  }
  // noise inverse FFT: B -> A -> B  (nz in B)
  k_fft_block<256,true ,false,false><<<64*8,  256, 0, stream>>>(B, A, 128, 8,   TWO_PI_F/32768.0f);
  k_fft_block<128,true ,false,true ><<<64*16, 256, 0, stream>>>(A, B, 256, 16, 0.0f);

  int bpc = sigPerChunk/8;
  int paired = (bpc >= 2) ? 1 : 0;
  int npair = paired ? bpc/2 : bpc;
  for (int c=0; c<nchunk; c++){
    int rowBase = c*sigPerChunk;
    k_build<<<dim3(16, sigPerChunk), 256, 0, stream>>>(P, B, C, rowBase);
    // conv forward FFT (65536 = 256*256), zero upper half: C -> D -> C
    k_fft_block<256,false,true ,false><<<sigPerChunk*16, 256, 0, stream>>>(C, D, 256, 16, -TWO_PI_F/65536.0f);
    k_fft_block<256,false,false,true ><<<sigPerChunk*16, 256, 0, stream>>>(D, C, 256, 16, 0.0f);
    {
      int total = npair*NFFT2;
      k_combine<<<(total+255)/256, 256, 0, stream>>>(C, D, bpc, paired, total);
    }
    // conv inverse FFT: D -> C -> D
    k_fft_block<256,true ,false,false><<<npair*16, 256, 0, stream>>>(D, C, 256, 16,  TWO_PI_F/65536.0f);
    k_fft_block<256,true ,false,true ><<<npair*16, 256, 0, stream>>>(C, D, 256, 16, 0.0f);
    {
      int total = bpc*NSAMP;
      k_output<<<(total+255)/256, 256, 0, stream>>>(D, out, c*bpc, paired, total);
    }
  }
}

// Round 4
// 157.209 us; speedup vs baseline: 2.9080x; 1.0691x over previous
//
#include <hip/hip_runtime.h>
#include <math.h>

#define NSAMP 32768
#define NFFT2 65536
#define NFRM 128
#define PSTRIDE 576
#define TWO_PI_F 6.28318530717958647692f

typedef float2 cplx;

__device__ __forceinline__ cplx cmul_(cplx a, cplx b){ return make_float2(a.x*b.x - a.y*b.y, a.x*b.y + a.y*b.x); }
__device__ __forceinline__ cplx cadd_(cplx a, cplx b){ return make_float2(a.x+b.x, a.y+b.y); }
__device__ __forceinline__ cplx csub_(cplx a, cplx b){ return make_float2(a.x-b.x, a.y-b.y); }

template<bool INV>
__device__ __forceinline__ void dft4_(cplx x0,cplx x1,cplx x2,cplx x3, cplx&y0,cplx&y1,cplx&y2,cplx&y3){
  cplx t0=cadd_(x0,x2), t1=csub_(x0,x2), t2=cadd_(x1,x3), t3=csub_(x1,x3);
  y0=cadd_(t0,t2); y2=csub_(t0,t2);
  cplx it3 = make_float2(-t3.y, t3.x);
  if (INV){ y1=cadd_(t1,it3); y3=csub_(t1,it3); }
  else    { y1=csub_(t1,it3); y3=cadd_(t1,it3); }
}

template<bool INV>
__device__ __forceinline__ void dft8ip_(cplx* v){
  cplx e0,e1,e2,e3,o0,o1,o2,o3;
  dft4_<INV>(v[0],v[2],v[4],v[6], e0,e1,e2,e3);
  dft4_<INV>(v[1],v[3],v[5],v[7], o0,o1,o2,o3);
  const float r = 0.70710678118654752440f;
  cplx w1 = INV ? make_float2(r, r)    : make_float2(r,-r);
  cplx w2 = INV ? make_float2(0.f,1.f) : make_float2(0.f,-1.f);
  cplx w3 = INV ? make_float2(-r,r)    : make_float2(-r,-r);
  cplx t1 = cmul_(o1,w1), t2 = cmul_(o2,w2), t3 = cmul_(o3,w3);
  v[0]=cadd_(e0,o0); v[4]=csub_(e0,o0);
  v[1]=cadd_(e1,t1); v[5]=csub_(e1,t1);
  v[2]=cadd_(e2,t2); v[6]=csub_(e2,t2);
  v[3]=cadd_(e3,t3); v[7]=csub_(e3,t3);
}

template<bool INV>
__device__ __forceinline__ void dft16ip_(cplx* v){
  cplx t0[4], t1[4], t2[4], t3[4];
  dft4_<INV>(v[0], v[4], v[8],  v[12], t0[0],t0[1],t0[2],t0[3]);
  dft4_<INV>(v[1], v[5], v[9],  v[13], t1[0],t1[1],t1[2],t1[3]);
  dft4_<INV>(v[2], v[6], v[10], v[14], t2[0],t2[1],t2[2],t2[3]);
  dft4_<INV>(v[3], v[7], v[11], v[15], t3[0],t3[1],t3[2],t3[3]);
  const float C1=0.92387953251128675613f, S1=0.38268343236508977172f, R2=0.70710678118654752440f;
  #define TWD_(x, cc, ss) (INV ? cmul_((x), make_float2((cc), (ss))) : cmul_((x), make_float2((cc), -(ss))))
  t1[1] = TWD_(t1[1], C1, S1);
  t1[2] = TWD_(t1[2], R2, R2);
  t1[3] = TWD_(t1[3], S1, C1);
  t2[1] = TWD_(t2[1], R2, R2);
  t2[2] = TWD_(t2[2], 0.f, 1.f);
  t2[3] = TWD_(t2[3], -R2, R2);
  t3[1] = TWD_(t3[1], S1, C1);
  t3[2] = TWD_(t3[2], -R2, R2);
  t3[3] = TWD_(t3[3], -C1, -S1);
  #undef TWD_
  dft4_<INV>(t0[0], t1[0], t2[0], t3[0], v[0], v[4], v[8],  v[12]);
  dft4_<INV>(t0[1], t1[1], t2[1], t3[1], v[1], v[5], v[9],  v[13]);
  dft4_<INV>(t0[2], t1[2], t2[2], t3[2], v[2], v[6], v[10], v[14]);
  dft4_<INV>(t0[3], t1[3], t2[3], t3[3], v[3], v[7], v[11], v[15]);
}

// stage1 (Q-pt DFT over r=a+16b, intra twiddle, swizzled transpose). Caller syncs before.
template<int R0, bool INV>
__device__ __forceinline__ void fft_core(float* lre, float* lim, int t){
  constexpr int Q = R0/16;
  constexpr int S1 = R0 + 8;
  int g = t >> 4, a = t & 15;
  cplx v[Q];
  #pragma unroll
  for (int bb=0;bb<Q;bb++){ int idx = g*S1 + a + 16*bb; v[bb]=make_float2(lre[idx],lim[idx]); }
  if constexpr (Q==16) dft16ip_<INV>(v); else dft8ip_<INV>(v);
  float th = (INV?TWO_PI_F:-TWO_PI_F)*(float)a/(float)R0;
  float sn,cs; __sincosf(th,&sn,&cs);
  cplx w1=make_float2(cs,sn), wu=w1;
  #pragma unroll
  for (int c=1;c<Q;c++){ v[c]=cmul_(v[c],wu); wu=cmul_(wu,w1); }
  __syncthreads();
  #pragma unroll
  for (int c=0;c<Q;c++){ int m = a*Q + ((c+a)&(Q-1)); lre[g*S1+m]=v[c].x; lim[g*S1+m]=v[c].y; }
  __syncthreads();
}

template<int R0, bool INV>
__device__ __forceinline__ bool fft_stage2(const float* lre, const float* lim, int t, int& g2, int& c2, cplx* z){
  constexpr int Q = R0/16; constexpr int S1 = R0+8;
  bool active = (R0==256) || (t < 16*Q);
  g2 = (R0==256)?(t>>4):(t>>3);
  c2 = (R0==256)?(t&15):(t&7);
  if (active){
    #pragma unroll
    for (int a2=0;a2<16;a2++){ int m = a2*Q + ((c2+a2)&(Q-1)); z[a2]=make_float2(lre[g2*S1+m], lim[g2*S1+m]); }
    dft16ip_<INV>(z);
  }
  return active;
}

// ---------------- generic LDS-fused radix-R0 Stockham pass ----------------
template<int R0, bool INV, bool FINALPASS>
__global__ __launch_bounds__(256) void k_fft_block(const cplx* __restrict__ src, cplx* __restrict__ dst,
    int perSig, int blocksPerSig, float interBase){
  constexpr int Q = R0/16;
  constexpr int S1 = R0 + 8;
  constexpr int LSZ = (R0*17 > 16*S1) ? R0*17 : 16*S1;
  __shared__ float lre[LSZ], lim[LSZ];
  int t = threadIdx.x;
  int bx = blockIdx.x;
  int sig = bx / blocksPerSig;
  int tBase = (bx - sig*blocksPerSig) * 16;
  const size_t N = (size_t)R0 * (size_t)perSig;
  const cplx* sb = src + (size_t)sig * N;
  cplx* db = dst + (size_t)sig * N;
  #pragma unroll
  for (int i=0;i<R0/16;i++){
    int e = t + 256*i;
    int g = e & 15, r = e >> 4;
    cplx vv = sb[tBase + g + (size_t)r*perSig];
    lre[g*S1 + r] = vv.x; lim[g*S1 + r] = vv.y;
  }
  __syncthreads();
  fft_core<R0,INV>(lre,lim,t);
  int g2,c2; cplx z[16];
  bool active = fft_stage2<R0,INV>(lre,lim,t,g2,c2,z);
  if constexpr (!FINALPASS){
    if (active){
      int p = tBase + g2;
      float thp = interBase * (float)p;
      float snc, csc; __sincosf(thp * (float)c2, &snc, &csc);
      float sns, css; __sincosf(thp * (float)Q,  &sns, &css);
      cplx wu = make_float2(csc, snc), ws = make_float2(css, sns);
      size_t ob = (size_t)R0 * (size_t)p + (size_t)c2;
      #pragma unroll
      for (int d=0; d<16; d++){ db[ob + (size_t)(d*Q)] = cmul_(z[d], wu); wu = cmul_(wu, ws); }
    }
  } else {
    __syncthreads();
    if (active){
      #pragma unroll
      for (int d=0;d<16;d++){ int u = c2 + Q*d; lre[u*17 + g2] = z[d].x; lim[u*17 + g2] = z[d].y; }
    }
    __syncthreads();
    #pragma unroll
    for (int i=0;i<R0/16;i++){
      int e = t + 256*i;
      int g3 = e & 15, u = e >> 4;
      db[tBase + g3 + (size_t)u*perSig] = make_float2(lre[u*17+g3], lim[u*17+g3]);
    }
  }
}

// ---------------- noise fwd pass1 with fused pack (R0=256, perSig=128) ----------------
__global__ __launch_bounds__(256) void k_fft_pack_fwd1(const float* __restrict__ noise, cplx* __restrict__ dst, float interBase){
  constexpr int R0=256, Q=16, S1=264;
  __shared__ float lre[4352], lim[4352];
  int t=threadIdx.x;
  int bx=blockIdx.x;
  int sig = bx>>3;
  int tBase=(bx&7)*16;
  const float* n0 = noise + (size_t)(2*sig)*NSAMP;
  const float* n1 = noise + (size_t)(2*sig+1)*NSAMP;
  #pragma unroll
  for (int i=0;i<16;i++){
    int e=t+256*i, g=e&15, r=e>>4;
    int ts = tBase+g+128*r;
    lre[g*S1+r]=n0[ts]*2.f-1.f;
    lim[g*S1+r]=n1[ts]*2.f-1.f;
  }
  __syncthreads();
  fft_core<256,false>(lre,lim,t);
  int g2,c2; cplx z[16];
  fft_stage2<256,false>(lre,lim,t,g2,c2,z);
  int p=tBase+g2;
  float thp=interBase*(float)p;
  float snc,csc; __sincosf(thp*(float)c2,&snc,&csc);
  float sns,css; __sincosf(thp*(float)Q,&sns,&css);
  cplx wu=make_float2(csc,snc), ws=make_float2(css,sns);
  cplx* db = dst + (size_t)sig*NSAMP;
  size_t ob=(size_t)256*(size_t)p+(size_t)c2;
  #pragma unroll
  for (int d=0;d<16;d++){ db[ob+(size_t)(d*16)]=cmul_(z[d],wu); wu=cmul_(wu,ws); }
}

// ---------------- noise inverse final pass with split-plane store (R0=128, perSig=256) ----------------
__global__ __launch_bounds__(256) void k_fft_final_split(const cplx* __restrict__ src, float* __restrict__ dstf){
  constexpr int R0=128, Q=8, S1=136;
  __shared__ float lre[2176], lim[2176];
  int t=threadIdx.x; int bx=blockIdx.x;
  int sig=bx>>4; int tBase=(bx&15)*16;
  const cplx* sb = src + (size_t)sig*NSAMP;
  #pragma unroll
  for (int i=0;i<8;i++){
    int e=t+256*i, g=e&15, r=e>>4;
    cplx vv = sb[tBase+g+(size_t)r*256];
    lre[g*S1+r]=vv.x; lim[g*S1+r]=vv.y;
  }
  __syncthreads();
  fft_core<128,true>(lre,lim,t);
  int g2,c2; cplx z[16];
  bool act=fft_stage2<128,true>(lre,lim,t,g2,c2,z);
  __syncthreads();
  if (act){
    #pragma unroll
    for (int d=0;d<16;d++){ int u=c2+8*d; lre[u*17+g2]=z[d].x; lim[u*17+g2]=z[d].y; }
  }
  __syncthreads();
  float* p0 = dstf + (size_t)(2*sig)*NSAMP;
  float* p1 = dstf + (size_t)(2*sig+1)*NSAMP;
  #pragma unroll
  for (int i=0;i<8;i++){
    int e=t+256*i, g3=e&15, u=e>>4;
    int ts = tBase+g3+u*256;
    p0[ts]=lre[u*17+g3]; p1[ts]=lim[u*17+g3];
  }
}

// ---------------- conv fwd pass1 with fused build (R0=256, perSig=256) ----------------
__global__ __launch_bounds__(256) void k_conv_build_fwd1(const float* __restrict__ P,
    const float* __restrict__ NZf, cplx* __restrict__ dst, int rowBase, float interBase){
  constexpr int Q=16, S1=264;
  __shared__ float lre[4352], lim[4352];
  __shared__ float fe[NFRM], f0a[NFRM];
  __shared__ float pw2[8][NFRM];
  __shared__ float A2[129][8], L2[129][8], Q2s[129][8];
  __shared__ float fac_s[8], sc[4];
  int t = threadIdx.x;
  int row = rowBase + blockIdx.y;
  int tBase = blockIdx.x*16;
  const float* Pr = P + (size_t)row*PSTRIDE;
  const double* Cd = (const double*)(Pr + 320);
  if (t < NFRM){ fe[t]=Pr[64+t]; f0a[t]=Pr[192+t]; }
  if (t < 8) fac_s[t]=Pr[4+t];
  if (t >= 8 && t < 12) sc[t-8]=Pr[t-8];
  __syncthreads();
  if (t < 8){
    float m=Pr[12+t], af=Pr[20+t];
    float acc=m*af;
    pw2[t][0]=acc;
    for (int f=1;f<NFRM;f++){ acc*=m; pw2[t][f]=acc; }
  }
  for (int idx=t; idx<129*8; idx+=256){
    int j=idx>>3, h=idx&7, k=j-1;
    const double MINF_D=20.0/11025.0, FSPAN_D=2980.0/11025.0;
    double fac=(double)fac_s[h];
    double A,Lv,Qv;
    if (k < 0){
      A=0.0; Lv=fac*(MINF_D+FSPAN_D*(double)f0a[0]); Qv=0.0;
    } else {
      double phi0=(double)(128+256*k)*MINF_D+FSPAN_D*Cd[k];
      A=fmod(fac*phi0,2.0);
      double f0k=(double)f0a[k];
      double d=(k<127)?((double)f0a[k+1]-f0k):0.0;
      Lv=fac*(MINF_D+FSPAN_D*f0k);
      Qv=fac*FSPAN_D*d*(1.0/512.0);
    }
    A2[j][h]=(float)(0.5*A); L2[j][h]=(float)(0.5*Lv); Q2s[j][h]=(float)(0.5*Qv);
  }
  __syncthreads();
  float mu=sc[0], sigma=sc[1], amp=sc[2], pscale=sc[3];
  const float* nzrow = NZf + (size_t)row*NSAMP;
  #pragma unroll
  for (int i=0;i<16;i++){
    int e=t+256*i, g=e&15, r=e>>4;
    float re=0.f, im=0.f;
    if (r < 128){
      int ts = tBase + g + 256*r;
      float cc=fminf(fmaxf((ts+0.5f)*(1.0f/256.0f)-0.5f,0.0f),127.0f);
      int lo=(int)cc; float w=cc-lo; int hi=min(lo+1,NFRM-1);
      int slot,n0;
      if (ts<128){ slot=0; n0=ts+1; } else { int km=(ts-128)>>8; slot=km+1; n0=ts-127-(km<<8); }
      float nf=(float)n0, nf2=nf*nf;
      float resv=0.f;
      #pragma unroll
      for (int h=0;h<8;h++){
        float rr=A2[slot][h]+nf*L2[slot][h]+nf2*Q2s[slot][h];
        float fr=rr-floorf(rr);
        resv += __builtin_amdgcn_sinf(fr)*(pw2[h][lo]+w*(pw2[h][hi]-pw2[h][lo]));
      }
      float zz=((float)ts-mu)/sigma;
      float prb=pscale*__expf(-0.5f*zz*zz);
      float fev=fe[lo]+w*(fe[hi]-fe[lo]);
      re = prb*nzrow[ts]*amp*fev;
      im = resv;
    }
    lre[g*S1+r]=re; lim[g*S1+r]=im;
  }
  __syncthreads();
  fft_core<256,false>(lre,lim,t);
  int g2,c2; cplx z[16];
  fft_stage2<256,false>(lre,lim,t,g2,c2,z);
  int p = tBase+g2;
  float thp = interBase*(float)p;
  float snc,csc; __sincosf(thp*(float)c2,&snc,&csc);
  float sns,css; __sincosf(thp*(float)Q,&sns,&css);
  cplx wu=make_float2(csc,snc), ws=make_float2(css,sns);
  cplx* db = dst + (size_t)blockIdx.y*NFFT2;
  size_t ob=(size_t)256*(size_t)p+(size_t)c2;
  #pragma unroll
  for (int d=0; d<16; d++){ db[ob+(size_t)(d*16)]=cmul_(z[d],wu); wu=cmul_(wu,ws); }
}

// ---------------- conv inverse final pass with fused output (R0=256, perSig=256) ----------------
__global__ __launch_bounds__(256) void k_fft_final_out(const cplx* __restrict__ src, float* __restrict__ out,
    int bBase, int paired){
  constexpr int S1=264;
  __shared__ float lre[4352], lim[4352];
  int t=threadIdx.x; int bx=blockIdx.x;
  int sig=bx>>4; int tBase=(bx&15)*16;
  const cplx* sb = src + (size_t)sig*NFFT2;
  #pragma unroll
  for (int i=0;i<16;i++){
    int e=t+256*i, g=e&15, r=e>>4;
    cplx vv = sb[tBase+g+(size_t)r*256];
    lre[g*S1+r]=vv.x; lim[g*S1+r]=vv.y;
  }
  __syncthreads();
  fft_core<256,true>(lre,lim,t);
  int g2,c2; cplx z[16];
  fft_stage2<256,true>(lre,lim,t,g2,c2,z);
  __syncthreads();
  #pragma unroll
  for (int d=0;d<16;d++){ int u=c2+16*d; lre[u*17+g2]=z[d].x; lim[u*17+g2]=z[d].y; }
  __syncthreads();
  int b0 = bBase + (paired ? 2*sig : sig);
  float* o0 = out + (size_t)b0*NSAMP;
  float* o1 = out + (size_t)(b0+1)*NSAMP;
  #pragma unroll
  for (int i=0;i<8;i++){
    int e=t+256*i, g3=e&15, u=e>>4;
    int ts=tBase+g3+u*256;
    o0[ts]=lre[u*17+g3];
    if (paired) o1[ts]=lim[u*17+g3];
  }
}

// ---------------- parameter extraction (+ per-row double cumsum) ----------------
__global__ void k_params(const float* __restrict__ x, float* __restrict__ P){
  int row = blockIdx.x; int tid = threadIdx.x;
  const float* xr = x + row*428;
  float* Pr = P + (size_t)row*PSTRIDE;
  __shared__ float sx[428];
  for (int i = tid; i < 428; i += 64) sx[i] = 1.0f/(1.0f+expf(-xr[i]));
  __syncthreads();
  if (tid == 0){
    float mean = sx[0]; float stds = sx[1]*0.1f; float amp = sx[2]*sx[2];
    float f0 = sx[3]*sx[3];
    float mu = fminf(fmaxf(mean*32768.0f, -16384.0f), 49152.0f);
    float sigma = fminf(fmaxf((1e-8f + stds)*32768.0f, 0.0f), 32767.0f);
    float c = 1.0f/(sigma*2.5066282746310002f);
    float tt0 = fminf(fmaxf(floorf(mu), 0.0f), 32767.0f);
    float tt1 = fminf(fmaxf(ceilf(mu), 0.0f), 32767.0f);
    float z0 = (tt0-mu)/sigma, z1=(tt1-mu)/sigma;
    float gmax = fmaxf(expf(-0.5f*z0*z0), expf(-0.5f*z1*z1));
    float pscale = c / (c*gmax + 1e-12f);
    Pr[0]=mu; Pr[1]=sigma; Pr[2]=amp; Pr[3]=pscale;
    Pr[4] = 1.0f;
    for (int h=1;h<8;h++) Pr[4+h] = 1.0f + sx[4+h]*7.0f;
    for (int h=0;h<8;h++){ float m = sx[12+h]*0.9999f; Pr[12+h] = m*m; }
    for (int h=0;h<8;h++) Pr[20+h] = sx[164+h]*sx[164+h];
    for (int i=0;i<16;i++) Pr[28+i] = sx[20+i];
    float acc = 0.0f;
    for (int f=0; f<NFRM; f++){ acc += sx[36+f]*2.0f - 1.0f; Pr[64+f] = fminf(fmaxf(acc,0.0f),1.0f); }
    for (int f=0; f<NFRM; f++){ float var = sx[172+f]*(f0*0.01f); Pr[192+f] = f0 + var; }
    double* Cdw = (double*)(Pr + 320);
    double accd = 128.0*(double)Pr[192];
    Cdw[0] = accd;
    for (int k=0;k<127;k++){ accd += 128.0*((double)Pr[192+k] + (double)Pr[192+k+1]); Cdw[k+1] = accd; }
  }
}

// ---------------- spectral filter, mirror-paired, x(1/N) ----------------
__global__ void k_filter2(const cplx* __restrict__ Zb, cplx* __restrict__ Fb, const float* __restrict__ P){
  int k = blockIdx.x*blockDim.x + threadIdx.x;
  if (k > NSAMP/2) return;
  int j = blockIdx.y;
  int km = (NSAMP - k) & (NSAMP-1);
  const cplx* Zr = Zb + ((size_t)j<<15);
  cplx Z = Zr[k], Zc = Zr[km];
  cplx U1 = make_float2(0.5f*(Z.x+Zc.x), 0.5f*(Z.y-Zc.y));
  cplx U2 = make_float2(0.5f*(Z.y+Zc.y), -0.5f*(Z.x-Zc.x));
  float coords=(k+0.5f)*(16.0f/16385.0f)-0.5f;
  coords=fminf(fmaxf(coords,0.0f),15.0f);
  int lo=(int)coords; float w=coords-lo; int hi=min(lo+1,15);
  const float* c1 = P + (size_t)(2*j)*PSTRIDE + 28;
  const float* c2 = c1 + PSTRIDE;
  float s1=(c1[lo]+w*(c1[hi]-c1[lo]))*(1.0f/32768.0f);
  float s2=(c2[lo]+w*(c2[hi]-c2[lo]))*(1.0f/32768.0f);
  float G1x=U1.x*s1, G1y=U1.y*s1, G2x=U2.x*s2, G2y=U2.y*s2;
  cplx* Fr = Fb + ((size_t)j<<15);
  Fr[k]  = make_float2(G1x - G2y, G1y + G2x);
  Fr[km] = make_float2(G1x + G2y, G2x - G1y);
}

// ---------------- spectral product, mirror-paired, sum events, pack batch pairs, x(1/M) ----------------
__global__ void k_combine2(const cplx* __restrict__ Sp, cplx* __restrict__ Dp, int paired){
  int k = blockIdx.x*blockDim.x + threadIdx.x;
  if (k > NSAMP) return;
  int j = blockIdx.y;
  int km = (NFFT2 - k) & (NFFT2-1);
  const float scale = 1.0f/65536.0f;
  float Wkx=0.f,Wky=0.f,Wmx=0.f,Wmy=0.f;
  int nb = paired?2:1;
  for (int bb=0;bb<nb;bb++){
    const cplx* Cb = Sp + (size_t)(paired?(2*j+bb):j)*8*NFFT2;
    float Pkx=0.f,Pky=0.f,Pmx=0.f,Pmy=0.f;
    for (int e=0;e<8;e++){
      cplx Z  = Cb[(size_t)e*NFFT2 + k];
      cplx Zc = Cb[(size_t)e*NFFT2 + km];
      cplx Z2=cmul_(Z,Z), Zc2=cmul_(Zc,Zc);
      float dx=Z2.x-Zc2.x, dy=Z2.y+Zc2.y;
      Pkx += 0.25f*dy; Pky -= 0.25f*dx;
      Pmx += 0.25f*dy; Pmy += 0.25f*dx;
    }
    if (bb==0){ Wkx+=Pkx*scale; Wky+=Pky*scale; Wmx+=Pmx*scale; Wmy+=Pmy*scale; }
    else      { Wkx-=Pky*scale; Wky+=Pkx*scale; Wmx-=Pmy*scale; Wmy+=Pmx*scale; }
  }
  cplx* Dj = Dp + (size_t)j*NFFT2;
  Dj[k]  = make_float2(Wkx,Wky);
  Dj[km] = make_float2(Wmx,Wmy);
}

// ---------------- host ----------------
extern "C" void kernel_launch(void* const* d_in, const int* in_sizes, int n_in,
                              void* d_out, int out_size, void* d_ws, size_t ws_size,
                              hipStream_t stream){
  const float* x = (const float*)d_in[0];
  const float* noise = (const float*)d_in[1];
  float* out = (float*)d_out;
  char* ws = (char*)d_ws;

  const size_t oA = (size_t)1<<20;
  const size_t szN = (size_t)64*NSAMP*sizeof(cplx);
  const size_t oB = oA + szN;
  const size_t oC = oB + szN;

  const int cand[5] = {1,2,4,8,16};
  int nchunk = -1;
  for (int ci=0; ci<5; ci++){
    size_t csz = ((size_t)(128/cand[ci]))*NFFT2*sizeof(cplx);
    if (oC + 2*csz <= ws_size){ nchunk = cand[ci]; break; }
  }
  if (nchunk < 0) return;

  int sigPerChunk = 128/nchunk;
  size_t csz = (size_t)sigPerChunk*NFFT2*sizeof(cplx);
  size_t oD = oC + csz;

  float* P = (float*)(ws);
  cplx* A = (cplx*)(ws + oA);
  cplx* B = (cplx*)(ws + oB);
  cplx* C = (cplx*)(ws + oC);
  cplx* D = (cplx*)(ws + oD);

  k_params<<<128, 64, 0, stream>>>(x, P);
  // noise forward FFT (32768 = 256*128), pack fused: noise -> A -> B (spectra in B)
  k_fft_pack_fwd1<<<64*8, 256, 0, stream>>>(noise, A, -TWO_PI_F/32768.0f);
  k_fft_block<128,false,true ><<<64*16, 256, 0, stream>>>(A, B, 256, 16, 0.0f);
  // filter, mirror-paired: B -> A
  k_filter2<<<dim3(65,64), 256, 0, stream>>>(B, A, P);
  // noise inverse FFT: A -> B -> (float planes in A)
  k_fft_block<256,true ,false><<<64*8,  256, 0, stream>>>(A, B, 128, 8, TWO_PI_F/32768.0f);
  k_fft_final_split<<<64*16, 256, 0, stream>>>(B, (float*)A);

  int bpc = sigPerChunk/8;
  int paired = (bpc >= 2) ? 1 : 0;
  int npair = paired ? bpc/2 : bpc;
  for (int c=0; c<nchunk; c++){
    int rowBase = c*sigPerChunk;
    // conv fwd pass1 with fused build: (P, nz planes) -> C
    k_conv_build_fwd1<<<dim3(16, sigPerChunk), 256, 0, stream>>>(P, (float*)A, C, rowBase, -TWO_PI_F/65536.0f);
    // conv fwd pass2: C -> D (natural-order spectra)
    k_fft_block<256,false,true ><<<sigPerChunk*16, 256, 0, stream>>>(C, D, 256, 16, 0.0f);
    // combine, mirror-paired: D -> C
    k_combine2<<<dim3(129, npair), 256, 0, stream>>>(D, C, paired);
    // conv inverse: C -> D -> out
    k_fft_block<256,true ,false><<<npair*16, 256, 0, stream>>>(C, D, 256, 16, TWO_PI_F/65536.0f);
    k_fft_final_out<<<npair*16, 256, 0, stream>>>(D, out, c*bpc, paired);
  }
}

// Round 5
// 151.267 us; speedup vs baseline: 3.0223x; 1.0393x over previous
//
#include <hip/hip_runtime.h>
#include <math.h>

#define NSAMP 32768
#define NFFT2 65536
#define NFRM 128
#define PSTRIDE 2688
#define P_FEPAIR 64
#define P_PW2 320
#define P_LQ 1344
#define P_AF 1604
#define P_END 2636
#define TWO_PI_F 6.28318530717958647692f

typedef float2 cplx;

__device__ __forceinline__ cplx cmul_(cplx a, cplx b){ return make_float2(a.x*b.x - a.y*b.y, a.x*b.y + a.y*b.x); }
__device__ __forceinline__ cplx cadd_(cplx a, cplx b){ return make_float2(a.x+b.x, a.y+b.y); }
__device__ __forceinline__ cplx csub_(cplx a, cplx b){ return make_float2(a.x-b.x, a.y-b.y); }

template<bool INV>
__device__ __forceinline__ void dft4_(cplx x0,cplx x1,cplx x2,cplx x3, cplx&y0,cplx&y1,cplx&y2,cplx&y3){
  cplx t0=cadd_(x0,x2), t1=csub_(x0,x2), t2=cadd_(x1,x3), t3=csub_(x1,x3);
  y0=cadd_(t0,t2); y2=csub_(t0,t2);
  cplx it3 = make_float2(-t3.y, t3.x);
  if (INV){ y1=cadd_(t1,it3); y3=csub_(t1,it3); }
  else    { y1=csub_(t1,it3); y3=cadd_(t1,it3); }
}

template<bool INV>
__device__ __forceinline__ void dft8ip_(cplx* v){
  cplx e0,e1,e2,e3,o0,o1,o2,o3;
  dft4_<INV>(v[0],v[2],v[4],v[6], e0,e1,e2,e3);
  dft4_<INV>(v[1],v[3],v[5],v[7], o0,o1,o2,o3);
  const float r = 0.70710678118654752440f;
  cplx w1 = INV ? make_float2(r, r)    : make_float2(r,-r);
  cplx w2 = INV ? make_float2(0.f,1.f) : make_float2(0.f,-1.f);
  cplx w3 = INV ? make_float2(-r,r)    : make_float2(-r,-r);
  cplx t1 = cmul_(o1,w1), t2 = cmul_(o2,w2), t3 = cmul_(o3,w3);
  v[0]=cadd_(e0,o0); v[4]=csub_(e0,o0);
  v[1]=cadd_(e1,t1); v[5]=csub_(e1,t1);
  v[2]=cadd_(e2,t2); v[6]=csub_(e2,t2);
  v[3]=cadd_(e3,t3); v[7]=csub_(e3,t3);
}

template<bool INV>
__device__ __forceinline__ void dft16ip_(cplx* v){
  cplx t0[4], t1[4], t2[4], t3[4];
  dft4_<INV>(v[0], v[4], v[8],  v[12], t0[0],t0[1],t0[2],t0[3]);
  dft4_<INV>(v[1], v[5], v[9],  v[13], t1[0],t1[1],t1[2],t1[3]);
  dft4_<INV>(v[2], v[6], v[10], v[14], t2[0],t2[1],t2[2],t2[3]);
  dft4_<INV>(v[3], v[7], v[11], v[15], t3[0],t3[1],t3[2],t3[3]);
  const float C1=0.92387953251128675613f, S1=0.38268343236508977172f, R2=0.70710678118654752440f;
  #define TWD_(x, cc, ss) (INV ? cmul_((x), make_float2((cc), (ss))) : cmul_((x), make_float2((cc), -(ss))))
  t1[1] = TWD_(t1[1], C1, S1);
  t1[2] = TWD_(t1[2], R2, R2);
  t1[3] = TWD_(t1[3], S1, C1);
  t2[1] = TWD_(t2[1], R2, R2);
  t2[2] = TWD_(t2[2], 0.f, 1.f);
  t2[3] = TWD_(t2[3], -R2, R2);
  t3[1] = TWD_(t3[1], S1, C1);
  t3[2] = TWD_(t3[2], -R2, R2);
  t3[3] = TWD_(t3[3], -C1, -S1);
  #undef TWD_
  dft4_<INV>(t0[0], t1[0], t2[0], t3[0], v[0], v[4], v[8],  v[12]);
  dft4_<INV>(t0[1], t1[1], t2[1], t3[1], v[1], v[5], v[9],  v[13]);
  dft4_<INV>(t0[2], t1[2], t2[2], t3[2], v[2], v[6], v[10], v[14]);
  dft4_<INV>(t0[3], t1[3], t2[3], t3[3], v[3], v[7], v[11], v[15]);
}

template<int R0, bool INV>
__device__ __forceinline__ void fft_core(float* lre, float* lim, int t){
  constexpr int Q = R0/16;
  constexpr int S1 = R0 + 8;
  int g = t >> 4, a = t & 15;
  cplx v[Q];
  #pragma unroll
  for (int bb=0;bb<Q;bb++){ int idx = g*S1 + a + 16*bb; v[bb]=make_float2(lre[idx],lim[idx]); }
  if constexpr (Q==16) dft16ip_<INV>(v); else dft8ip_<INV>(v);
  float th = (INV?TWO_PI_F:-TWO_PI_F)*(float)a/(float)R0;
  float sn,cs; __sincosf(th,&sn,&cs);
  cplx w1=make_float2(cs,sn), wu=w1;
  #pragma unroll
  for (int c=1;c<Q;c++){ v[c]=cmul_(v[c],wu); wu=cmul_(wu,w1); }
  __syncthreads();
  #pragma unroll
  for (int c=0;c<Q;c++){ int m = a*Q + ((c+a)&(Q-1)); lre[g*S1+m]=v[c].x; lim[g*S1+m]=v[c].y; }
  __syncthreads();
}

template<int R0, bool INV>
__device__ __forceinline__ bool fft_stage2(const float* lre, const float* lim, int t, int& g2, int& c2, cplx* z){
  constexpr int Q = R0/16; constexpr int S1 = R0+8;
  bool active = (R0==256) || (t < 16*Q);
  g2 = (R0==256)?(t>>4):(t>>3);
  c2 = (R0==256)?(t&15):(t&7);
  if (active){
    #pragma unroll
    for (int a2=0;a2<16;a2++){ int m = a2*Q + ((c2+a2)&(Q-1)); z[a2]=make_float2(lre[g2*S1+m], lim[g2*S1+m]); }
    dft16ip_<INV>(z);
  }
  return active;
}

// ---------------- generic LDS-fused radix-R0 Stockham pass ----------------
template<int R0, bool INV, bool FINALPASS>
__global__ __launch_bounds__(256) void k_fft_block(const cplx* __restrict__ src, cplx* __restrict__ dst,
    int perSig, int blocksPerSig, float interBase){
  constexpr int Q = R0/16;
  constexpr int S1 = R0 + 8;
  constexpr int LSZ = (R0*17 > 16*S1) ? R0*17 : 16*S1;
  __shared__ float lre[LSZ], lim[LSZ];
  int t = threadIdx.x;
  int bx = blockIdx.x;
  int sig = bx / blocksPerSig;
  int tBase = (bx - sig*blocksPerSig) * 16;
  const size_t N = (size_t)R0 * (size_t)perSig;
  const cplx* sb = src + (size_t)sig * N;
  cplx* db = dst + (size_t)sig * N;
  #pragma unroll
  for (int i=0;i<R0/16;i++){
    int e = t + 256*i;
    int g = e & 15, r = e >> 4;
    cplx vv = sb[tBase + g + (size_t)r*perSig];
    lre[g*S1 + r] = vv.x; lim[g*S1 + r] = vv.y;
  }
  __syncthreads();
  fft_core<R0,INV>(lre,lim,t);
  int g2,c2; cplx z[16];
  bool active = fft_stage2<R0,INV>(lre,lim,t,g2,c2,z);
  if constexpr (!FINALPASS){
    if (active){
      int p = tBase + g2;
      float thp = interBase * (float)p;
      float snc, csc; __sincosf(thp * (float)c2, &snc, &csc);
      float sns, css; __sincosf(thp * (float)Q,  &sns, &css);
      cplx wu = make_float2(csc, snc), ws = make_float2(css, sns);
      size_t ob = (size_t)R0 * (size_t)p + (size_t)c2;
      #pragma unroll
      for (int d=0; d<16; d++){ db[ob + (size_t)(d*Q)] = cmul_(z[d], wu); wu = cmul_(wu, ws); }
    }
  } else {
    __syncthreads();
    if (active){
      #pragma unroll
      for (int d=0;d<16;d++){ int u = c2 + Q*d; lre[u*17 + g2] = z[d].x; lim[u*17 + g2] = z[d].y; }
    }
    __syncthreads();
    #pragma unroll
    for (int i=0;i<R0/16;i++){
      int e = t + 256*i;
      int g3 = e & 15, u = e >> 4;
      db[tBase + g3 + (size_t)u*perSig] = make_float2(lre[u*17+g3], lim[u*17+g3]);
    }
  }
}

// ---------------- noise fwd pass1 with fused pack (R0=256, perSig=128) ----------------
__global__ __launch_bounds__(256) void k_fft_pack_fwd1(const float* __restrict__ noise, cplx* __restrict__ dst, float interBase){
  constexpr int Q=16, S1=264;
  __shared__ float lre[4352], lim[4352];
  int t=threadIdx.x;
  int bx=blockIdx.x;
  int sig = bx>>3;
  int tBase=(bx&7)*16;
  const float* n0 = noise + (size_t)(2*sig)*NSAMP;
  const float* n1 = noise + (size_t)(2*sig+1)*NSAMP;
  #pragma unroll
  for (int i=0;i<16;i++){
    int e=t+256*i, g=e&15, r=e>>4;
    int ts = tBase+g+128*r;
    lre[g*S1+r]=n0[ts]*2.f-1.f;
    lim[g*S1+r]=n1[ts]*2.f-1.f;
  }
  __syncthreads();
  fft_core<256,false>(lre,lim,t);
  int g2,c2; cplx z[16];
  fft_stage2<256,false>(lre,lim,t,g2,c2,z);
  int p=tBase+g2;
  float thp=interBase*(float)p;
  float snc,csc; __sincosf(thp*(float)c2,&snc,&csc);
  float sns,css; __sincosf(thp*(float)Q,&sns,&css);
  cplx wu=make_float2(csc,snc), ws=make_float2(css,sns);
  cplx* db = dst + (size_t)sig*NSAMP;
  size_t ob=(size_t)256*(size_t)p+(size_t)c2;
  #pragma unroll
  for (int d=0;d<16;d++){ db[ob+(size_t)(d*16)]=cmul_(z[d],wu); wu=cmul_(wu,ws); }
}

// ---------------- noise fwd pass2 (final) + spectral filter fused ----------------
__device__ __forceinline__ void fft128_natural(float* re, float* im, int t){
  __syncthreads();
  fft_core<128,false>(re,im,t);
  int g2,c2; cplx z[16];
  bool act = fft_stage2<128,false>(re,im,t,g2,c2,z);
  __syncthreads();
  if (act){
    #pragma unroll
    for (int d=0;d<16;d++){ int u=c2+8*d; re[u*17+g2]=z[d].x; im[u*17+g2]=z[d].y; }
  }
  __syncthreads();
}

__global__ __launch_bounds__(256) void k_fft2_filter(const cplx* __restrict__ src, cplx* __restrict__ dst,
    const float* __restrict__ P){
  __shared__ float aRe[2176], aIm[2176], bRe[2176], bIm[2176];
  __shared__ float c1s[16], c2sh[16];
  int t=threadIdx.x, pb=blockIdx.x, j=blockIdx.y;
  const cplx* sb = src + ((size_t)j<<15);
  cplx* db = dst + ((size_t)j<<15);
  if (t<16) c1s[t] = P[(size_t)(2*j)*PSTRIDE+28+t];
  else if (t<32) c2sh[t-16] = P[(size_t)(2*j+1)*PSTRIDE+28+(t-16)];
  // set A (pb<8: cols 16pb+g; pb==8: edge cols 16g)
  #pragma unroll
  for (int i=0;i<8;i++){
    int e=t+256*i, g=e&15, r=e>>4;
    int col = (pb<8)? (pb*16+g) : (g*16);
    cplx v = sb[col + (r<<8)];
    aRe[g*136+r]=v.x; aIm[g*136+r]=v.y;
  }
  fft128_natural(aRe,aIm,t);
  if (pb<8){
    #pragma unroll
    for (int i=0;i<8;i++){
      int e=t+256*i, g=e&15, r=e>>4;
      int col = 240-pb*16+g;
      cplx v = sb[col + (r<<8)];
      bRe[g*136+r]=v.x; bIm[g*136+r]=v.y;
    }
    fft128_natural(bRe,bIm,t);
  }
  const float inv32768 = 1.0f/32768.0f;
  if (pb<8){
    #pragma unroll
    for (int it=0; it<16; it++){
      int s=it>>3, uu=it&7;
      int g=t&15, u=(t>>4)+16*uu;
      if (g!=0){
        int colK = s? (240-pb*16+g) : (pb*16+g);
        int gm=16-g, um=127-u;
        float Zkx,Zky,Zmx,Zmy;
        if (s==0){ Zkx=aRe[u*17+g]; Zky=aIm[u*17+g]; Zmx=bRe[um*17+gm]; Zmy=bIm[um*17+gm]; }
        else     { Zkx=bRe[u*17+g]; Zky=bIm[u*17+g]; Zmx=aRe[um*17+gm]; Zmy=aIm[um*17+gm]; }
        int k = colK + (u<<8);
        int kb = min(k, NSAMP-k);
        float coords=fminf(fmaxf((kb+0.5f)*(16.0f/16385.0f)-0.5f,0.0f),15.0f);
        int lo=(int)coords; float w=coords-lo; int hi=min(lo+1,15);
        float s1=(c1s[lo]+w*(c1s[hi]-c1s[lo]))*inv32768;
        float s2=(c2sh[lo]+w*(c2sh[hi]-c2sh[lo]))*inv32768;
        float U1x=0.5f*(Zkx+Zmx), U1y=0.5f*(Zky-Zmy);
        float U2x=0.5f*(Zky+Zmy), U2y=-0.5f*(Zkx-Zmx);
        db[k]=make_float2(U1x*s1 - U2y*s2, U1y*s1 + U2x*s2);
      }
    }
  } else {
    #pragma unroll
    for (int uu=0; uu<8; uu++){
      int g=t&15, u=(t>>4)+16*uu;
      int k = g*16 + (u<<8);
      int gm=(16-g)&15;
      int um=(g==0)? ((128-u)&127) : (127-u);
      float Zkx=aRe[u*17+g], Zky=aIm[u*17+g];
      float Zmx=aRe[um*17+gm], Zmy=aIm[um*17+gm];
      int kb = min(k, NSAMP-k);
      float coords=fminf(fmaxf((kb+0.5f)*(16.0f/16385.0f)-0.5f,0.0f),15.0f);
      int lo=(int)coords; float w=coords-lo; int hi=min(lo+1,15);
      float s1=(c1s[lo]+w*(c1s[hi]-c1s[lo]))*inv32768;
      float s2=(c2sh[lo]+w*(c2sh[hi]-c2sh[lo]))*inv32768;
      float U1x=0.5f*(Zkx+Zmx), U1y=0.5f*(Zky-Zmy);
      float U2x=0.5f*(Zky+Zmy), U2y=-0.5f*(Zkx-Zmx);
      db[k]=make_float2(U1x*s1 - U2y*s2, U1y*s1 + U2x*s2);
    }
  }
}

// ---------------- noise inverse final pass with split-plane store (R0=128, perSig=256) ----------------
__global__ __launch_bounds__(256) void k_fft_final_split(const cplx* __restrict__ src, float* __restrict__ dstf){
  constexpr int S1=136;
  __shared__ float lre[2176], lim[2176];
  int t=threadIdx.x; int bx=blockIdx.x;
  int sig=bx>>4; int tBase=(bx&15)*16;
  const cplx* sb = src + (size_t)sig*NSAMP;
  #pragma unroll
  for (int i=0;i<8;i++){
    int e=t+256*i, g=e&15, r=e>>4;
    cplx vv = sb[tBase+g+(size_t)r*256];
    lre[g*S1+r]=vv.x; lim[g*S1+r]=vv.y;
  }
  __syncthreads();
  fft_core<128,true>(lre,lim,t);
  int g2,c2; cplx z[16];
  bool act=fft_stage2<128,true>(lre,lim,t,g2,c2,z);
  __syncthreads();
  if (act){
    #pragma unroll
    for (int d=0;d<16;d++){ int u=c2+8*d; lre[u*17+g2]=z[d].x; lim[u*17+g2]=z[d].y; }
  }
  __syncthreads();
  float* p0 = dstf + (size_t)(2*sig)*NSAMP;
  float* p1 = dstf + (size_t)(2*sig+1)*NSAMP;
  #pragma unroll
  for (int i=0;i<8;i++){
    int e=t+256*i, g3=e&15, u=e>>4;
    int ts = tBase+g3+u*256;
    p0[ts]=lre[u*17+g3]; p1[ts]=lim[u*17+g3];
  }
}

// ---------------- conv fwd pass1 with fused build (tables precomputed) ----------------
__global__ __launch_bounds__(256) void k_conv_build_fwd1(const float* __restrict__ P,
    const float* __restrict__ NZf, cplx* __restrict__ dst, int rowBase, float interBase){
  constexpr int Q=16, S1=264;
  __shared__ float lre[4224], lim[4224];
  __shared__ float sTab[2640];
  int t=threadIdx.x;
  int row = rowBase + blockIdx.y;
  int tBase = blockIdx.x*16;
  const float* Pr = P + (size_t)row*PSTRIDE;
  for (int i=t; i<P_END; i+=256) sTab[i] = Pr[i];
  __syncthreads();
  float mu=sTab[0], sigma=sTab[1], amp=sTab[2], pscale=sTab[3];
  float fac[8], mh[8];
  #pragma unroll
  for (int h=0;h<8;h++){ fac[h]=sTab[4+h]; mh[h]=sTab[12+h]; }
  const float2* fe2 = (const float2*)&sTab[P_FEPAIR];
  const float*  pw2 = &sTab[P_PW2];
  const float2* LQt = (const float2*)&sTab[P_LQ];
  const float*  Af  = &sTab[P_AF];
  const float* nzrow = NZf + (size_t)row*NSAMP;
  #pragma unroll
  for (int i=0;i<8;i++){
    int e=t+256*i, g=e&15, r=e>>4;
    int ts = tBase + g + (r<<8);
    float cc=fminf(fmaxf((ts+0.5f)*(1.0f/256.0f)-0.5f,0.0f),127.0f);
    int lo=(int)cc; float w=cc-lo;
    float2 fp = fe2[lo];
    float fev = fp.x + w*fp.y;
    int slot, n0;
    if (ts<128){ slot=0; n0=ts+1; } else { int km=(ts-128)>>8; slot=km+1; n0=ts-127-(km<<8); }
    float nf=(float)n0, nf2=nf*nf;
    float2 lq = LQt[slot];
    float base = nf*lq.x + nf2*lq.y;
    float wm = (lo<127)? w : 0.0f;
    float resv=0.f;
    #pragma unroll
    for (int h=0;h<8;h++){
      float mgb = pw2[h*128+lo];
      if (mgb > 1e-7f){
        float rr = Af[slot*8+h] + fac[h]*base;
        float fr = rr - floorf(rr);
        float s = __builtin_amdgcn_sinf(fr);
        resv += s*mgb*(1.0f + wm*(mh[h]-1.0f));
      }
    }
    float zz=((float)ts-mu)/sigma;
    float prb=pscale*__expf(-0.5f*zz*zz);
    float re = prb*nzrow[ts]*amp*fev;
    lre[g*S1+r]=re; lim[g*S1+r]=resv;
  }
  #pragma unroll
  for (int i=8;i<16;i++){
    int e=t+256*i, g=e&15, r=e>>4;
    lre[g*S1+r]=0.f; lim[g*S1+r]=0.f;
  }
  __syncthreads();
  fft_core<256,false>(lre,lim,t);
  int g2,c2; cplx z[16];
  fft_stage2<256,false>(lre,lim,t,g2,c2,z);
  int p = tBase+g2;
  float thp = interBase*(float)p;
  float snc,csc; __sincosf(thp*(float)c2,&snc,&csc);
  float sns,css; __sincosf(thp*(float)Q,&sns,&css);
  cplx wu=make_float2(csc,snc), ws=make_float2(css,sns);
  cplx* db = dst + (size_t)blockIdx.y*NFFT2;
  size_t ob=(size_t)256*(size_t)p+(size_t)c2;
  #pragma unroll
  for (int d=0; d<16; d++){ db[ob+(size_t)(d*16)]=cmul_(z[d],wu); wu=cmul_(wu,ws); }
}

// ---------------- conv inverse final pass with fused output ----------------
__global__ __launch_bounds__(256) void k_fft_final_out(const cplx* __restrict__ src, float* __restrict__ out,
    int bBase, int paired){
  constexpr int S1=264;
  __shared__ float lre[4352], lim[4352];
  int t=threadIdx.x; int bx=blockIdx.x;
  int sig=bx>>4; int tBase=(bx&15)*16;
  const cplx* sb = src + (size_t)sig*NFFT2;
  #pragma unroll
  for (int i=0;i<16;i++){
    int e=t+256*i, g=e&15, r=e>>4;
    cplx vv = sb[tBase+g+(size_t)r*256];
    lre[g*S1+r]=vv.x; lim[g*S1+r]=vv.y;
  }
  __syncthreads();
  fft_core<256,true>(lre,lim,t);
  int g2,c2; cplx z[16];
  fft_stage2<256,true>(lre,lim,t,g2,c2,z);
  __syncthreads();
  #pragma unroll
  for (int d=0;d<16;d++){ int u=c2+16*d; lre[u*17+g2]=z[d].x; lim[u*17+g2]=z[d].y; }
  __syncthreads();
  int b0 = bBase + (paired ? 2*sig : sig);
  float* o0 = out + (size_t)b0*NSAMP;
  float* o1 = out + (size_t)(b0+1)*NSAMP;
  #pragma unroll
  for (int i=0;i<8;i++){
    int e=t+256*i, g3=e&15, u=e>>4;
    int ts=tBase+g3+u*256;
    o0[ts]=lre[u*17+g3];
    if (paired) o1[ts]=lim[u*17+g3];
  }
}

// ---------------- parameter extraction + ALL per-row tables ----------------
__global__ __launch_bounds__(256) void k_params(const float* __restrict__ x, float* __restrict__ P){
  int row = blockIdx.x; int t = threadIdx.x;
  const float* xr = x + row*428;
  float* Pr = P + (size_t)row*PSTRIDE;
  __shared__ float sx[428];
  __shared__ float fes[128], f0s[128];
  __shared__ double Cds[128];
  __shared__ float facs[8], ms[8], afs[8];
  __shared__ float f0_sh;
  for (int i=t;i<428;i+=256) sx[i]=1.0f/(1.0f+expf(-xr[i]));
  __syncthreads();
  if (t==0){
    float mean = sx[0]; float stds = sx[1]*0.1f; float amp = sx[2]*sx[2];
    float mu = fminf(fmaxf(mean*32768.0f, -16384.0f), 49152.0f);
    float sigma = fminf(fmaxf((1e-8f + stds)*32768.0f, 0.0f), 32767.0f);
    float c = 1.0f/(sigma*2.5066282746310002f);
    float tt0 = fminf(fmaxf(floorf(mu), 0.0f), 32767.0f);
    float tt1 = fminf(fmaxf(ceilf(mu), 0.0f), 32767.0f);
    float z0 = (tt0-mu)/sigma, z1=(tt1-mu)/sigma;
    float gmax = fmaxf(expf(-0.5f*z0*z0), expf(-0.5f*z1*z1));
    float pscale = c / (c*gmax + 1e-12f);
    Pr[0]=mu; Pr[1]=sigma; Pr[2]=amp; Pr[3]=pscale;
  }
  if (t<8){
    float fv = (t==0)?1.0f:(1.0f+sx[4+t]*7.0f);
    facs[t]=fv; Pr[4+t]=fv;
    float m = sx[12+t]*0.9999f; m=m*m; ms[t]=m; Pr[12+t]=m;
    afs[t]=sx[164+t]*sx[164+t];
  }
  if (t>=32&&t<48) Pr[28+(t-32)] = sx[20+(t-32)];
  if (t==64) f0_sh = sx[3]*sx[3];
  if (t==65){
    float acc=0.f;
    for (int f=0;f<128;f++){ acc += sx[36+f]*2.0f-1.0f; fes[f]=fminf(fmaxf(acc,0.f),1.f); }
  }
  __syncthreads();
  if (t<128){
    float f0=f0_sh;
    f0s[t] = f0 + sx[172+t]*(f0*0.01f);
  }
  __syncthreads();
  if (t==0){
    double acc = 128.0*(double)f0s[0]; Cds[0]=acc;
    for (int k=0;k<127;k++){ acc += 128.0*((double)f0s[k]+(double)f0s[k+1]); Cds[k+1]=acc; }
  }
  if (t<128){
    float v=fes[t], vh=fes[min(t+1,127)];
    Pr[P_FEPAIR+2*t]=v; Pr[P_FEPAIR+2*t+1]=vh-v;
  }
  if (t>=128 && t<136){
    int h=t-128; float m=ms[h];
    float acc = afs[h]*m;
    float* dstp = Pr + P_PW2 + h*128;
    dstp[0]=acc;
    for (int f=1;f<128;f++){ acc*=m; dstp[f]=acc; }
  }
  __syncthreads();
  const double MINF_D=20.0/11025.0, FSPAN_D=2980.0/11025.0;
  if (t<129){
    int k=t-1;
    float Lb, Qb;
    if (k<0){ Lb=(float)(0.5*(MINF_D+FSPAN_D*(double)f0s[0])); Qb=0.f; }
    else {
      double f0k=(double)f0s[k];
      double d=(k<127)?((double)f0s[k+1]-f0k):0.0;
      Lb=(float)(0.5*(MINF_D+FSPAN_D*f0k));
      Qb=(float)(0.5*FSPAN_D*d*(1.0/512.0));
    }
    Pr[P_LQ+2*t]=Lb; Pr[P_LQ+2*t+1]=Qb;
  }
  for (int idx=t; idx<129*8; idx+=256){
    int jj=idx>>3, h=idx&7, k=jj-1;
    float Aval;
    if (k<0) Aval=0.f;
    else {
      double phi0=(double)(128+256*k)*MINF_D+FSPAN_D*Cds[k];
      Aval=(float)(0.5*fmod((double)facs[h]*phi0,2.0));
    }
    Pr[P_AF+idx]=Aval;
  }
}

// ---------------- spectral product, mirror-paired, sum events, pack batch pairs, x(1/M) ----------------
__global__ void k_combine2(const cplx* __restrict__ Sp, cplx* __restrict__ Dp, int paired){
  int k = blockIdx.x*blockDim.x + threadIdx.x;
  if (k > NSAMP) return;
  int j = blockIdx.y;
  int km = (NFFT2 - k) & (NFFT2-1);
  const float scale = 1.0f/65536.0f;
  float Wkx=0.f,Wky=0.f,Wmx=0.f,Wmy=0.f;
  int nb = paired?2:1;
  for (int bb=0;bb<nb;bb++){
    const cplx* Cb = Sp + (size_t)(paired?(2*j+bb):j)*8*NFFT2;
    float Pkx=0.f,Pky=0.f,Pmx=0.f,Pmy=0.f;
    for (int e=0;e<8;e++){
      cplx Z  = Cb[(size_t)e*NFFT2 + k];
      cplx Zc = Cb[(size_t)e*NFFT2 + km];
      cplx Z2=cmul_(Z,Z), Zc2=cmul_(Zc,Zc);
      float dx=Z2.x-Zc2.x, dy=Z2.y+Zc2.y;
      Pkx += 0.25f*dy; Pky -= 0.25f*dx;
      Pmx += 0.25f*dy; Pmy += 0.25f*dx;
    }
    if (bb==0){ Wkx+=Pkx*scale; Wky+=Pky*scale; Wmx+=Pmx*scale; Wmy+=Pmy*scale; }
    else      { Wkx-=Pky*scale; Wky+=Pkx*scale; Wmx-=Pmy*scale; Wmy+=Pmx*scale; }
  }
  cplx* Dj = Dp + (size_t)j*NFFT2;
  Dj[k]  = make_float2(Wkx,Wky);
  Dj[km] = make_float2(Wmx,Wmy);
}

// ---------------- host ----------------
extern "C" void kernel_launch(void* const* d_in, const int* in_sizes, int n_in,
                              void* d_out, int out_size, void* d_ws, size_t ws_size,
                              hipStream_t stream){
  const float* x = (const float*)d_in[0];
  const float* noise = (const float*)d_in[1];
  float* out = (float*)d_out;
  char* ws = (char*)d_ws;

  const size_t oA = (size_t)2<<20;                       // params region: 2 MiB
  const size_t szN = (size_t)64*NSAMP*sizeof(cplx);
  const size_t oB = oA + szN;
  const size_t oC = oB + szN;

  const int cand[5] = {1,2,4,8,16};
  int nchunk = -1;
  for (int ci=0; ci<5; ci++){
    size_t csz = ((size_t)(128/cand[ci]))*NFFT2*sizeof(cplx);
    if (oC + 2*csz <= ws_size){ nchunk = cand[ci]; break; }
  }
  if (nchunk < 0) return;

  int sigPerChunk = 128/nchunk;
  size_t csz = (size_t)sigPerChunk*NFFT2*sizeof(cplx);
  size_t oD = oC + csz;

  float* P = (float*)(ws);
  cplx* A = (cplx*)(ws + oA);
  cplx* B = (cplx*)(ws + oB);
  cplx* C = (cplx*)(ws + oC);
  cplx* D = (cplx*)(ws + oD);

  k_params<<<128, 256, 0, stream>>>(x, P);
  // noise forward FFT (32768 = 256*128), pack fused: noise -> A; pass2+filter fused: A -> B (F natural)
  k_fft_pack_fwd1<<<64*8, 256, 0, stream>>>(noise, A, -TWO_PI_F/32768.0f);
  k_fft2_filter<<<dim3(9,64), 256, 0, stream>>>(A, B, P);
  // noise inverse FFT: B -> A -> (float planes in B)
  k_fft_block<256,true ,false><<<64*8,  256, 0, stream>>>(B, A, 128, 8, TWO_PI_F/32768.0f);
  k_fft_final_split<<<64*16, 256, 0, stream>>>(A, (float*)B);

  int bpc = sigPerChunk/8;
  int paired = (bpc >= 2) ? 1 : 0;
  int npair = paired ? bpc/2 : bpc;
  for (int c=0; c<nchunk; c++){
    int rowBase = c*sigPerChunk;
    k_conv_build_fwd1<<<dim3(16, sigPerChunk), 256, 0, stream>>>(P, (float*)B, C, rowBase, -TWO_PI_F/65536.0f);
    k_fft_block<256,false,true ><<<sigPerChunk*16, 256, 0, stream>>>(C, D, 256, 16, 0.0f);
    k_combine2<<<dim3(129, npair), 256, 0, stream>>>(D, C, paired);
    k_fft_block<256,true ,false><<<npair*16, 256, 0, stream>>>(C, D, 256, 16, TWO_PI_F/65536.0f);
    k_fft_final_out<<<npair*16, 256, 0, stream>>>(D, out, c*bpc, paired);
  }
}

// Round 6
// 142.236 us; speedup vs baseline: 3.2142x; 1.0635x over previous
//
#include <hip/hip_runtime.h>
#include <math.h>

#define NSAMP 32768
#define NFFT2 65536
#define NFRM 128
#define PSTRIDE 2688
#define P_FEPAIR 64
#define P_PW2 320
#define P_LQ 1344
#define P_AF 1604
#define P_END 2636
#define TWO_PI_F 6.28318530717958647692f

typedef float2 cplx;

__device__ __forceinline__ cplx cmul_(cplx a, cplx b){ return make_float2(a.x*b.x - a.y*b.y, a.x*b.y + a.y*b.x); }
__device__ __forceinline__ cplx cadd_(cplx a, cplx b){ return make_float2(a.x+b.x, a.y+b.y); }
__device__ __forceinline__ cplx csub_(cplx a, cplx b){ return make_float2(a.x-b.x, a.y-b.y); }

template<bool INV>
__device__ __forceinline__ void dft4_(cplx x0,cplx x1,cplx x2,cplx x3, cplx&y0,cplx&y1,cplx&y2,cplx&y3){
  cplx t0=cadd_(x0,x2), t1=csub_(x0,x2), t2=cadd_(x1,x3), t3=csub_(x1,x3);
  y0=cadd_(t0,t2); y2=csub_(t0,t2);
  cplx it3 = make_float2(-t3.y, t3.x);
  if (INV){ y1=cadd_(t1,it3); y3=csub_(t1,it3); }
  else    { y1=csub_(t1,it3); y3=cadd_(t1,it3); }
}

template<bool INV>
__device__ __forceinline__ void dft8ip_(cplx* v){
  cplx e0,e1,e2,e3,o0,o1,o2,o3;
  dft4_<INV>(v[0],v[2],v[4],v[6], e0,e1,e2,e3);
  dft4_<INV>(v[1],v[3],v[5],v[7], o0,o1,o2,o3);
  const float r = 0.70710678118654752440f;
  cplx w1 = INV ? make_float2(r, r)    : make_float2(r,-r);
  cplx w2 = INV ? make_float2(0.f,1.f) : make_float2(0.f,-1.f);
  cplx w3 = INV ? make_float2(-r,r)    : make_float2(-r,-r);
  cplx t1 = cmul_(o1,w1), t2 = cmul_(o2,w2), t3 = cmul_(o3,w3);
  v[0]=cadd_(e0,o0); v[4]=csub_(e0,o0);
  v[1]=cadd_(e1,t1); v[5]=csub_(e1,t1);
  v[2]=cadd_(e2,t2); v[6]=csub_(e2,t2);
  v[3]=cadd_(e3,t3); v[7]=csub_(e3,t3);
}

template<bool INV>
__device__ __forceinline__ void dft16ip_(cplx* v){
  cplx t0[4], t1[4], t2[4], t3[4];
  dft4_<INV>(v[0], v[4], v[8],  v[12], t0[0],t0[1],t0[2],t0[3]);
  dft4_<INV>(v[1], v[5], v[9],  v[13], t1[0],t1[1],t1[2],t1[3]);
  dft4_<INV>(v[2], v[6], v[10], v[14], t2[0],t2[1],t2[2],t2[3]);
  dft4_<INV>(v[3], v[7], v[11], v[15], t3[0],t3[1],t3[2],t3[3]);
  const float C1=0.92387953251128675613f, S1=0.38268343236508977172f, R2=0.70710678118654752440f;
  #define TWD_(x, cc, ss) (INV ? cmul_((x), make_float2((cc), (ss))) : cmul_((x), make_float2((cc), -(ss))))
  t1[1] = TWD_(t1[1], C1, S1);
  t1[2] = TWD_(t1[2], R2, R2);
  t1[3] = TWD_(t1[3], S1, C1);
  t2[1] = TWD_(t2[1], R2, R2);
  t2[2] = TWD_(t2[2], 0.f, 1.f);
  t2[3] = TWD_(t2[3], -R2, R2);
  t3[1] = TWD_(t3[1], S1, C1);
  t3[2] = TWD_(t3[2], -R2, R2);
  t3[3] = TWD_(t3[3], -C1, -S1);
  #undef TWD_
  dft4_<INV>(t0[0], t1[0], t2[0], t3[0], v[0], v[4], v[8],  v[12]);
  dft4_<INV>(t0[1], t1[1], t2[1], t3[1], v[1], v[5], v[9],  v[13]);
  dft4_<INV>(t0[2], t1[2], t2[2], t3[2], v[2], v[6], v[10], v[14]);
  dft4_<INV>(t0[3], t1[3], t2[3], t3[3], v[3], v[7], v[11], v[15]);
}

template<int R0, bool INV>
__device__ __forceinline__ void fft_core(float* lre, float* lim, int t){
  constexpr int Q = R0/16;
  constexpr int S1 = R0 + 8;
  int g = t >> 4, a = t & 15;
  cplx v[Q];
  #pragma unroll
  for (int bb=0;bb<Q;bb++){ int idx = g*S1 + a + 16*bb; v[bb]=make_float2(lre[idx],lim[idx]); }
  if constexpr (Q==16) dft16ip_<INV>(v); else dft8ip_<INV>(v);
  float th = (INV?TWO_PI_F:-TWO_PI_F)*(float)a/(float)R0;
  float sn,cs; __sincosf(th,&sn,&cs);
  cplx w1=make_float2(cs,sn), wu=w1;
  #pragma unroll
  for (int c=1;c<Q;c++){ v[c]=cmul_(v[c],wu); wu=cmul_(wu,w1); }
  __syncthreads();
  #pragma unroll
  for (int c=0;c<Q;c++){ int m = a*Q + ((c+a)&(Q-1)); lre[g*S1+m]=v[c].x; lim[g*S1+m]=v[c].y; }
  __syncthreads();
}

template<int R0, bool INV>
__device__ __forceinline__ bool fft_stage2(const float* lre, const float* lim, int t, int& g2, int& c2, cplx* z){
  constexpr int Q = R0/16; constexpr int S1 = R0+8;
  bool active = (R0==256) || (t < 16*Q);
  g2 = (R0==256)?(t>>4):(t>>3);
  c2 = (R0==256)?(t&15):(t&7);
  if (active){
    #pragma unroll
    for (int a2=0;a2<16;a2++){ int m = a2*Q + ((c2+a2)&(Q-1)); z[a2]=make_float2(lre[g2*S1+m], lim[g2*S1+m]); }
    dft16ip_<INV>(z);
  }
  return active;
}

// ---------------- generic LDS-fused radix-R0 Stockham pass ----------------
template<int R0, bool INV, bool FINALPASS>
__global__ __launch_bounds__(256) void k_fft_block(const cplx* __restrict__ src, cplx* __restrict__ dst,
    int perSig, int blocksPerSig, float interBase){
  constexpr int Q = R0/16;
  constexpr int S1 = R0 + 8;
  constexpr int LSZ = (R0*17 > 16*S1) ? R0*17 : 16*S1;
  __shared__ float lre[LSZ], lim[LSZ];
  int t = threadIdx.x;
  int bx = blockIdx.x;
  int sig = bx / blocksPerSig;
  int tBase = (bx - sig*blocksPerSig) * 16;
  const size_t N = (size_t)R0 * (size_t)perSig;
  const cplx* sb = src + (size_t)sig * N;
  cplx* db = dst + (size_t)sig * N;
  #pragma unroll
  for (int i=0;i<R0/16;i++){
    int e = t + 256*i;
    int g = e & 15, r = e >> 4;
    cplx vv = sb[tBase + g + (size_t)r*perSig];
    lre[g*S1 + r] = vv.x; lim[g*S1 + r] = vv.y;
  }
  __syncthreads();
  fft_core<R0,INV>(lre,lim,t);
  int g2,c2; cplx z[16];
  bool active = fft_stage2<R0,INV>(lre,lim,t,g2,c2,z);
  if constexpr (!FINALPASS){
    if (active){
      int p = tBase + g2;
      float thp = interBase * (float)p;
      float snc, csc; __sincosf(thp * (float)c2, &snc, &csc);
      float sns, css; __sincosf(thp * (float)Q,  &sns, &css);
      cplx wu = make_float2(csc, snc), ws = make_float2(css, sns);
      size_t ob = (size_t)R0 * (size_t)p + (size_t)c2;
      #pragma unroll
      for (int d=0; d<16; d++){ db[ob + (size_t)(d*Q)] = cmul_(z[d], wu); wu = cmul_(wu, ws); }
    }
  } else {
    __syncthreads();
    if (active){
      #pragma unroll
      for (int d=0;d<16;d++){ int u = c2 + Q*d; lre[u*17 + g2] = z[d].x; lim[u*17 + g2] = z[d].y; }
    }
    __syncthreads();
    #pragma unroll
    for (int i=0;i<R0/16;i++){
      int e = t + 256*i;
      int g3 = e & 15, u = e >> 4;
      db[tBase + g3 + (size_t)u*perSig] = make_float2(lre[u*17+g3], lim[u*17+g3]);
    }
  }
}

// ---------------- noise fwd pass1 with fused pack (R0=256, perSig=128) ----------------
__global__ __launch_bounds__(256) void k_fft_pack_fwd1(const float* __restrict__ noise, cplx* __restrict__ dst, float interBase){
  constexpr int Q=16, S1=264;
  __shared__ float lre[4352], lim[4352];
  int t=threadIdx.x;
  int bx=blockIdx.x;
  int sig = bx>>3;
  int tBase=(bx&7)*16;
  const float* n0 = noise + (size_t)(2*sig)*NSAMP;
  const float* n1 = noise + (size_t)(2*sig+1)*NSAMP;
  #pragma unroll
  for (int i=0;i<16;i++){
    int e=t+256*i, g=e&15, r=e>>4;
    int ts = tBase+g+128*r;
    lre[g*S1+r]=n0[ts]*2.f-1.f;
    lim[g*S1+r]=n1[ts]*2.f-1.f;
  }
  __syncthreads();
  fft_core<256,false>(lre,lim,t);
  int g2,c2; cplx z[16];
  fft_stage2<256,false>(lre,lim,t,g2,c2,z);
  int p=tBase+g2;
  float thp=interBase*(float)p;
  float snc,csc; __sincosf(thp*(float)c2,&snc,&csc);
  float sns,css; __sincosf(thp*(float)Q,&sns,&css);
  cplx wu=make_float2(csc,snc), ws=make_float2(css,sns);
  cplx* db = dst + (size_t)sig*NSAMP;
  size_t ob=(size_t)256*(size_t)p+(size_t)c2;
  #pragma unroll
  for (int d=0;d<16;d++){ db[ob+(size_t)(d*16)]=cmul_(z[d],wu); wu=cmul_(wu,ws); }
}

// ---------------- noise fwd pass2 (final) + spectral filter fused ----------------
__device__ __forceinline__ void fft128_natural(float* re, float* im, int t){
  __syncthreads();
  fft_core<128,false>(re,im,t);
  int g2,c2; cplx z[16];
  bool act = fft_stage2<128,false>(re,im,t,g2,c2,z);
  __syncthreads();
  if (act){
    #pragma unroll
    for (int d=0;d<16;d++){ int u=c2+8*d; re[u*17+g2]=z[d].x; im[u*17+g2]=z[d].y; }
  }
  __syncthreads();
}

__global__ __launch_bounds__(256) void k_fft2_filter(const cplx* __restrict__ src, cplx* __restrict__ dst,
    const float* __restrict__ P){
  __shared__ float aRe[2176], aIm[2176], bRe[2176], bIm[2176];
  __shared__ float c1s[16], c2sh[16];
  int t=threadIdx.x, pb=blockIdx.x, j=blockIdx.y;
  const cplx* sb = src + ((size_t)j<<15);
  cplx* db = dst + ((size_t)j<<15);
  if (t<16) c1s[t] = P[(size_t)(2*j)*PSTRIDE+28+t];
  else if (t<32) c2sh[t-16] = P[(size_t)(2*j+1)*PSTRIDE+28+(t-16)];
  #pragma unroll
  for (int i=0;i<8;i++){
    int e=t+256*i, g=e&15, r=e>>4;
    int col = (pb<8)? (pb*16+g) : (g*16);
    cplx v = sb[col + (r<<8)];
    aRe[g*136+r]=v.x; aIm[g*136+r]=v.y;
  }
  fft128_natural(aRe,aIm,t);
  if (pb<8){
    #pragma unroll
    for (int i=0;i<8;i++){
      int e=t+256*i, g=e&15, r=e>>4;
      int col = 240-pb*16+g;
      cplx v = sb[col + (r<<8)];
      bRe[g*136+r]=v.x; bIm[g*136+r]=v.y;
    }
    fft128_natural(bRe,bIm,t);
  }
  const float inv32768 = 1.0f/32768.0f;
  if (pb<8){
    #pragma unroll
    for (int it=0; it<16; it++){
      int s=it>>3, uu=it&7;
      int g=t&15, u=(t>>4)+16*uu;
      if (g!=0){
        int colK = s? (240-pb*16+g) : (pb*16+g);
        int gm=16-g, um=127-u;
        float Zkx,Zky,Zmx,Zmy;
        if (s==0){ Zkx=aRe[u*17+g]; Zky=aIm[u*17+g]; Zmx=bRe[um*17+gm]; Zmy=bIm[um*17+gm]; }
        else     { Zkx=bRe[u*17+g]; Zky=bIm[u*17+g]; Zmx=aRe[um*17+gm]; Zmy=aIm[um*17+gm]; }
        int k = colK + (u<<8);
        int kb = min(k, NSAMP-k);
        float coords=fminf(fmaxf((kb+0.5f)*(16.0f/16385.0f)-0.5f,0.0f),15.0f);
        int lo=(int)coords; float w=coords-lo; int hi=min(lo+1,15);
        float s1=(c1s[lo]+w*(c1s[hi]-c1s[lo]))*inv32768;
        float s2=(c2sh[lo]+w*(c2sh[hi]-c2sh[lo]))*inv32768;
        float U1x=0.5f*(Zkx+Zmx), U1y=0.5f*(Zky-Zmy);
        float U2x=0.5f*(Zky+Zmy), U2y=-0.5f*(Zkx-Zmx);
        db[k]=make_float2(U1x*s1 - U2y*s2, U1y*s1 + U2x*s2);
      }
    }
  } else {
    #pragma unroll
    for (int uu=0; uu<8; uu++){
      int g=t&15, u=(t>>4)+16*uu;
      int k = g*16 + (u<<8);
      int gm=(16-g)&15;
      int um=(g==0)? ((128-u)&127) : (127-u);
      float Zkx=aRe[u*17+g], Zky=aIm[u*17+g];
      float Zmx=aRe[um*17+gm], Zmy=aIm[um*17+gm];
      int kb = min(k, NSAMP-k);
      float coords=fminf(fmaxf((kb+0.5f)*(16.0f/16385.0f)-0.5f,0.0f),15.0f);
      int lo=(int)coords; float w=coords-lo; int hi=min(lo+1,15);
      float s1=(c1s[lo]+w*(c1s[hi]-c1s[lo]))*inv32768;
      float s2=(c2sh[lo]+w*(c2sh[hi]-c2sh[lo]))*inv32768;
      float U1x=0.5f*(Zkx+Zmx), U1y=0.5f*(Zky-Zmy);
      float U2x=0.5f*(Zky+Zmy), U2y=-0.5f*(Zkx-Zmx);
      db[k]=make_float2(U1x*s1 - U2y*s2, U1y*s1 + U2x*s2);
    }
  }
}

// ---------------- noise inverse final pass with split-plane store (R0=128, perSig=256) ----------------
__global__ __launch_bounds__(256) void k_fft_final_split(const cplx* __restrict__ src, float* __restrict__ dstf){
  constexpr int S1=136;
  __shared__ float lre[2176], lim[2176];
  int t=threadIdx.x; int bx=blockIdx.x;
  int sig=bx>>4; int tBase=(bx&15)*16;
  const cplx* sb = src + (size_t)sig*NSAMP;
  #pragma unroll
  for (int i=0;i<8;i++){
    int e=t+256*i, g=e&15, r=e>>4;
    cplx vv = sb[tBase+g+(size_t)r*256];
    lre[g*S1+r]=vv.x; lim[g*S1+r]=vv.y;
  }
  __syncthreads();
  fft_core<128,true>(lre,lim,t);
  int g2,c2; cplx z[16];
  bool act=fft_stage2<128,true>(lre,lim,t,g2,c2,z);
  __syncthreads();
  if (act){
    #pragma unroll
    for (int d=0;d<16;d++){ int u=c2+8*d; lre[u*17+g2]=z[d].x; lim[u*17+g2]=z[d].y; }
  }
  __syncthreads();
  float* p0 = dstf + (size_t)(2*sig)*NSAMP;
  float* p1 = dstf + (size_t)(2*sig+1)*NSAMP;
  #pragma unroll
  for (int i=0;i<8;i++){
    int e=t+256*i, g3=e&15, u=e>>4;
    int ts = tBase+g3+u*256;
    p0[ts]=lre[u*17+g3]; p1[ts]=lim[u*17+g3];
  }
}

// ---------------- conv fwd pass1 with fused build ----------------
// LDS overlay: tables live in lre region during phase A; samples staged in registers.
__global__ __launch_bounds__(256) void k_conv_build_fwd1(const float* __restrict__ P,
    const float* __restrict__ NZf, cplx* __restrict__ dst, int rowBase, float interBase){
  constexpr int Q=16, S1=264;
  __shared__ float smem[8448];             // lre=smem[0..4223], lim=smem[4224..8447]
  float* lre = smem;
  float* lim = smem + 4224;
  float* sTab = smem;                      // overlay: tables occupy lre region in phase A
  int t=threadIdx.x;
  int row = rowBase + blockIdx.y;
  int tBase = blockIdx.x*16;
  const float* Pr = P + (size_t)row*PSTRIDE;
  for (int i=t; i<P_END; i+=256) sTab[i] = Pr[i];
  __syncthreads();
  float mu=sTab[0], sigma=sTab[1], amp=sTab[2], pscale=sTab[3];
  float fac[8], mh[8];
  #pragma unroll
  for (int h=0;h<8;h++){ fac[h]=sTab[4+h]; mh[h]=sTab[12+h]; }
  const float2* fe2 = (const float2*)&sTab[P_FEPAIR];
  const float*  pw2 = &sTab[P_PW2];
  const float2* LQt = (const float2*)&sTab[P_LQ];
  const float*  Af  = &sTab[P_AF];
  const float* nzrow = NZf + (size_t)row*NSAMP;
  // phase A: compute 8 (re,im) pairs into registers
  float vre[8], vim[8];
  #pragma unroll
  for (int i=0;i<8;i++){
    int e=t+256*i, g=e&15, r=e>>4;
    int ts = tBase + g + (r<<8);
    float cc=fminf(fmaxf((ts+0.5f)*(1.0f/256.0f)-0.5f,0.0f),127.0f);
    int lo=(int)cc; float w=cc-lo;
    float2 fp = fe2[lo];
    float fev = fp.x + w*fp.y;
    int slot, n0;
    if (ts<128){ slot=0; n0=ts+1; } else { int km=(ts-128)>>8; slot=km+1; n0=ts-127-(km<<8); }
    float nf=(float)n0, nf2=nf*nf;
    float2 lq = LQt[slot];
    float base = nf*lq.x + nf2*lq.y;
    float wm = (lo<127)? w : 0.0f;
    float resv=0.f;
    #pragma unroll
    for (int h=0;h<8;h++){
      float mgb = pw2[h*128+lo];
      if (mgb > 1e-7f){
        float rr = Af[slot*8+h] + fac[h]*base;
        float fr = rr - floorf(rr);
        float s = __builtin_amdgcn_sinf(fr);
        resv += s*mgb*(1.0f + wm*(mh[h]-1.0f));
      }
    }
    float zz=((float)ts-mu)/sigma;
    float prb=pscale*__expf(-0.5f*zz*zz);
    vre[i] = prb*nzrow[ts]*amp*fev;
    vim[i] = resv;
  }
  __syncthreads();
  // phase B: stage FFT tile (overwrites table region)
  #pragma unroll
  for (int i=0;i<8;i++){
    int e=t+256*i, g=e&15, r=e>>4;
    lre[g*S1+r]=vre[i]; lim[g*S1+r]=vim[i];
  }
  #pragma unroll
  for (int i=8;i<16;i++){
    int e=t+256*i, g=e&15, r=e>>4;
    lre[g*S1+r]=0.f; lim[g*S1+r]=0.f;
  }
  __syncthreads();
  fft_core<256,false>(lre,lim,t);
  int g2,c2; cplx z[16];
  fft_stage2<256,false>(lre,lim,t,g2,c2,z);
  int p = tBase+g2;
  float thp = interBase*(float)p;
  float snc,csc; __sincosf(thp*(float)c2,&snc,&csc);
  float sns,css; __sincosf(thp*(float)Q,&sns,&css);
  cplx wu=make_float2(csc,snc), ws=make_float2(css,sns);
  cplx* db = dst + (size_t)blockIdx.y*NFFT2;
  size_t ob=(size_t)256*(size_t)p+(size_t)c2;
  #pragma unroll
  for (int d=0; d<16; d++){ db[ob+(size_t)(d*16)]=cmul_(z[d],wu); wu=cmul_(wu,ws); }
}

// ---------------- conv inverse final pass with fused output ----------------
__global__ __launch_bounds__(256) void k_fft_final_out(const cplx* __restrict__ src, float* __restrict__ out,
    int bBase, int paired){
  constexpr int S1=264;
  __shared__ float lre[4352], lim[4352];
  int t=threadIdx.x; int bx=blockIdx.x;
  int sig=bx>>4; int tBase=(bx&15)*16;
  const cplx* sb = src + (size_t)sig*NFFT2;
  #pragma unroll
  for (int i=0;i<16;i++){
    int e=t+256*i, g=e&15, r=e>>4;
    cplx vv = sb[tBase+g+(size_t)r*256];
    lre[g*S1+r]=vv.x; lim[g*S1+r]=vv.y;
  }
  __syncthreads();
  fft_core<256,true>(lre,lim,t);
  int g2,c2; cplx z[16];
  fft_stage2<256,true>(lre,lim,t,g2,c2,z);
  __syncthreads();
  #pragma unroll
  for (int d=0;d<16;d++){ int u=c2+16*d; lre[u*17+g2]=z[d].x; lim[u*17+g2]=z[d].y; }
  __syncthreads();
  int b0 = bBase + (paired ? 2*sig : sig);
  float* o0 = out + (size_t)b0*NSAMP;
  float* o1 = out + (size_t)(b0+1)*NSAMP;
  #pragma unroll
  for (int i=0;i<8;i++){
    int e=t+256*i, g3=e&15, u=e>>4;
    int ts=tBase+g3+u*256;
    o0[ts]=lre[u*17+g3];
    if (paired) o1[ts]=lim[u*17+g3];
  }
}

// ---------------- parameter extraction + ALL per-row tables ----------------
__global__ __launch_bounds__(256) void k_params(const float* __restrict__ x, float* __restrict__ P){
  int row = blockIdx.x; int t = threadIdx.x;
  const float* xr = x + row*428;
  float* Pr = P + (size_t)row*PSTRIDE;
  __shared__ float sx[428];
  __shared__ float fes[128], f0s[128];
  __shared__ double Cds[128];
  __shared__ float facs[8], ms[8], afs[8];
  __shared__ float f0_sh;
  for (int i=t;i<428;i+=256) sx[i]=1.0f/(1.0f+expf(-xr[i]));
  __syncthreads();
  if (t==0){
    float mean = sx[0]; float stds = sx[1]*0.1f; float amp = sx[2]*sx[2];
    float mu = fminf(fmaxf(mean*32768.0f, -16384.0f), 49152.0f);
    float sigma = fminf(fmaxf((1e-8f + stds)*32768.0f, 0.0f), 32767.0f);
    float c = 1.0f/(sigma*2.5066282746310002f);
    float tt0 = fminf(fmaxf(floorf(mu), 0.0f), 32767.0f);
    float tt1 = fminf(fmaxf(ceilf(mu), 0.0f), 32767.0f);
    float z0 = (tt0-mu)/sigma, z1=(tt1-mu)/sigma;
    float gmax = fmaxf(expf(-0.5f*z0*z0), expf(-0.5f*z1*z1));
    float pscale = c / (c*gmax + 1e-12f);
    Pr[0]=mu; Pr[1]=sigma; Pr[2]=amp; Pr[3]=pscale;
  }
  if (t<8){
    float fv = (t==0)?1.0f:(1.0f+sx[4+t]*7.0f);
    facs[t]=fv; Pr[4+t]=fv;
    float m = sx[12+t]*0.9999f; m=m*m; ms[t]=m; Pr[12+t]=m;
    afs[t]=sx[164+t]*sx[164+t];
  }
  if (t>=32&&t<48) Pr[28+(t-32)] = sx[20+(t-32)];
  if (t==64) f0_sh = sx[3]*sx[3];
  if (t==65){
    float acc=0.f;
    for (int f=0;f<128;f++){ acc += sx[36+f]*2.0f-1.0f; fes[f]=fminf(fmaxf(acc,0.f),1.f); }
  }
  __syncthreads();
  if (t<128){
    float f0=f0_sh;
    f0s[t] = f0 + sx[172+t]*(f0*0.01f);
  }
  __syncthreads();
  if (t==0){
    double acc = 128.0*(double)f0s[0]; Cds[0]=acc;
    for (int k=0;k<127;k++){ acc += 128.0*((double)f0s[k]+(double)f0s[k+1]); Cds[k+1]=acc; }
  }
  if (t<128){
    float v=fes[t], vh=fes[min(t+1,127)];
    Pr[P_FEPAIR+2*t]=v; Pr[P_FEPAIR+2*t+1]=vh-v;
  }
  if (t>=128 && t<136){
    int h=t-128; float m=ms[h];
    float acc = afs[h]*m;
    float* dstp = Pr + P_PW2 + h*128;
    dstp[0]=acc;
    for (int f=1;f<128;f++){ acc*=m; dstp[f]=acc; }
  }
  __syncthreads();
  const double MINF_D=20.0/11025.0, FSPAN_D=2980.0/11025.0;
  if (t<129){
    int k=t-1;
    float Lb, Qb;
    if (k<0){ Lb=(float)(0.5*(MINF_D+FSPAN_D*(double)f0s[0])); Qb=0.f; }
    else {
      double f0k=(double)f0s[k];
      double d=(k<127)?((double)f0s[k+1]-f0k):0.0;
      Lb=(float)(0.5*(MINF_D+FSPAN_D*f0k));
      Qb=(float)(0.5*FSPAN_D*d*(1.0/512.0));
    }
    Pr[P_LQ+2*t]=Lb; Pr[P_LQ+2*t+1]=Qb;
  }
  for (int idx=t; idx<129*8; idx+=256){
    int jj=idx>>3, h=idx&7, k=jj-1;
    float Aval;
    if (k<0) Aval=0.f;
    else {
      double phi0=(double)(128+256*k)*MINF_D+FSPAN_D*Cds[k];
      Aval=(float)(0.5*fmod((double)facs[h]*phi0,2.0));
    }
    Pr[P_AF+idx]=Aval;
  }
}

// ---------------- spectral product, mirror-paired, sum events, pack batch pairs, x(1/M) ----------------
__global__ void k_combine2(const cplx* __restrict__ Sp, cplx* __restrict__ Dp, int paired){
  int k = blockIdx.x*blockDim.x + threadIdx.x;
  if (k > NSAMP) return;
  int j = blockIdx.y;
  int km = (NFFT2 - k) & (NFFT2-1);
  const float scale = 1.0f/65536.0f;
  float Wkx=0.f,Wky=0.f,Wmx=0.f,Wmy=0.f;
  int nb = paired?2:1;
  for (int bb=0;bb<nb;bb++){
    const cplx* Cb = Sp + (size_t)(paired?(2*j+bb):j)*8*NFFT2;
    float Pkx=0.f,Pky=0.f,Pmx=0.f,Pmy=0.f;
    for (int e=0;e<8;e++){
      cplx Z  = Cb[(size_t)e*NFFT2 + k];
      cplx Zc = Cb[(size_t)e*NFFT2 + km];
      cplx Z2=cmul_(Z,Z), Zc2=cmul_(Zc,Zc);
      float dx=Z2.x-Zc2.x, dy=Z2.y+Zc2.y;
      Pkx += 0.25f*dy; Pky -= 0.25f*dx;
      Pmx += 0.25f*dy; Pmy += 0.25f*dx;
    }
    if (bb==0){ Wkx+=Pkx*scale; Wky+=Pky*scale; Wmx+=Pmx*scale; Wmy+=Pmy*scale; }
    else      { Wkx-=Pky*scale; Wky+=Pkx*scale; Wmx-=Pmy*scale; Wmy+=Pmx*scale; }
  }
  cplx* Dj = Dp + (size_t)j*NFFT2;
  Dj[k]  = make_float2(Wkx,Wky);
  Dj[km] = make_float2(Wmx,Wmy);
}

// ---------------- host ----------------
extern "C" void kernel_launch(void* const* d_in, const int* in_sizes, int n_in,
                              void* d_out, int out_size, void* d_ws, size_t ws_size,
                              hipStream_t stream){
  const float* x = (const float*)d_in[0];
  const float* noise = (const float*)d_in[1];
  float* out = (float*)d_out;
  char* ws = (char*)d_ws;

  const size_t oA = (size_t)2<<20;
  const size_t szN = (size_t)64*NSAMP*sizeof(cplx);
  const size_t oB = oA + szN;
  const size_t oC = oB + szN;

  const int cand[5] = {1,2,4,8,16};
  int nchunk = -1;
  for (int ci=0; ci<5; ci++){
    size_t csz = ((size_t)(128/cand[ci]))*NFFT2*sizeof(cplx);
    if (oC + 2*csz <= ws_size){ nchunk = cand[ci]; break; }
  }
  if (nchunk < 0) return;

  int sigPerChunk = 128/nchunk;
  size_t csz = (size_t)sigPerChunk*NFFT2*sizeof(cplx);
  size_t oD = oC + csz;

  float* P = (float*)(ws);
  cplx* A = (cplx*)(ws + oA);
  cplx* B = (cplx*)(ws + oB);
  cplx* C = (cplx*)(ws + oC);
  cplx* D = (cplx*)(ws + oD);

  k_params<<<128, 256, 0, stream>>>(x, P);
  k_fft_pack_fwd1<<<64*8, 256, 0, stream>>>(noise, A, -TWO_PI_F/32768.0f);
  k_fft2_filter<<<dim3(9,64), 256, 0, stream>>>(A, B, P);
  k_fft_block<256,true ,false><<<64*8,  256, 0, stream>>>(B, A, 128, 8, TWO_PI_F/32768.0f);
  k_fft_final_split<<<64*16, 256, 0, stream>>>(A, (float*)B);

  int bpc = sigPerChunk/8;
  int paired = (bpc >= 2) ? 1 : 0;
  int npair = paired ? bpc/2 : bpc;
  for (int c=0; c<nchunk; c++){
    int rowBase = c*sigPerChunk;
    k_conv_build_fwd1<<<dim3(16, sigPerChunk), 256, 0, stream>>>(P, (float*)B, C, rowBase, -TWO_PI_F/65536.0f);
    k_fft_block<256,false,true ><<<sigPerChunk*16, 256, 0, stream>>>(C, D, 256, 16, 0.0f);
    k_combine2<<<dim3(129, npair), 256, 0, stream>>>(D, C, paired);
    k_fft_block<256,true ,false><<<npair*16, 256, 0, stream>>>(C, D, 256, 16, TWO_PI_F/65536.0f);
    k_fft_final_out<<<npair*16, 256, 0, stream>>>(D, out, c*bpc, paired);
  }
}

// Round 7
// 130.366 us; speedup vs baseline: 3.5068x; 1.0910x over previous
//
#include <hip/hip_runtime.h>
#include <math.h>

#define NSAMP 32768
#define NFFT2 65536
#define NFRM 128
#define PSTRIDE 2688
#define P_FEPAIR 64
#define P_PW2 320
#define P_LQ 1344
#define P_AF 1604
#define P_END 2636
#define TWO_PI_F 6.28318530717958647692f

typedef float2 cplx;

__device__ __forceinline__ cplx cmul_(cplx a, cplx b){ return make_float2(a.x*b.x - a.y*b.y, a.x*b.y + a.y*b.x); }
__device__ __forceinline__ cplx cadd_(cplx a, cplx b){ return make_float2(a.x+b.x, a.y+b.y); }
__device__ __forceinline__ cplx csub_(cplx a, cplx b){ return make_float2(a.x-b.x, a.y-b.y); }

template<bool INV>
__device__ __forceinline__ void dft4_(cplx x0,cplx x1,cplx x2,cplx x3, cplx&y0,cplx&y1,cplx&y2,cplx&y3){
  cplx t0=cadd_(x0,x2), t1=csub_(x0,x2), t2=cadd_(x1,x3), t3=csub_(x1,x3);
  y0=cadd_(t0,t2); y2=csub_(t0,t2);
  cplx it3 = make_float2(-t3.y, t3.x);
  if (INV){ y1=cadd_(t1,it3); y3=csub_(t1,it3); }
  else    { y1=csub_(t1,it3); y3=cadd_(t1,it3); }
}

template<bool INV>
__device__ __forceinline__ void dft8ip_(cplx* v){
  cplx e0,e1,e2,e3,o0,o1,o2,o3;
  dft4_<INV>(v[0],v[2],v[4],v[6], e0,e1,e2,e3);
  dft4_<INV>(v[1],v[3],v[5],v[7], o0,o1,o2,o3);
  const float r = 0.70710678118654752440f;
  cplx w1 = INV ? make_float2(r, r)    : make_float2(r,-r);
  cplx w2 = INV ? make_float2(0.f,1.f) : make_float2(0.f,-1.f);
  cplx w3 = INV ? make_float2(-r,r)    : make_float2(-r,-r);
  cplx t1 = cmul_(o1,w1), t2 = cmul_(o2,w2), t3 = cmul_(o3,w3);
  v[0]=cadd_(e0,o0); v[4]=csub_(e0,o0);
  v[1]=cadd_(e1,t1); v[5]=csub_(e1,t1);
  v[2]=cadd_(e2,t2); v[6]=csub_(e2,t2);
  v[3]=cadd_(e3,t3); v[7]=csub_(e3,t3);
}

template<bool INV>
__device__ __forceinline__ void dft16ip_(cplx* v){
  cplx t0[4], t1[4], t2[4], t3[4];
  dft4_<INV>(v[0], v[4], v[8],  v[12], t0[0],t0[1],t0[2],t0[3]);
  dft4_<INV>(v[1], v[5], v[9],  v[13], t1[0],t1[1],t1[2],t1[3]);
  dft4_<INV>(v[2], v[6], v[10], v[14], t2[0],t2[1],t2[2],t2[3]);
  dft4_<INV>(v[3], v[7], v[11], v[15], t3[0],t3[1],t3[2],t3[3]);
  const float C1=0.92387953251128675613f, S1=0.38268343236508977172f, R2=0.70710678118654752440f;
  #define TWD_(x, cc, ss) (INV ? cmul_((x), make_float2((cc), (ss))) : cmul_((x), make_float2((cc), -(ss))))
  t1[1] = TWD_(t1[1], C1, S1);
  t1[2] = TWD_(t1[2], R2, R2);
  t1[3] = TWD_(t1[3], S1, C1);
  t2[1] = TWD_(t2[1], R2, R2);
  t2[2] = TWD_(t2[2], 0.f, 1.f);
  t2[3] = TWD_(t2[3], -R2, R2);
  t3[1] = TWD_(t3[1], S1, C1);
  t3[2] = TWD_(t3[2], -R2, R2);
  t3[3] = TWD_(t3[3], -C1, -S1);
  #undef TWD_
  dft4_<INV>(t0[0], t1[0], t2[0], t3[0], v[0], v[4], v[8],  v[12]);
  dft4_<INV>(t0[1], t1[1], t2[1], t3[1], v[1], v[5], v[9],  v[13]);
  dft4_<INV>(t0[2], t1[2], t2[2], t3[2], v[2], v[6], v[10], v[14]);
  dft4_<INV>(t0[3], t1[3], t2[3], t3[3], v[3], v[7], v[11], v[15]);
}

template<int R0, bool INV>
__device__ __forceinline__ void fft_core(float* lre, float* lim, int t){
  constexpr int Q = R0/16;
  constexpr int S1 = R0 + 8;
  int g = t >> 4, a = t & 15;
  cplx v[Q];
  #pragma unroll
  for (int bb=0;bb<Q;bb++){ int idx = g*S1 + a + 16*bb; v[bb]=make_float2(lre[idx],lim[idx]); }
  if constexpr (Q==16) dft16ip_<INV>(v); else dft8ip_<INV>(v);
  float th = (INV?TWO_PI_F:-TWO_PI_F)*(float)a/(float)R0;
  float sn,cs; __sincosf(th,&sn,&cs);
  cplx w1=make_float2(cs,sn), wu=w1;
  #pragma unroll
  for (int c=1;c<Q;c++){ v[c]=cmul_(v[c],wu); wu=cmul_(wu,w1); }
  __syncthreads();
  #pragma unroll
  for (int c=0;c<Q;c++){ int m = a*Q + ((c+a)&(Q-1)); lre[g*S1+m]=v[c].x; lim[g*S1+m]=v[c].y; }
  __syncthreads();
}

template<int R0, bool INV>
__device__ __forceinline__ bool fft_stage2(const float* lre, const float* lim, int t, int& g2, int& c2, cplx* z){
  constexpr int Q = R0/16; constexpr int S1 = R0+8;
  bool active = (R0==256) || (t < 16*Q);
  g2 = (R0==256)?(t>>4):(t>>3);
  c2 = (R0==256)?(t&15):(t&7);
  if (active){
    #pragma unroll
    for (int a2=0;a2<16;a2++){ int m = a2*Q + ((c2+a2)&(Q-1)); z[a2]=make_float2(lre[g2*S1+m], lim[g2*S1+m]); }
    dft16ip_<INV>(z);
  }
  return active;
}

// ---------------- noise fwd pass1 with fused pack (R0=256, perSig=128) ----------------
__global__ __launch_bounds__(256) void k_fft_pack_fwd1(const float* __restrict__ noise, cplx* __restrict__ dst, float interBase){
  constexpr int Q=16, S1=264;
  __shared__ float lre[4352], lim[4352];
  int t=threadIdx.x;
  int bx=blockIdx.x;
  int sig = bx>>3;
  int tBase=(bx&7)*16;
  const float* n0 = noise + (size_t)(2*sig)*NSAMP;
  const float* n1 = noise + (size_t)(2*sig+1)*NSAMP;
  #pragma unroll
  for (int i=0;i<16;i++){
    int e=t+256*i, g=e&15, r=e>>4;
    int ts = tBase+g+128*r;
    lre[g*S1+r]=n0[ts]*2.f-1.f;
    lim[g*S1+r]=n1[ts]*2.f-1.f;
  }
  __syncthreads();
  fft_core<256,false>(lre,lim,t);
  int g2,c2; cplx z[16];
  fft_stage2<256,false>(lre,lim,t,g2,c2,z);
  int p=tBase+g2;
  float thp=interBase*(float)p;
  float snc,csc; __sincosf(thp*(float)c2,&snc,&csc);
  float sns,css; __sincosf(thp*(float)Q,&sns,&css);
  cplx wu=make_float2(csc,snc), ws=make_float2(css,sns);
  cplx* db = dst + (size_t)sig*NSAMP;
  size_t ob=(size_t)256*(size_t)p+(size_t)c2;
  #pragma unroll
  for (int d=0;d<16;d++){ db[ob+(size_t)(d*16)]=cmul_(z[d],wu); wu=cmul_(wu,ws); }
}

// ---------------- noise fwd pass2 + filter + inverse pass1, all fused ----------------
__device__ __forceinline__ void fft128_natural(float* re, float* im, int t){
  __syncthreads();
  fft_core<128,false>(re,im,t);
  int g2,c2; cplx z[16];
  bool act = fft_stage2<128,false>(re,im,t,g2,c2,z);
  __syncthreads();
  if (act){
    #pragma unroll
    for (int d=0;d<16;d++){ int u=c2+8*d; re[u*17+g2]=z[d].x; im[u*17+g2]=z[d].y; }
  }
  __syncthreads();
}

__global__ __launch_bounds__(256) void k_nfilter_ip1(const cplx* __restrict__ src, cplx* __restrict__ dst,
    const float* __restrict__ P){
  __shared__ float aRe[2176], aIm[2176], bRe[2176], bIm[2176];
  __shared__ float fRe[2176], fIm[2176];
  __shared__ float c1s[16], c2sh[16];
  int t=threadIdx.x, pb=blockIdx.x, j=blockIdx.y;
  const cplx* sb = src + ((size_t)j<<15);
  cplx* db = dst + ((size_t)j<<15);
  if (t<16) c1s[t] = P[(size_t)(2*j)*PSTRIDE+28+t];
  else if (t<32) c2sh[t-16] = P[(size_t)(2*j+1)*PSTRIDE+28+(t-16)];
  #pragma unroll
  for (int i=0;i<8;i++){
    int e=t+256*i, g=e&15, r=e>>4;
    int col = (pb<8)? (pb*16+g) : (g*16);
    cplx v = sb[col + (r<<8)];
    aRe[g*136+r]=v.x; aIm[g*136+r]=v.y;
  }
  fft128_natural(aRe,aIm,t);
  if (pb<8){
    #pragma unroll
    for (int i=0;i<8;i++){
      int e=t+256*i, g=e&15, r=e>>4;
      int col = 240-pb*16+g;
      cplx v = sb[col + (r<<8)];
      bRe[g*136+r]=v.x; bIm[g*136+r]=v.y;
    }
    fft128_natural(bRe,bIm,t);
  }
  const float inv32768 = 1.0f/32768.0f;
  if (pb<8){
    for (int s=0;s<2;s++){
      __syncthreads();
      #pragma unroll
      for (int uu=0; uu<8; uu++){
        int g=t&15, u=(t>>4)+16*uu;
        if (g!=0){
          int colK = s? (240-pb*16+g) : (pb*16+g);
          int gm=16-g, um=127-u;
          float Zkx,Zky,Zmx,Zmy;
          if (s==0){ Zkx=aRe[u*17+g]; Zky=aIm[u*17+g]; Zmx=bRe[um*17+gm]; Zmy=bIm[um*17+gm]; }
          else     { Zkx=bRe[u*17+g]; Zky=bIm[u*17+g]; Zmx=aRe[um*17+gm]; Zmy=aIm[um*17+gm]; }
          int k = colK + (u<<8);
          int kb = min(k, NSAMP-k);
          float coords=fminf(fmaxf((kb+0.5f)*(16.0f/16385.0f)-0.5f,0.0f),15.0f);
          int lo=(int)coords; float w=coords-lo; int hi=min(lo+1,15);
          float s1=(c1s[lo]+w*(c1s[hi]-c1s[lo]))*inv32768;
          float s2=(c2sh[lo]+w*(c2sh[hi]-c2sh[lo]))*inv32768;
          float U1x=0.5f*(Zkx+Zmx), U1y=0.5f*(Zky-Zmy);
          float U2x=0.5f*(Zky+Zmy), U2y=-0.5f*(Zkx-Zmx);
          fRe[g*136+u]=U1x*s1 - U2y*s2; fIm[g*136+u]=U1y*s1 + U2x*s2;
        }
      }
      __syncthreads();
      fft_core<128,true>(fRe,fIm,t);
      int gg,cc; cplx z[16];
      bool act = fft_stage2<128,true>(fRe,fIm,t,gg,cc,z);
      if (act && gg!=0){
        int p = (s==0) ? (pb*16+gg) : (240-pb*16+gg);
        float thp=(TWO_PI_F/32768.0f)*(float)p;
        float snc,csc; __sincosf(thp*(float)cc,&snc,&csc);
        float sns,css; __sincosf(thp*8.0f,&sns,&css);
        cplx wu=make_float2(csc,snc), wsx=make_float2(css,sns);
        int ob=128*p+cc;
        #pragma unroll
        for (int d=0;d<16;d++){ db[ob+8*d]=cmul_(z[d],wu); wu=cmul_(wu,wsx); }
      }
    }
  } else {
    __syncthreads();
    #pragma unroll
    for (int uu=0; uu<8; uu++){
      int g=t&15, u=(t>>4)+16*uu;
      int k = g*16 + (u<<8);
      int gm=(16-g)&15;
      int um=(g==0)? ((128-u)&127) : (127-u);
      float Zkx=aRe[u*17+g], Zky=aIm[u*17+g];
      float Zmx=aRe[um*17+gm], Zmy=aIm[um*17+gm];
      int kb = min(k, NSAMP-k);
      float coords=fminf(fmaxf((kb+0.5f)*(16.0f/16385.0f)-0.5f,0.0f),15.0f);
      int lo=(int)coords; float w=coords-lo; int hi=min(lo+1,15);
      float s1=(c1s[lo]+w*(c1s[hi]-c1s[lo]))*inv32768;
      float s2=(c2sh[lo]+w*(c2sh[hi]-c2sh[lo]))*inv32768;
      float U1x=0.5f*(Zkx+Zmx), U1y=0.5f*(Zky-Zmy);
      float U2x=0.5f*(Zky+Zmy), U2y=-0.5f*(Zkx-Zmx);
      fRe[g*136+u]=U1x*s1 - U2y*s2; fIm[g*136+u]=U1y*s1 + U2x*s2;
    }
    __syncthreads();
    fft_core<128,true>(fRe,fIm,t);
    int gg,cc; cplx z[16];
    bool act = fft_stage2<128,true>(fRe,fIm,t,gg,cc,z);
    if (act){
      int p = 16*gg;
      float thp=(TWO_PI_F/32768.0f)*(float)p;
      float snc,csc; __sincosf(thp*(float)cc,&snc,&csc);
      float sns,css; __sincosf(thp*8.0f,&sns,&css);
      cplx wu=make_float2(csc,snc), wsx=make_float2(css,sns);
      int ob=128*p+cc;
      #pragma unroll
      for (int d=0;d<16;d++){ db[ob+8*d]=cmul_(z[d],wu); wu=cmul_(wu,wsx); }
    }
  }
}

// ---------------- noise inverse final (R0=256, perSig=128) with split-plane store ----------------
__global__ __launch_bounds__(256) void k_ifinal_split(const cplx* __restrict__ src, float* __restrict__ dstf){
  constexpr int S1=264;
  __shared__ float lre[4352], lim[4352];
  int t=threadIdx.x; int bx=blockIdx.x;
  int sig=bx>>3; int tBase=(bx&7)*16;
  const cplx* sb = src + (size_t)sig*NSAMP;
  #pragma unroll
  for (int i=0;i<16;i++){
    int e=t+256*i, g=e&15, r=e>>4;
    cplx vv = sb[tBase+g + (size_t)r*128];
    lre[g*S1+r]=vv.x; lim[g*S1+r]=vv.y;
  }
  __syncthreads();
  fft_core<256,true>(lre,lim,t);
  int g2,c2; cplx z[16];
  fft_stage2<256,true>(lre,lim,t,g2,c2,z);
  __syncthreads();
  #pragma unroll
  for (int d=0;d<16;d++){ int u=c2+16*d; lre[u*17+g2]=z[d].x; lim[u*17+g2]=z[d].y; }
  __syncthreads();
  float* p0 = dstf + (size_t)(2*sig)*NSAMP;
  float* p1 = dstf + (size_t)(2*sig+1)*NSAMP;
  #pragma unroll
  for (int i=0;i<16;i++){
    int e=t+256*i, g3=e&15, u=e>>4;
    int ts = tBase+g3+u*128;
    p0[ts]=lre[u*17+g3]; p1[ts]=lim[u*17+g3];
  }
}

// ---------------- conv fwd pass1 with fused build (LDS overlay, tables precomputed) ----------------
__global__ __launch_bounds__(256) void k_conv_build_fwd1(const float* __restrict__ P,
    const float* __restrict__ NZf, cplx* __restrict__ dst, int rowBase, float interBase){
  constexpr int Q=16, S1=264;
  __shared__ float smem[8448];
  float* lre = smem;
  float* lim = smem + 4224;
  float* sTab = smem;
  int t=threadIdx.x;
  int row = rowBase + blockIdx.y;
  int tBase = blockIdx.x*16;
  const float* Pr = P + (size_t)row*PSTRIDE;
  for (int i=t; i<P_END; i+=256) sTab[i] = Pr[i];
  __syncthreads();
  float mu=sTab[0], sigma=sTab[1], amp=sTab[2], pscale=sTab[3];
  float fac[8], mh[8];
  #pragma unroll
  for (int h=0;h<8;h++){ fac[h]=sTab[4+h]; mh[h]=sTab[12+h]; }
  const float2* fe2 = (const float2*)&sTab[P_FEPAIR];
  const float*  pw2 = &sTab[P_PW2];
  const float2* LQt = (const float2*)&sTab[P_LQ];
  const float*  Af  = &sTab[P_AF];
  const float* nzrow = NZf + (size_t)row*NSAMP;
  float vre[8], vim[8];
  #pragma unroll
  for (int i=0;i<8;i++){
    int e=t+256*i, g=e&15, r=e>>4;
    int ts = tBase + g + (r<<8);
    float cc=fminf(fmaxf((ts+0.5f)*(1.0f/256.0f)-0.5f,0.0f),127.0f);
    int lo=(int)cc; float w=cc-lo;
    float2 fp = fe2[lo];
    float fev = fp.x + w*fp.y;
    int slot, n0;
    if (ts<128){ slot=0; n0=ts+1; } else { int km=(ts-128)>>8; slot=km+1; n0=ts-127-(km<<8); }
    float nf=(float)n0, nf2=nf*nf;
    float2 lq = LQt[slot];
    float base = nf*lq.x + nf2*lq.y;
    float wm = (lo<127)? w : 0.0f;
    float resv=0.f;
    #pragma unroll
    for (int h=0;h<8;h++){
      float mgb = pw2[h*128+lo];
      if (mgb > 1e-7f){
        float rr = Af[slot*8+h] + fac[h]*base;
        float fr = rr - floorf(rr);
        float s = __builtin_amdgcn_sinf(fr);
        resv += s*mgb*(1.0f + wm*(mh[h]-1.0f));
      }
    }
    float zz=((float)ts-mu)/sigma;
    float prb=pscale*__expf(-0.5f*zz*zz);
    vre[i] = prb*nzrow[ts]*amp*fev;
    vim[i] = resv;
  }
  __syncthreads();
  #pragma unroll
  for (int i=0;i<8;i++){
    int e=t+256*i, g=e&15, r=e>>4;
    lre[g*S1+r]=vre[i]; lim[g*S1+r]=vim[i];
  }
  #pragma unroll
  for (int i=8;i<16;i++){
    int e=t+256*i, g=e&15, r=e>>4;
    lre[g*S1+r]=0.f; lim[g*S1+r]=0.f;
  }
  __syncthreads();
  fft_core<256,false>(lre,lim,t);
  int g2,c2; cplx z[16];
  fft_stage2<256,false>(lre,lim,t,g2,c2,z);
  int p = tBase+g2;
  float thp = interBase*(float)p;
  float snc,csc; __sincosf(thp*(float)c2,&snc,&csc);
  float sns,css; __sincosf(thp*(float)Q,&sns,&css);
  cplx wu=make_float2(csc,snc), ws=make_float2(css,sns);
  cplx* db = dst + (size_t)blockIdx.y*NFFT2;
  size_t ob=(size_t)256*(size_t)p+(size_t)c2;
  #pragma unroll
  for (int d=0; d<16; d++){ db[ob+(size_t)(d*16)]=cmul_(z[d],wu); wu=cmul_(wu,ws); }
}

// ---------------- conv fwd pass2 + pointwise Z^2 event-accumulate (no mirror needed) ----------------
// grid (16 colgroups, bpc batches, 2 event-halves); acc in registers across 4 events.
__global__ __launch_bounds__(256) void k_fwd2_sq(const cplx* __restrict__ C,
    cplx* __restrict__ D0, cplx* __restrict__ D1){
  constexpr int S1=264;
  __shared__ float lre[4352], lim[4352];
  int t=threadIdx.x;
  int tBase = blockIdx.x*16;
  int bLoc = blockIdx.y;
  int half = blockIdx.z;
  cplx* Dh = half ? D1 : D0;
  float accx[16], accy[16];
  #pragma unroll
  for (int d=0;d<16;d++){ accx[d]=0.f; accy[d]=0.f; }
  int g2=t>>4, c2=t&15;
  for (int e=0;e<4;e++){
    int sigLoc = bLoc*8 + half*4 + e;
    const cplx* sb = C + (size_t)sigLoc*NFFT2;
    __syncthreads();
    #pragma unroll
    for (int i=0;i<16;i++){
      int ee=t+256*i, g=ee&15, r=ee>>4;
      cplx vv = sb[tBase+g + (size_t)r*256];
      lre[g*S1+r]=vv.x; lim[g*S1+r]=vv.y;
    }
    __syncthreads();
    fft_core<256,false>(lre,lim,t);
    int gg,cc; cplx z[16];
    fft_stage2<256,false>(lre,lim,t,gg,cc,z);
    #pragma unroll
    for (int d=0;d<16;d++){
      float x=z[d].x, y=z[d].y;
      accx[d] += x*x - y*y;
      accy[d] += 2.f*x*y;
    }
  }
  __syncthreads();
  const float s = 1.0f/131072.0f;   // 1/(2*65536): IFFT norm and the 1/2 of the Im identity
  #pragma unroll
  for (int d=0;d<16;d++){ int u=c2+16*d; lre[u*17+g2]=accx[d]*s; lim[u*17+g2]=accy[d]*s; }
  __syncthreads();
  cplx* db = Dh + (size_t)bLoc*NFFT2;
  #pragma unroll
  for (int i=0;i<16;i++){
    int ee=t+256*i, g3=ee&15, u=ee>>4;
    db[tBase+g3 + (size_t)u*256] = make_float2(lre[u*17+g3], lim[u*17+g3]);
  }
}

// ---------------- conv inverse pass1 with fused D0+D1 sum ----------------
__global__ __launch_bounds__(256) void k_inv1_sum(const cplx* __restrict__ D0, const cplx* __restrict__ D1,
    cplx* __restrict__ E){
  constexpr int Q=16, S1=264;
  __shared__ float lre[4352], lim[4352];
  int t=threadIdx.x, bx=blockIdx.x;
  int sig=bx>>4, tBase=(bx&15)*16;
  const cplx* s0 = D0 + (size_t)sig*NFFT2;
  const cplx* s1 = D1 + (size_t)sig*NFFT2;
  cplx* db = E + (size_t)sig*NFFT2;
  #pragma unroll
  for (int i=0;i<16;i++){
    int e=t+256*i, g=e&15, r=e>>4;
    size_t idx = tBase+g + (size_t)r*256;
    cplx a=s0[idx], b=s1[idx];
    lre[g*S1+r]=a.x+b.x; lim[g*S1+r]=a.y+b.y;
  }
  __syncthreads();
  fft_core<256,true>(lre,lim,t);
  int g2,c2; cplx z[16];
  fft_stage2<256,true>(lre,lim,t,g2,c2,z);
  int p = tBase+g2;
  float thp = (TWO_PI_F/65536.0f)*(float)p;
  float snc,csc; __sincosf(thp*(float)c2,&snc,&csc);
  float sns,css; __sincosf(thp*(float)Q,&sns,&css);
  cplx wu=make_float2(csc,snc), ws=make_float2(css,sns);
  size_t ob=(size_t)256*(size_t)p+(size_t)c2;
  #pragma unroll
  for (int d=0; d<16; d++){ db[ob+(size_t)(d*16)]=cmul_(z[d],wu); wu=cmul_(wu,ws); }
}

// ---------------- conv inverse final: keep Im, write first 32768 samples to out ----------------
__global__ __launch_bounds__(256) void k_final_imout(const cplx* __restrict__ E, float* __restrict__ out,
    int batchBase){
  constexpr int S1=264;
  __shared__ float lre[4352], lim[4352];
  int t=threadIdx.x; int bx=blockIdx.x;
  int sig=bx>>4; int tBase=(bx&15)*16;
  const cplx* sb = E + (size_t)sig*NFFT2;
  #pragma unroll
  for (int i=0;i<16;i++){
    int e=t+256*i, g=e&15, r=e>>4;
    cplx vv = sb[tBase+g+(size_t)r*256];
    lre[g*S1+r]=vv.x; lim[g*S1+r]=vv.y;
  }
  __syncthreads();
  fft_core<256,true>(lre,lim,t);
  int g2,c2; cplx z[16];
  fft_stage2<256,true>(lre,lim,t,g2,c2,z);
  __syncthreads();
  #pragma unroll
  for (int d=0;d<16;d++){ int u=c2+16*d; lre[u*17+g2]=z[d].y; }   // Im only
  __syncthreads();
  float* o = out + (size_t)(batchBase+sig)*NSAMP;
  #pragma unroll
  for (int i=0;i<8;i++){
    int e=t+256*i, g3=e&15, u=e>>4;      // u < 128 -> t < 32768
    o[tBase+g3 + u*256] = lre[u*17+g3];
  }
}

// ---------------- parameter extraction + ALL per-row tables ----------------
__global__ __launch_bounds__(256) void k_params(const float* __restrict__ x, float* __restrict__ P){
  int row = blockIdx.x; int t = threadIdx.x;
  const float* xr = x + row*428;
  float* Pr = P + (size_t)row*PSTRIDE;
  __shared__ float sx[428];
  __shared__ float fes[128], f0s[128];
  __shared__ double Cds[128];
  __shared__ float facs[8], ms[8], afs[8];
  __shared__ float f0_sh;
  for (int i=t;i<428;i+=256) sx[i]=1.0f/(1.0f+expf(-xr[i]));
  __syncthreads();
  if (t==0){
    float mean = sx[0]; float stds = sx[1]*0.1f; float amp = sx[2]*sx[2];
    float mu = fminf(fmaxf(mean*32768.0f, -16384.0f), 49152.0f);
    float sigma = fminf(fmaxf((1e-8f + stds)*32768.0f, 0.0f), 32767.0f);
    float c = 1.0f/(sigma*2.5066282746310002f);
    float tt0 = fminf(fmaxf(floorf(mu), 0.0f), 32767.0f);
    float tt1 = fminf(fmaxf(ceilf(mu), 0.0f), 32767.0f);
    float z0 = (tt0-mu)/sigma, z1=(tt1-mu)/sigma;
    float gmax = fmaxf(expf(-0.5f*z0*z0), expf(-0.5f*z1*z1));
    float pscale = c / (c*gmax + 1e-12f);
    Pr[0]=mu; Pr[1]=sigma; Pr[2]=amp; Pr[3]=pscale;
  }
  if (t<8){
    float fv = (t==0)?1.0f:(1.0f+sx[4+t]*7.0f);
    facs[t]=fv; Pr[4+t]=fv;
    float m = sx[12+t]*0.9999f; m=m*m; ms[t]=m; Pr[12+t]=m;
    afs[t]=sx[164+t]*sx[164+t];
  }
  if (t>=32&&t<48) Pr[28+(t-32)] = sx[20+(t-32)];
  if (t==64) f0_sh = sx[3]*sx[3];
  if (t==65){
    float acc=0.f;
    for (int f=0;f<128;f++){ acc += sx[36+f]*2.0f-1.0f; fes[f]=fminf(fmaxf(acc,0.f),1.f); }
  }
  __syncthreads();
  if (t<128){
    float f0=f0_sh;
    f0s[t] = f0 + sx[172+t]*(f0*0.01f);
  }
  __syncthreads();
  if (t==0){
    double acc = 128.0*(double)f0s[0]; Cds[0]=acc;
    for (int k=0;k<127;k++){ acc += 128.0*((double)f0s[k]+(double)f0s[k+1]); Cds[k+1]=acc; }
  }
  if (t<128){
    float v=fes[t], vh=fes[min(t+1,127)];
    Pr[P_FEPAIR+2*t]=v; Pr[P_FEPAIR+2*t+1]=vh-v;
  }
  if (t>=128 && t<136){
    int h=t-128; float m=ms[h];
    float acc = afs[h]*m;
    float* dstp = Pr + P_PW2 + h*128;
    dstp[0]=acc;
    for (int f=1;f<128;f++){ acc*=m; dstp[f]=acc; }
  }
  __syncthreads();
  const double MINF_D=20.0/11025.0, FSPAN_D=2980.0/11025.0;
  if (t<129){
    int k=t-1;
    float Lb, Qb;
    if (k<0){ Lb=(float)(0.5*(MINF_D+FSPAN_D*(double)f0s[0])); Qb=0.f; }
    else {
      double f0k=(double)f0s[k];
      double d=(k<127)?((double)f0s[k+1]-f0k):0.0;
      Lb=(float)(0.5*(MINF_D+FSPAN_D*f0k));
      Qb=(float)(0.5*FSPAN_D*d*(1.0/512.0));
    }
    Pr[P_LQ+2*t]=Lb; Pr[P_LQ+2*t+1]=Qb;
  }
  for (int idx=t; idx<129*8; idx+=256){
    int jj=idx>>3, h=idx&7, k=jj-1;
    float Aval;
    if (k<0) Aval=0.f;
    else {
      double phi0=(double)(128+256*k)*MINF_D+FSPAN_D*Cds[k];
      Aval=(float)(0.5*fmod((double)facs[h]*phi0,2.0));
    }
    Pr[P_AF+idx]=Aval;
  }
}

// ---------------- host ----------------
extern "C" void kernel_launch(void* const* d_in, const int* in_sizes, int n_in,
                              void* d_out, int out_size, void* d_ws, size_t ws_size,
                              hipStream_t stream){
  const float* x = (const float*)d_in[0];
  const float* noise = (const float*)d_in[1];
  float* out = (float*)d_out;
  char* ws = (char*)d_ws;

  const size_t szN = (size_t)64*NSAMP*sizeof(cplx);   // 16.8 MB
  const size_t szD = (size_t)16*NFFT2*sizeof(cplx);   // 8.4 MB
  const size_t oA = (size_t)2<<20;
  const size_t oB = oA + szN;
  const size_t oD0 = oB + szN;
  const size_t oD1 = oD0 + szD;
  const size_t oE  = oD1 + szD;
  const size_t oC  = oE + szD;

  const int cand[5] = {1,2,4,8,16};
  int nchunk = -1;
  for (int ci=0; ci<5; ci++){
    size_t csz = ((size_t)(128/cand[ci]))*NFFT2*sizeof(cplx);
    if (oC + csz <= ws_size){ nchunk = cand[ci]; break; }
  }
  if (nchunk < 0) return;
  int sigPerChunk = 128/nchunk;
  int bpc = sigPerChunk/8;

  float* P = (float*)(ws);
  cplx* A = (cplx*)(ws + oA);
  cplx* B = (cplx*)(ws + oB);
  cplx* D0 = (cplx*)(ws + oD0);
  cplx* D1 = (cplx*)(ws + oD1);
  cplx* E  = (cplx*)(ws + oE);
  cplx* C  = (cplx*)(ws + oC);

  k_params<<<128, 256, 0, stream>>>(x, P);
  // noise: pack+pass1 -> A; pass2+filter+ipass1 -> B; final+split -> A (float planes)
  k_fft_pack_fwd1<<<512, 256, 0, stream>>>(noise, A, -TWO_PI_F/32768.0f);
  k_nfilter_ip1<<<dim3(9,64), 256, 0, stream>>>(A, B, P);
  k_ifinal_split<<<512, 256, 0, stream>>>(B, (float*)A);

  for (int c=0; c<nchunk; c++){
    int rowBase = c*sigPerChunk;
    int batchBase = c*bpc;
    k_conv_build_fwd1<<<dim3(16, sigPerChunk), 256, 0, stream>>>(P, (float*)A, C, rowBase, -TWO_PI_F/65536.0f);
    k_fwd2_sq<<<dim3(16, bpc, 2), 256, 0, stream>>>(C, D0, D1);
    k_inv1_sum<<<bpc*16, 256, 0, stream>>>(D0, D1, E);
    k_final_imout<<<bpc*16, 256, 0, stream>>>(E, out, batchBase);
  }
}

// Round 8
// 116.110 us; speedup vs baseline: 3.9374x; 1.1228x over previous
//
#include <hip/hip_runtime.h>
#include <math.h>

#define NSAMP 32768
#define NFFT2 65536
#define NFRM 128
#define PSTRIDE 2688
#define P_FEPAIR 64
#define P_PW2 320
#define P_LQ 1344
#define P_AF 1604
#define P_END 2636
#define TWO_PI_F 6.28318530717958647692f

typedef float2 cplx;

__device__ __forceinline__ cplx cmul_(cplx a, cplx b){ return make_float2(a.x*b.x - a.y*b.y, a.x*b.y + a.y*b.x); }
__device__ __forceinline__ cplx cadd_(cplx a, cplx b){ return make_float2(a.x+b.x, a.y+b.y); }
__device__ __forceinline__ cplx csub_(cplx a, cplx b){ return make_float2(a.x-b.x, a.y-b.y); }

__device__ __forceinline__ unsigned int packbf2(float re, float im){
  unsigned int ur = __float_as_uint(re);
  unsigned int ui = __float_as_uint(im);
  ur = (ur + 0x7FFFu + ((ur>>16)&1u)) >> 16;
  ui = (ui + 0x7FFFu + ((ui>>16)&1u)) & 0xFFFF0000u;
  return ur | ui;
}

template<bool INV>
__device__ __forceinline__ void dft4_(cplx x0,cplx x1,cplx x2,cplx x3, cplx&y0,cplx&y1,cplx&y2,cplx&y3){
  cplx t0=cadd_(x0,x2), t1=csub_(x0,x2), t2=cadd_(x1,x3), t3=csub_(x1,x3);
  y0=cadd_(t0,t2); y2=csub_(t0,t2);
  cplx it3 = make_float2(-t3.y, t3.x);
  if (INV){ y1=cadd_(t1,it3); y3=csub_(t1,it3); }
  else    { y1=csub_(t1,it3); y3=cadd_(t1,it3); }
}

template<bool INV>
__device__ __forceinline__ void dft8ip_(cplx* v){
  cplx e0,e1,e2,e3,o0,o1,o2,o3;
  dft4_<INV>(v[0],v[2],v[4],v[6], e0,e1,e2,e3);
  dft4_<INV>(v[1],v[3],v[5],v[7], o0,o1,o2,o3);
  const float r = 0.70710678118654752440f;
  cplx w1 = INV ? make_float2(r, r)    : make_float2(r,-r);
  cplx w2 = INV ? make_float2(0.f,1.f) : make_float2(0.f,-1.f);
  cplx w3 = INV ? make_float2(-r,r)    : make_float2(-r,-r);
  cplx t1 = cmul_(o1,w1), t2 = cmul_(o2,w2), t3 = cmul_(o3,w3);
  v[0]=cadd_(e0,o0); v[4]=csub_(e0,o0);
  v[1]=cadd_(e1,t1); v[5]=csub_(e1,t1);
  v[2]=cadd_(e2,t2); v[6]=csub_(e2,t2);
  v[3]=cadd_(e3,t3); v[7]=csub_(e3,t3);
}

template<bool INV>
__device__ __forceinline__ void dft16ip_(cplx* v){
  cplx t0[4], t1[4], t2[4], t3[4];
  dft4_<INV>(v[0], v[4], v[8],  v[12], t0[0],t0[1],t0[2],t0[3]);
  dft4_<INV>(v[1], v[5], v[9],  v[13], t1[0],t1[1],t1[2],t1[3]);
  dft4_<INV>(v[2], v[6], v[10], v[14], t2[0],t2[1],t2[2],t2[3]);
  dft4_<INV>(v[3], v[7], v[11], v[15], t3[0],t3[1],t3[2],t3[3]);
  const float C1=0.92387953251128675613f, S1=0.38268343236508977172f, R2=0.70710678118654752440f;
  #define TWD_(x, cc, ss) (INV ? cmul_((x), make_float2((cc), (ss))) : cmul_((x), make_float2((cc), -(ss))))
  t1[1] = TWD_(t1[1], C1, S1);
  t1[2] = TWD_(t1[2], R2, R2);
  t1[3] = TWD_(t1[3], S1, C1);
  t2[1] = TWD_(t2[1], R2, R2);
  t2[2] = TWD_(t2[2], 0.f, 1.f);
  t2[3] = TWD_(t2[3], -R2, R2);
  t3[1] = TWD_(t3[1], S1, C1);
  t3[2] = TWD_(t3[2], -R2, R2);
  t3[3] = TWD_(t3[3], -C1, -S1);
  #undef TWD_
  dft4_<INV>(t0[0], t1[0], t2[0], t3[0], v[0], v[4], v[8],  v[12]);
  dft4_<INV>(t0[1], t1[1], t2[1], t3[1], v[1], v[5], v[9],  v[13]);
  dft4_<INV>(t0[2], t1[2], t2[2], t3[2], v[2], v[6], v[10], v[14]);
  dft4_<INV>(t0[3], t1[3], t2[3], t3[3], v[3], v[7], v[11], v[15]);
}

template<int R0, bool INV>
__device__ __forceinline__ void fft_core(float* lre, float* lim, int t){
  constexpr int Q = R0/16;
  constexpr int S1 = R0 + 8;
  int g = t >> 4, a = t & 15;
  cplx v[Q];
  #pragma unroll
  for (int bb=0;bb<Q;bb++){ int idx = g*S1 + a + 16*bb; v[bb]=make_float2(lre[idx],lim[idx]); }
  if constexpr (Q==16) dft16ip_<INV>(v); else dft8ip_<INV>(v);
  float th = (INV?TWO_PI_F:-TWO_PI_F)*(float)a/(float)R0;
  float sn,cs; __sincosf(th,&sn,&cs);
  cplx w1=make_float2(cs,sn), wu=w1;
  #pragma unroll
  for (int c=1;c<Q;c++){ v[c]=cmul_(v[c],wu); wu=cmul_(wu,w1); }
  __syncthreads();
  #pragma unroll
  for (int c=0;c<Q;c++){ int m = a*Q + ((c+a)&(Q-1)); lre[g*S1+m]=v[c].x; lim[g*S1+m]=v[c].y; }
  __syncthreads();
}

template<int R0, bool INV>
__device__ __forceinline__ bool fft_stage2(const float* lre, const float* lim, int t, int& g2, int& c2, cplx* z){
  constexpr int Q = R0/16; constexpr int S1 = R0+8;
  bool active = (R0==256) || (t < 16*Q);
  g2 = (R0==256)?(t>>4):(t>>3);
  c2 = (R0==256)?(t&15):(t&7);
  if (active){
    #pragma unroll
    for (int a2=0;a2<16;a2++){ int m = a2*Q + ((c2+a2)&(Q-1)); z[a2]=make_float2(lre[g2*S1+m], lim[g2*S1+m]); }
    dft16ip_<INV>(z);
  }
  return active;
}

// ---------------- noise fwd pass1 with fused pack (R0=256, perSig=128) ----------------
__global__ __launch_bounds__(256) void k_fft_pack_fwd1(const float* __restrict__ noise, cplx* __restrict__ dst, float interBase){
  constexpr int Q=16, S1=264;
  __shared__ float lre[4352], lim[4352];
  int t=threadIdx.x;
  int bx=blockIdx.x;
  int sig = bx>>3;
  int tBase=(bx&7)*16;
  const float* n0 = noise + (size_t)(2*sig)*NSAMP;
  const float* n1 = noise + (size_t)(2*sig+1)*NSAMP;
  #pragma unroll
  for (int i=0;i<16;i++){
    int e=t+256*i, g=e&15, r=e>>4;
    int ts = tBase+g+128*r;
    lre[g*S1+r]=n0[ts]*2.f-1.f;
    lim[g*S1+r]=n1[ts]*2.f-1.f;
  }
  __syncthreads();
  fft_core<256,false>(lre,lim,t);
  int g2,c2; cplx z[16];
  fft_stage2<256,false>(lre,lim,t,g2,c2,z);
  int p=tBase+g2;
  float thp=interBase*(float)p;
  float snc,csc; __sincosf(thp*(float)c2,&snc,&csc);
  float sns,css; __sincosf(thp*(float)Q,&sns,&css);
  cplx wu=make_float2(csc,snc), ws=make_float2(css,sns);
  cplx* db = dst + (size_t)sig*NSAMP;
  size_t ob=(size_t)256*(size_t)p+(size_t)c2;
  #pragma unroll
  for (int d=0;d<16;d++){ db[ob+(size_t)(d*16)]=cmul_(z[d],wu); wu=cmul_(wu,ws); }
}

// ---------------- noise fwd pass2 + filter + inverse pass1, all fused ----------------
__device__ __forceinline__ void fft128_natural(float* re, float* im, int t){
  __syncthreads();
  fft_core<128,false>(re,im,t);
  int g2,c2; cplx z[16];
  bool act = fft_stage2<128,false>(re,im,t,g2,c2,z);
  __syncthreads();
  if (act){
    #pragma unroll
    for (int d=0;d<16;d++){ int u=c2+8*d; re[u*17+g2]=z[d].x; im[u*17+g2]=z[d].y; }
  }
  __syncthreads();
}

__global__ __launch_bounds__(256) void k_nfilter_ip1(const cplx* __restrict__ src, cplx* __restrict__ dst,
    const float* __restrict__ P){
  __shared__ float aRe[2176], aIm[2176], bRe[2176], bIm[2176];
  __shared__ float fRe[2176], fIm[2176];
  __shared__ float c1s[16], c2sh[16];
  int t=threadIdx.x, pb=blockIdx.x, j=blockIdx.y;
  const cplx* sb = src + ((size_t)j<<15);
  cplx* db = dst + ((size_t)j<<15);
  if (t<16) c1s[t] = P[(size_t)(2*j)*PSTRIDE+28+t];
  else if (t<32) c2sh[t-16] = P[(size_t)(2*j+1)*PSTRIDE+28+(t-16)];
  #pragma unroll
  for (int i=0;i<8;i++){
    int e=t+256*i, g=e&15, r=e>>4;
    int col = (pb<8)? (pb*16+g) : (g*16);
    cplx v = sb[col + (r<<8)];
    aRe[g*136+r]=v.x; aIm[g*136+r]=v.y;
  }
  fft128_natural(aRe,aIm,t);
  if (pb<8){
    #pragma unroll
    for (int i=0;i<8;i++){
      int e=t+256*i, g=e&15, r=e>>4;
      int col = 240-pb*16+g;
      cplx v = sb[col + (r<<8)];
      bRe[g*136+r]=v.x; bIm[g*136+r]=v.y;
    }
    fft128_natural(bRe,bIm,t);
  }
  const float inv32768 = 1.0f/32768.0f;
  if (pb<8){
    for (int s=0;s<2;s++){
      __syncthreads();
      #pragma unroll
      for (int uu=0; uu<8; uu++){
        int g=t&15, u=(t>>4)+16*uu;
        if (g!=0){
          int colK = s? (240-pb*16+g) : (pb*16+g);
          int gm=16-g, um=127-u;
          float Zkx,Zky,Zmx,Zmy;
          if (s==0){ Zkx=aRe[u*17+g]; Zky=aIm[u*17+g]; Zmx=bRe[um*17+gm]; Zmy=bIm[um*17+gm]; }
          else     { Zkx=bRe[u*17+g]; Zky=bIm[u*17+g]; Zmx=aRe[um*17+gm]; Zmy=aIm[um*17+gm]; }
          int k = colK + (u<<8);
          int kb = min(k, NSAMP-k);
          float coords=fminf(fmaxf((kb+0.5f)*(16.0f/16385.0f)-0.5f,0.0f),15.0f);
          int lo=(int)coords; float w=coords-lo; int hi=min(lo+1,15);
          float s1=(c1s[lo]+w*(c1s[hi]-c1s[lo]))*inv32768;
          float s2=(c2sh[lo]+w*(c2sh[hi]-c2sh[lo]))*inv32768;
          float U1x=0.5f*(Zkx+Zmx), U1y=0.5f*(Zky-Zmy);
          float U2x=0.5f*(Zky+Zmy), U2y=-0.5f*(Zkx-Zmx);
          fRe[g*136+u]=U1x*s1 - U2y*s2; fIm[g*136+u]=U1y*s1 + U2x*s2;
        }
      }
      __syncthreads();
      fft_core<128,true>(fRe,fIm,t);
      int gg,cc; cplx z[16];
      bool act = fft_stage2<128,true>(fRe,fIm,t,gg,cc,z);
      if (act && gg!=0){
        int p = (s==0) ? (pb*16+gg) : (240-pb*16+gg);
        float thp=(TWO_PI_F/32768.0f)*(float)p;
        float snc,csc; __sincosf(thp*(float)cc,&snc,&csc);
        float sns,css; __sincosf(thp*8.0f,&sns,&css);
        cplx wu=make_float2(csc,snc), wsx=make_float2(css,sns);
        int ob=128*p+cc;
        #pragma unroll
        for (int d=0;d<16;d++){ db[ob+8*d]=cmul_(z[d],wu); wu=cmul_(wu,wsx); }
      }
    }
  } else {
    __syncthreads();
    #pragma unroll
    for (int uu=0; uu<8; uu++){
      int g=t&15, u=(t>>4)+16*uu;
      int k = g*16 + (u<<8);
      int gm=(16-g)&15;
      int um=(g==0)? ((128-u)&127) : (127-u);
      float Zkx=aRe[u*17+g], Zky=aIm[u*17+g];
      float Zmx=aRe[um*17+gm], Zmy=aIm[um*17+gm];
      int kb = min(k, NSAMP-k);
      float coords=fminf(fmaxf((kb+0.5f)*(16.0f/16385.0f)-0.5f,0.0f),15.0f);
      int lo=(int)coords; float w=coords-lo; int hi=min(lo+1,15);
      float s1=(c1s[lo]+w*(c1s[hi]-c1s[lo]))*inv32768;
      float s2=(c2sh[lo]+w*(c2sh[hi]-c2sh[lo]))*inv32768;
      float U1x=0.5f*(Zkx+Zmx), U1y=0.5f*(Zky-Zmy);
      float U2x=0.5f*(Zky+Zmy), U2y=-0.5f*(Zkx-Zmx);
      fRe[g*136+u]=U1x*s1 - U2y*s2; fIm[g*136+u]=U1y*s1 + U2x*s2;
    }
    __syncthreads();
    fft_core<128,true>(fRe,fIm,t);
    int gg,cc; cplx z[16];
    bool act = fft_stage2<128,true>(fRe,fIm,t,gg,cc,z);
    if (act){
      int p = 16*gg;
      float thp=(TWO_PI_F/32768.0f)*(float)p;
      float snc,csc; __sincosf(thp*(float)cc,&snc,&csc);
      float sns,css; __sincosf(thp*8.0f,&sns,&css);
      cplx wu=make_float2(csc,snc), wsx=make_float2(css,sns);
      int ob=128*p+cc;
      #pragma unroll
      for (int d=0;d<16;d++){ db[ob+8*d]=cmul_(z[d],wu); wu=cmul_(wu,wsx); }
    }
  }
}

// ---------------- noise inverse final (R0=256, perSig=128) with split-plane store ----------------
__global__ __launch_bounds__(256) void k_ifinal_split(const cplx* __restrict__ src, float* __restrict__ dstf){
  constexpr int S1=264;
  __shared__ float lre[4352], lim[4352];
  int t=threadIdx.x; int bx=blockIdx.x;
  int sig=bx>>3; int tBase=(bx&7)*16;
  const cplx* sb = src + (size_t)sig*NSAMP;
  #pragma unroll
  for (int i=0;i<16;i++){
    int e=t+256*i, g=e&15, r=e>>4;
    cplx vv = sb[tBase+g + (size_t)r*128];
    lre[g*S1+r]=vv.x; lim[g*S1+r]=vv.y;
  }
  __syncthreads();
  fft_core<256,true>(lre,lim,t);
  int g2,c2; cplx z[16];
  fft_stage2<256,true>(lre,lim,t,g2,c2,z);
  __syncthreads();
  #pragma unroll
  for (int d=0;d<16;d++){ int u=c2+16*d; lre[u*17+g2]=z[d].x; lim[u*17+g2]=z[d].y; }
  __syncthreads();
  float* p0 = dstf + (size_t)(2*sig)*NSAMP;
  float* p1 = dstf + (size_t)(2*sig+1)*NSAMP;
  #pragma unroll
  for (int i=0;i<16;i++){
    int e=t+256*i, g3=e&15, u=e>>4;
    int ts = tBase+g3+u*128;
    p0[ts]=lre[u*17+g3]; p1[ts]=lim[u*17+g3];
  }
}

// ---------------- conv fwd pass1 with fused build (LDS overlay); bf16-packed output ----------------
__global__ __launch_bounds__(256) void k_conv_build_fwd1(const float* __restrict__ P,
    const float* __restrict__ NZf, unsigned int* __restrict__ dst, int rowBase, float interBase){
  constexpr int Q=16, S1=264;
  __shared__ float smem[8448];
  float* lre = smem;
  float* lim = smem + 4224;
  float* sTab = smem;
  int t=threadIdx.x;
  int row = rowBase + blockIdx.y;
  int tBase = blockIdx.x*16;
  const float* Pr = P + (size_t)row*PSTRIDE;
  for (int i=t; i<P_END; i+=256) sTab[i] = Pr[i];
  __syncthreads();
  float mu=sTab[0], sigma=sTab[1], amp=sTab[2], pscale=sTab[3];
  float fac[8], mh[8];
  #pragma unroll
  for (int h=0;h<8;h++){ fac[h]=sTab[4+h]; mh[h]=sTab[12+h]; }
  const float2* fe2 = (const float2*)&sTab[P_FEPAIR];
  const float*  pw2 = &sTab[P_PW2];
  const float2* LQt = (const float2*)&sTab[P_LQ];
  const float*  Af  = &sTab[P_AF];
  const float* nzrow = NZf + (size_t)row*NSAMP;
  float vre[8], vim[8];
  #pragma unroll
  for (int i=0;i<8;i++){
    int e=t+256*i, g=e&15, r=e>>4;
    int ts = tBase + g + (r<<8);
    float cc=fminf(fmaxf((ts+0.5f)*(1.0f/256.0f)-0.5f,0.0f),127.0f);
    int lo=(int)cc; float w=cc-lo;
    float2 fp = fe2[lo];
    float fev = fp.x + w*fp.y;
    int slot, n0;
    if (ts<128){ slot=0; n0=ts+1; } else { int km=(ts-128)>>8; slot=km+1; n0=ts-127-(km<<8); }
    float nf=(float)n0, nf2=nf*nf;
    float2 lq = LQt[slot];
    float base = nf*lq.x + nf2*lq.y;
    float wm = (lo<127)? w : 0.0f;
    float resv=0.f;
    #pragma unroll
    for (int h=0;h<8;h++){
      float mgb = pw2[h*128+lo];
      if (mgb > 1e-7f){
        float rr = Af[slot*8+h] + fac[h]*base;
        float fr = rr - floorf(rr);
        float s = __builtin_amdgcn_sinf(fr);
        resv += s*mgb*(1.0f + wm*(mh[h]-1.0f));
      }
    }
    float zz=((float)ts-mu)/sigma;
    float prb=pscale*__expf(-0.5f*zz*zz);
    vre[i] = prb*nzrow[ts]*amp*fev;
    vim[i] = resv;
  }
  __syncthreads();
  #pragma unroll
  for (int i=0;i<8;i++){
    int e=t+256*i, g=e&15, r=e>>4;
    lre[g*S1+r]=vre[i]; lim[g*S1+r]=vim[i];
  }
  #pragma unroll
  for (int i=8;i<16;i++){
    int e=t+256*i, g=e&15, r=e>>4;
    lre[g*S1+r]=0.f; lim[g*S1+r]=0.f;
  }
  __syncthreads();
  fft_core<256,false>(lre,lim,t);
  int g2,c2; cplx z[16];
  fft_stage2<256,false>(lre,lim,t,g2,c2,z);
  int p = tBase+g2;
  float thp = interBase*(float)p;
  float snc,csc; __sincosf(thp*(float)c2,&snc,&csc);
  float sns,css; __sincosf(thp*(float)Q,&sns,&css);
  cplx wu=make_float2(csc,snc), ws=make_float2(css,sns);
  unsigned int* db = dst + (size_t)blockIdx.y*NFFT2;
  size_t ob=(size_t)256*(size_t)p+(size_t)c2;
  #pragma unroll
  for (int d=0; d<16; d++){
    cplx val = cmul_(z[d],wu);
    db[ob+(size_t)(d*16)] = packbf2(val.x, val.y);
    wu=cmul_(wu,ws);
  }
}

// ---------------- fused: conv fwd pass2 + Z^2 event-accumulate + inverse pass1 ----------------
// grid (16 colgroups, bpc batches, 2 halves). Eliminates the D intermediate entirely.
__global__ __launch_bounds__(256) void k_sq_inv1(const unsigned int* __restrict__ C,
    cplx* __restrict__ E0, cplx* __restrict__ E1){
  constexpr int Q=16, S1=264;
  __shared__ float lre[4352], lim[4352];
  int t=threadIdx.x;
  int tBase = blockIdx.x*16;
  int bLoc = blockIdx.y;
  int half = blockIdx.z;
  cplx* Eh = half ? E1 : E0;
  float accx[16], accy[16];
  #pragma unroll
  for (int d=0;d<16;d++){ accx[d]=0.f; accy[d]=0.f; }
  int g2=t>>4, c2=t&15;
  for (int e=0;e<4;e++){
    int sigLoc = bLoc*8 + half*4 + e;
    const unsigned int* sb = C + (size_t)sigLoc*NFFT2;
    __syncthreads();
    #pragma unroll
    for (int i=0;i<16;i++){
      int ee=t+256*i, g=ee&15, r=ee>>4;
      unsigned int u = sb[tBase+g + (size_t)r*256];
      lre[g*S1+r]=__uint_as_float(u<<16);
      lim[g*S1+r]=__uint_as_float(u & 0xFFFF0000u);
    }
    __syncthreads();
    fft_core<256,false>(lre,lim,t);
    int gg,cc; cplx z[16];
    fft_stage2<256,false>(lre,lim,t,gg,cc,z);
    #pragma unroll
    for (int d=0;d<16;d++){
      float x=z[d].x, y=z[d].y;
      accx[d] += x*x - y*y;
      accy[d] += 2.f*x*y;
    }
  }
  __syncthreads();
  // write accumulated spectrum tile (scaled) back as inverse-pass-1 input: column g2, rows c2+16d
  const float s = 1.0f/131072.0f;
  #pragma unroll
  for (int d=0;d<16;d++){
    int rrow = c2 + 16*d;
    lre[g2*S1+rrow] = accx[d]*s;
    lim[g2*S1+rrow] = accy[d]*s;
  }
  __syncthreads();
  fft_core<256,true>(lre,lim,t);
  int gg,cc; cplx z[16];
  fft_stage2<256,true>(lre,lim,t,gg,cc,z);
  int p = tBase+gg;
  float thp = (TWO_PI_F/65536.0f)*(float)p;
  float snc,csc; __sincosf(thp*(float)cc,&snc,&csc);
  float sns,css; __sincosf(thp*(float)Q,&sns,&css);
  cplx wu=make_float2(csc,snc), ws=make_float2(css,sns);
  cplx* db = Eh + (size_t)bLoc*NFFT2;
  size_t ob=(size_t)256*(size_t)p+(size_t)cc;
  #pragma unroll
  for (int d=0; d<16; d++){ db[ob+(size_t)(d*16)]=cmul_(z[d],wu); wu=cmul_(wu,ws); }
}

// ---------------- conv inverse final: sum E0+E1, keep Im, write first 32768 to out ----------------
__global__ __launch_bounds__(256) void k_final_imout(const cplx* __restrict__ E0, const cplx* __restrict__ E1,
    float* __restrict__ out, int batchBase){
  constexpr int S1=264;
  __shared__ float lre[4352], lim[4352];
  int t=threadIdx.x; int bx=blockIdx.x;
  int sig=bx>>4; int tBase=(bx&15)*16;
  const cplx* s0 = E0 + (size_t)sig*NFFT2;
  const cplx* s1 = E1 + (size_t)sig*NFFT2;
  #pragma unroll
  for (int i=0;i<16;i++){
    int e=t+256*i, g=e&15, r=e>>4;
    size_t idx = tBase+g+(size_t)r*256;
    cplx a=s0[idx], b=s1[idx];
    lre[g*S1+r]=a.x+b.x; lim[g*S1+r]=a.y+b.y;
  }
  __syncthreads();
  fft_core<256,true>(lre,lim,t);
  int g2,c2; cplx z[16];
  fft_stage2<256,true>(lre,lim,t,g2,c2,z);
  __syncthreads();
  #pragma unroll
  for (int d=0;d<16;d++){ int u=c2+16*d; lre[u*17+g2]=z[d].y; }   // Im only
  __syncthreads();
  float* o = out + (size_t)(batchBase+sig)*NSAMP;
  #pragma unroll
  for (int i=0;i<8;i++){
    int e=t+256*i, g3=e&15, u=e>>4;
    o[tBase+g3 + u*256] = lre[u*17+g3];
  }
}

// ---------------- parameter extraction + ALL per-row tables ----------------
__global__ __launch_bounds__(256) void k_params(const float* __restrict__ x, float* __restrict__ P){
  int row = blockIdx.x; int t = threadIdx.x;
  const float* xr = x + row*428;
  float* Pr = P + (size_t)row*PSTRIDE;
  __shared__ float sx[428];
  __shared__ float fes[128], f0s[128];
  __shared__ double Cds[128];
  __shared__ float facs[8], ms[8], afs[8];
  __shared__ float f0_sh;
  for (int i=t;i<428;i+=256) sx[i]=1.0f/(1.0f+expf(-xr[i]));
  __syncthreads();
  if (t==0){
    float mean = sx[0]; float stds = sx[1]*0.1f; float amp = sx[2]*sx[2];
    float mu = fminf(fmaxf(mean*32768.0f, -16384.0f), 49152.0f);
    float sigma = fminf(fmaxf((1e-8f + stds)*32768.0f, 0.0f), 32767.0f);
    float c = 1.0f/(sigma*2.5066282746310002f);
    float tt0 = fminf(fmaxf(floorf(mu), 0.0f), 32767.0f);
    float tt1 = fminf(fmaxf(ceilf(mu), 0.0f), 32767.0f);
    float z0 = (tt0-mu)/sigma, z1=(tt1-mu)/sigma;
    float gmax = fmaxf(expf(-0.5f*z0*z0), expf(-0.5f*z1*z1));
    float pscale = c / (c*gmax + 1e-12f);
    Pr[0]=mu; Pr[1]=sigma; Pr[2]=amp; Pr[3]=pscale;
  }
  if (t<8){
    float fv = (t==0)?1.0f:(1.0f+sx[4+t]*7.0f);
    facs[t]=fv; Pr[4+t]=fv;
    float m = sx[12+t]*0.9999f; m=m*m; ms[t]=m; Pr[12+t]=m;
    afs[t]=sx[164+t]*sx[164+t];
  }
  if (t>=32&&t<48) Pr[28+(t-32)] = sx[20+(t-32)];
  if (t==64) f0_sh = sx[3]*sx[3];
  if (t==65){
    float acc=0.f;
    for (int f=0;f<128;f++){ acc += sx[36+f]*2.0f-1.0f; fes[f]=fminf(fmaxf(acc,0.f),1.f); }
  }
  __syncthreads();
  if (t<128){
    float f0=f0_sh;
    f0s[t] = f0 + sx[172+t]*(f0*0.01f);
  }
  __syncthreads();
  if (t==0){
    double acc = 128.0*(double)f0s[0]; Cds[0]=acc;
    for (int k=0;k<127;k++){ acc += 128.0*((double)f0s[k]+(double)f0s[k+1]); Cds[k+1]=acc; }
  }
  if (t<128){
    float v=fes[t], vh=fes[min(t+1,127)];
    Pr[P_FEPAIR+2*t]=v; Pr[P_FEPAIR+2*t+1]=vh-v;
  }
  if (t>=128 && t<136){
    int h=t-128; float m=ms[h];
    float acc = afs[h]*m;
    float* dstp = Pr + P_PW2 + h*128;
    dstp[0]=acc;
    for (int f=1;f<128;f++){ acc*=m; dstp[f]=acc; }
  }
  __syncthreads();
  const double MINF_D=20.0/11025.0, FSPAN_D=2980.0/11025.0;
  if (t<129){
    int k=t-1;
    float Lb, Qb;
    if (k<0){ Lb=(float)(0.5*(MINF_D+FSPAN_D*(double)f0s[0])); Qb=0.f; }
    else {
      double f0k=(double)f0s[k];
      double d=(k<127)?((double)f0s[k+1]-f0k):0.0;
      Lb=(float)(0.5*(MINF_D+FSPAN_D*f0k));
      Qb=(float)(0.5*FSPAN_D*d*(1.0/512.0));
    }
    Pr[P_LQ+2*t]=Lb; Pr[P_LQ+2*t+1]=Qb;
  }
  for (int idx=t; idx<129*8; idx+=256){
    int jj=idx>>3, h=idx&7, k=jj-1;
    float Aval;
    if (k<0) Aval=0.f;
    else {
      double phi0=(double)(128+256*k)*MINF_D+FSPAN_D*Cds[k];
      Aval=(float)(0.5*fmod((double)facs[h]*phi0,2.0));
    }
    Pr[P_AF+idx]=Aval;
  }
}

// ---------------- host ----------------
extern "C" void kernel_launch(void* const* d_in, const int* in_sizes, int n_in,
                              void* d_out, int out_size, void* d_ws, size_t ws_size,
                              hipStream_t stream){
  const float* x = (const float*)d_in[0];
  const float* noise = (const float*)d_in[1];
  float* out = (float*)d_out;
  char* ws = (char*)d_ws;

  const size_t szN = (size_t)64*NSAMP*sizeof(cplx);     // 16.8 MB
  const size_t szE = (size_t)16*NFFT2*sizeof(cplx);     // 8.4 MB (max bpc=16)
  const size_t oA  = (size_t)2<<20;
  const size_t oB  = oA + szN;
  const size_t oE0 = oB + szN;
  const size_t oE1 = oE0 + szE;
  const size_t oC  = oE1 + szE;

  const int cand[5] = {1,2,4,8,16};
  int nchunk = -1;
  for (int ci=0; ci<5; ci++){
    size_t csz = ((size_t)(128/cand[ci]))*NFFT2*sizeof(unsigned int);
    if (oC + csz <= ws_size){ nchunk = cand[ci]; break; }
  }
  if (nchunk < 0) return;
  int sigPerChunk = 128/nchunk;
  int bpc = sigPerChunk/8;

  float* P = (float*)(ws);
  cplx* A = (cplx*)(ws + oA);
  cplx* B = (cplx*)(ws + oB);
  cplx* E0 = (cplx*)(ws + oE0);
  cplx* E1 = (cplx*)(ws + oE1);
  unsigned int* C = (unsigned int*)(ws + oC);

  k_params<<<128, 256, 0, stream>>>(x, P);
  // noise: pack+pass1 -> A; pass2+filter+ipass1 -> B; final+split -> A (float planes)
  k_fft_pack_fwd1<<<512, 256, 0, stream>>>(noise, A, -TWO_PI_F/32768.0f);
  k_nfilter_ip1<<<dim3(9,64), 256, 0, stream>>>(A, B, P);
  k_ifinal_split<<<512, 256, 0, stream>>>(B, (float*)A);

  for (int c=0; c<nchunk; c++){
    int rowBase = c*sigPerChunk;
    int batchBase = c*bpc;
    k_conv_build_fwd1<<<dim3(16, sigPerChunk), 256, 0, stream>>>(P, (float*)A, C, rowBase, -TWO_PI_F/65536.0f);
    k_sq_inv1<<<dim3(16, bpc, 2), 256, 0, stream>>>(C, E0, E1);
    k_final_imout<<<bpc*16, 256, 0, stream>>>(E0, E1, out, batchBase);
  }
}